// Round 21
// baseline (683.065 us; speedup 1.0000x reference)
//
#include <hip/hip_runtime.h>
#include <math.h>

#define HH 128
#define WW 128
#define CC 180
#define BB 4
#define IMG (HH*WW)          // 16384 tokens per image
#define NTOK (BB*IMG)        // 65536
#define HALFTOK (2*IMG)      // 32768
#define NHEADS 6
#define HD 30
#define WSZ 16
#define NTOKW (WSZ*WSZ)      // 256
#define HID 720
#define QKVSTR 672           // merged row: q/k/v (3x192) + cab0 (96)

typedef __attribute__((ext_vector_type(8))) short short8v;
typedef __attribute__((ext_vector_type(4))) short short4v;
typedef __attribute__((ext_vector_type(4))) float f32x4;
typedef unsigned short ushortw;

__device__ __forceinline__ float warp_sum(float v) {
    #pragma unroll
    for (int o = 32; o > 0; o >>= 1) v += __shfl_xor(v, o);
    return v;
}
__device__ __forceinline__ float warp_max(float v) {
    #pragma unroll
    for (int o = 32; o > 0; o >>= 1) v = fmaxf(v, __shfl_xor(v, o));
    return v;
}
__device__ __forceinline__ float gelu_exact(float v) {
    return 0.5f * v * (1.f + erff(v * 0.70710678118654752f));
}
__device__ __forceinline__ ushortw f2bf(float f) {
    union { float f; unsigned int u; } c; c.f = f;
    unsigned int r = (c.u + 0x7FFFu + ((c.u >> 16) & 1u)) >> 16;
    return (ushortw)r;
}
__device__ __forceinline__ float bf2f(ushortw u) {
    union { unsigned int u; float f; } c; c.u = ((unsigned int)u) << 16; return c.f;
}

// ---------------- fused weight/bias prep (one launch) ----------------
__global__ __launch_bounds__(256) void prep_kernel(
    const float* __restrict__ qkv_w, const float* __restrict__ proj_w,
    const float* __restrict__ cab_w0, const float* __restrict__ cab_b0,
    const float* __restrict__ cab_w2,
    const float* __restrict__ fc1_w, const float* __restrict__ pw_w,
    const float* __restrict__ fc2_w,
    const float* __restrict__ cab_w1, const float* __restrict__ cab_b1,
    const float* __restrict__ cab_w3, const float* __restrict__ cab_b3,
    const float* __restrict__ dw_w, const float* __restrict__ dw_b,
    const float* __restrict__ qkv_b, const int* __restrict__ rpi,
    const float* __restrict__ rpb,
    ushortw* __restrict__ wqkvc, ushortw* __restrict__ wproj,
    ushortw* __restrict__ wcab2,
    ushortw* __restrict__ wfc1, ushortw* __restrict__ wpw, ushortw* __restrict__ wfc2,
    float* __restrict__ dwt1, float* __restrict__ db1,
    float* __restrict__ dwt2, float* __restrict__ db2,
    float* __restrict__ dwt3, float* __restrict__ db3,
    float* __restrict__ qb672, float* __restrict__ biasN)
{
    int idx = blockIdx.x * 256 + threadIdx.x;
    if (idx < 129024) {                              // J0: wqkvc [672][192]
        int r = idx / 192, k = idx - r * 192;
        float v = 0.f;
        if (r < 576) {
            int sub = r / 192, rem = r - sub * 192;
            int hh = rem >> 5, dd = rem & 31;
            if (dd < 30 && k < 180) v = qkv_w[(sub * 180 + hh * 30 + dd) * 180 + k];
        } else if (r < 666) {
            if (k < 180) v = cab_w0[(r - 576) * 180 + k];
        }
        wqkvc[idx] = f2bf(v);
    } else if (idx < 178176) {                       // J1: wproj [256][192]
        int l = idx - 129024; int r = l / 192, k = l - r * 192;
        wproj[l] = f2bf((r < 180 && k < 180) ? proj_w[r * 180 + k] : 0.f);
    } else if (idx < 210944) {                       // J2: wcab2 [256][128]
        int l = idx - 178176; int r = l / 128, k = l - r * 128;
        wcab2[l] = f2bf((r < 180 && k < 90) ? cab_w2[r * 90 + k] : 0.f);
    } else if (idx < 358400) {                       // J3: wfc1 [768][192]
        int l = idx - 210944; int r = l / 192, k = l - r * 192;
        wfc1[l] = f2bf((r < 720 && k < 180) ? fc1_w[r * 180 + k] : 0.f);
    } else if (idx < 948224) {                       // J4: wpw [768][768]
        int l = idx - 358400; int r = l / 768, k = l - r * 768;
        wpw[l] = f2bf((r < 720 && k < 720) ? pw_w[r * 720 + k] : 0.f);
    } else if (idx < 1144832) {                      // J5: wfc2 [256][768]
        int l = idx - 948224; int r = l / 768, k = l - r * 768;
        wfc2[l] = f2bf((r < 180 && k < 720) ? fc2_w[r * 720 + k] : 0.f);
    } else if (idx < 1145984) {                      // J6: dwt1 [9][128]
        int l = idx - 1144832; int c = l / 9, k = l - c * 9;
        dwt1[k * 128 + c] = (c < 90) ? cab_w1[c * 9 + k] : 0.f;
        if (k == 0) db1[c] = (c < 90) ? cab_b1[c] : 0.f;
    } else if (idx < 1147712) {                      // J7: dwt2 [9][192]
        int l = idx - 1145984; int c = l / 9, k = l - c * 9;
        dwt2[k * 192 + c] = (c < 180) ? cab_w3[c * 9 + k] : 0.f;
        if (k == 0) db2[c] = (c < 180) ? cab_b3[c] : 0.f;
    } else if (idx < 1154624) {                      // J8: dwt3 [9][768]
        int l = idx - 1147712; int c = l / 9, k = l - c * 9;
        dwt3[k * 768 + c] = (c < 720) ? dw_w[c * 9 + k] : 0.f;
        if (k == 0) db3[c] = (c < 720) ? dw_b[c] : 0.f;
    } else if (idx < 1155296) {                      // J9: qb672
        int l = idx - 1154624;
        float v = 0.f;
        if (l < 576) {
            int sub = l / 192, rem = l - sub * 192;
            int hh = rem >> 5, dd = rem & 31;
            if (dd < 30) v = qkv_b[sub * 180 + hh * 30 + dd];
        } else if (l < 666) {
            v = cab_b0[l - 576];
        }
        qb672[l] = v;
    } else if (idx < 1220832) {                      // J10: biasN [6][65536]
        int l = idx - 1155296;
        int r = rpi[l];
        #pragma unroll
        for (int h = 0; h < NHEADS; h++)
            biasN[((size_t)h << 16) + l] = rpb[r * NHEADS + h];
    }
}

// ---------------- LayerNorm -> bf16 xn (stride 192, pads 0) + bf16 copy of x ----------------
__global__ __launch_bounds__(256) void ln_kernel(
    const float* __restrict__ x, const float* __restrict__ g,
    const float* __restrict__ b, ushortw* __restrict__ out, ushortw* __restrict__ xb)
{
    int wid = threadIdx.x >> 6, lane = threadIdx.x & 63;
    int t = blockIdx.x * 4 + wid;
    size_t off = (size_t)t * CC;
    size_t off2 = (size_t)t * 192;
    bool has2 = lane < (CC - 128);
    float v0 = x[off + lane];
    float v1 = x[off + lane + 64];
    float v2 = has2 ? x[off + lane + 128] : 0.f;
    xb[off + lane] = f2bf(v0);
    xb[off + lane + 64] = f2bf(v1);
    if (has2) xb[off + lane + 128] = f2bf(v2);
    float s = warp_sum(v0 + v1 + v2);
    float mu = s * (1.f / CC);
    float d0 = v0 - mu, d1 = v1 - mu, d2 = has2 ? v2 - mu : 0.f;
    float var = warp_sum(d0*d0 + d1*d1 + d2*d2) * (1.f / CC);
    float rs = rsqrtf(var + 1e-5f);
    out[off2 + lane]      = f2bf(d0 * rs * g[lane]      + b[lane]);
    out[off2 + lane + 64] = f2bf(d1 * rs * g[lane + 64] + b[lane + 64]);
    out[off2 + lane + 128] = has2 ? f2bf(d2 * rs * g[lane + 128] + b[lane + 128]) : (ushortw)0;
}

// ---------------- bf16 MFMA GEMM: BK=32 dbuf + XOR swizzle + transposed-acc epilogue ----------
__global__ __launch_bounds__(256) void mgemm_kernel(
    const ushortw* __restrict__ A, const ushortw* __restrict__ Wt,
    const float* __restrict__ bias, void* __restrict__ Cout,
    int M, int N, int Kp, int ldc, int outbf, int zfill, int act, int residbf, int nN,
    const float* __restrict__ rowscale, const void* __restrict__ residv)
{
    __shared__ ushortw sA[2][128 * 32];
    __shared__ ushortw sB[2][128 * 32];
    int tid = threadIdx.x, lane = tid & 63, wid = tid >> 6;
    int total = (int)gridDim.x;
    int orig = blockIdx.x;
    int q = total >> 3, r = total & 7;
    int xcd = orig & 7, slot = orig >> 3;
    int wgid = (xcd < r ? xcd * (q + 1) : r * (q + 1) + (xcd - r) * q) + slot;
    int mp = wgid / nN, np = wgid - mp * nN;
    int m0 = mp << 7, n0 = np << 7;
    int wm = (wid >> 1) << 6, wn = (wid & 1) << 6;
    int lrow = lane & 15, kgrp = lane >> 4;

    f32x4 acc[4][4];
    #pragma unroll
    for (int i = 0; i < 4; i++)
        #pragma unroll
        for (int j = 0; j < 4; j++)
            #pragma unroll
            for (int rr = 0; rr < 4; rr++) acc[i][j][rr] = 0.f;

    int nk = Kp >> 5;
    #pragma unroll
    for (int qq = 0; qq < 2; qq++) {
        int seg = (wid << 1) + qq;                 // 0..7
        int row = (seg << 4) + (lane >> 2);        // 0..127
        int cg = (lane & 3) ^ (row & 3) ^ ((row >> 2) & 3);
        const ushortw* ga = A + (size_t)(m0 + row) * Kp + (cg << 3);
        __builtin_amdgcn_global_load_lds(
            (const __attribute__((address_space(1))) void*)ga,
            (__attribute__((address_space(3))) void*)&sA[0][seg << 9], 16, 0, 0);
        const ushortw* gb = Wt + (size_t)(n0 + row) * Kp + (cg << 3);
        __builtin_amdgcn_global_load_lds(
            (const __attribute__((address_space(1))) void*)gb,
            (__attribute__((address_space(3))) void*)&sB[0][seg << 9], 16, 0, 0);
    }
    __syncthreads();

    int cur = 0;
    for (int t = 0; t < nk; t++) {
        if (t + 1 < nk) {
            int kk2 = (t + 1) << 5;
            #pragma unroll
            for (int qq = 0; qq < 2; qq++) {
                int seg = (wid << 1) + qq;
                int row = (seg << 4) + (lane >> 2);
                int cg = (lane & 3) ^ (row & 3) ^ ((row >> 2) & 3);
                const ushortw* ga = A + (size_t)(m0 + row) * Kp + kk2 + (cg << 3);
                __builtin_amdgcn_global_load_lds(
                    (const __attribute__((address_space(1))) void*)ga,
                    (__attribute__((address_space(3))) void*)&sA[cur ^ 1][seg << 9], 16, 0, 0);
                const ushortw* gb = Wt + (size_t)(n0 + row) * Kp + kk2 + (cg << 3);
                __builtin_amdgcn_global_load_lds(
                    (const __attribute__((address_space(1))) void*)gb,
                    (__attribute__((address_space(3))) void*)&sB[cur ^ 1][seg << 9], 16, 0, 0);
            }
        }
        short8v a[4], b[4];
        #pragma unroll
        for (int i = 0; i < 4; i++) {
            int rr = wm + (i << 4) + lrow;
            int slot2 = kgrp ^ (rr & 3) ^ ((rr >> 2) & 3);
            a[i] = *reinterpret_cast<const short8v*>(&sA[cur][(rr << 5) + (slot2 << 3)]);
        }
        #pragma unroll
        for (int j = 0; j < 4; j++) {
            int rr = wn + (j << 4) + lrow;
            int slot2 = kgrp ^ (rr & 3) ^ ((rr >> 2) & 3);
            b[j] = *reinterpret_cast<const short8v*>(&sB[cur][(rr << 5) + (slot2 << 3)]);
        }
        #pragma unroll
        for (int i = 0; i < 4; i++)
            #pragma unroll
            for (int j = 0; j < 4; j++)
                acc[i][j] = __builtin_amdgcn_mfma_f32_16x16x32_bf16(b[j], a[i], acc[i][j], 0, 0, 0);
        __syncthreads();
        cur ^= 1;
    }
    // transposed-acc epilogue: row = token (lane), 4 consecutive cols per reg
    #pragma unroll
    for (int i = 0; i < 4; i++) {
        int row = m0 + wm + (i << 4) + lrow;
        float rsv = rowscale ? rowscale[row] : 1.f;
        #pragma unroll
        for (int j = 0; j < 4; j++) {
            int colb = n0 + wn + (j << 4) + (kgrp << 2);
            if (colb < N) {
                float4 bi4 = *reinterpret_cast<const float4*>(bias + colb);
                float vv[4];
                vv[0] = acc[i][j][0]; vv[1] = acc[i][j][1];
                vv[2] = acc[i][j][2]; vv[3] = acc[i][j][3];
                if (rowscale) {
                    vv[0] *= rsv; vv[1] *= rsv; vv[2] *= rsv; vv[3] *= rsv;
                }
                vv[0] += bi4.x; vv[1] += bi4.y; vv[2] += bi4.z; vv[3] += bi4.w;
                if (act == 1) {
                    vv[0] = gelu_exact(vv[0]); vv[1] = gelu_exact(vv[1]);
                    vv[2] = gelu_exact(vv[2]); vv[3] = gelu_exact(vv[3]);
                } else if (act == 2) {
                    vv[0] = fmaxf(vv[0], 0.f); vv[1] = fmaxf(vv[1], 0.f);
                    vv[2] = fmaxf(vv[2], 0.f); vv[3] = fmaxf(vv[3], 0.f);
                }
                if (residv) {
                    if (residbf) {
                        short4v rv = *reinterpret_cast<const short4v*>(
                            (const ushortw*)residv + (size_t)row * N + colb);
                        vv[0] += bf2f((ushortw)rv[0]); vv[1] += bf2f((ushortw)rv[1]);
                        vv[2] += bf2f((ushortw)rv[2]); vv[3] += bf2f((ushortw)rv[3]);
                    } else {
                        float4 rv = *reinterpret_cast<const float4*>(
                            (const float*)residv + (size_t)row * N + colb);
                        vv[0] += rv.x; vv[1] += rv.y; vv[2] += rv.z; vv[3] += rv.w;
                    }
                }
                if (outbf) {
                    short4v o;
                    o[0] = (short)f2bf(vv[0]); o[1] = (short)f2bf(vv[1]);
                    o[2] = (short)f2bf(vv[2]); o[3] = (short)f2bf(vv[3]);
                    *reinterpret_cast<short4v*>((ushortw*)Cout + (size_t)row * ldc + colb) = o;
                } else {
                    float4 o = make_float4(vv[0], vv[1], vv[2], vv[3]);
                    *reinterpret_cast<float4*>((float*)Cout + (size_t)row * ldc + colb) = o;
                }
            } else if (zfill && colb < ldc) {
                if (outbf) {
                    short4v o; o[0] = 0; o[1] = 0; o[2] = 0; o[3] = 0;
                    *reinterpret_cast<short4v*>((ushortw*)Cout + (size_t)row * ldc + colb) = o;
                } else {
                    *reinterpret_cast<float4*>((float*)Cout + (size_t)row * ldc + colb) =
                        make_float4(0.f, 0.f, 0.f, 0.f);
                }
            }
        }
    }
}

// ---------------- MFMA window attention (swapped QK^T): block = (img, win, head) ----------------
// r18 config + strip loop unrolled x2 (compiler may overlap strip i+1 QK with strip i PV;
// same-wave DS ordering guarantees Pw correctness).
__global__ __launch_bounds__(256, 3) void attn_mfma_kernel(
    const ushortw* __restrict__ qkvP, const float* __restrict__ biasN,
    ushortw* __restrict__ out)
{
    __shared__ ushortw Vc[32 * 33 * 8];      // 16896 B
    __shared__ ushortw Kc[256 * 32];         // 16384 B
    __shared__ ushortw Pl[4][2048];          // 16384 B
    const float SCALE = 0.18257418583505536f;   // 30^-0.5
    int blk = blockIdx.x;
    int img = blk / 384;
    int rem = blk - img * 384;
    int win = rem / NHEADS;
    int h = rem - win * NHEADS;
    int base = img * IMG + (win >> 3) * WSZ * WW + (win & 7) * WSZ;
    int tid = threadIdx.x;
    int lane = tid & 63, w = tid >> 6;
    int a15 = lane & 15, kg = lane >> 4;

    {
        int j = tid;
        int g = base + (j >> 4) * WW + (j & 15);
        const ushortw* vp = qkvP + (size_t)g * QKVSTR + 384 + h * 32;
        short8v c0 = *reinterpret_cast<const short8v*>(vp);
        short8v c1 = *reinterpret_cast<const short8v*>(vp + 8);
        short8v c2 = *reinterpret_cast<const short8v*>(vp + 16);
        short8v c3 = *reinterpret_cast<const short8v*>(vp + 24);
        int bo = (j >> 3) * 264 + (j & 7);
        #pragma unroll
        for (int e = 0; e < 8; e++)  Vc[bo + (e) * 8]      = (ushortw)c0[e];
        #pragma unroll
        for (int e = 0; e < 8; e++)  Vc[bo + (8 + e) * 8]  = (ushortw)c1[e];
        #pragma unroll
        for (int e = 0; e < 8; e++)  Vc[bo + (16 + e) * 8] = (ushortw)c2[e];
        #pragma unroll
        for (int e = 0; e < 8; e++)  Vc[bo + (24 + e) * 8] = (ushortw)c3[e];
        const ushortw* kp = qkvP + (size_t)g * QKVSTR + 192 + h * 32;
        short8v k0 = *reinterpret_cast<const short8v*>(kp);
        short8v k1 = *reinterpret_cast<const short8v*>(kp + 8);
        short8v k2 = *reinterpret_cast<const short8v*>(kp + 16);
        short8v k3 = *reinterpret_cast<const short8v*>(kp + 24);
        short8v* krow = reinterpret_cast<short8v*>(&Kc[j * 32]);
        int jsw = (j >> 1) & 3;
        krow[0 ^ jsw] = k0; krow[1 ^ jsw] = k1; krow[2 ^ jsw] = k2; krow[3 ^ jsw] = k3;
    }
    __syncthreads();

    ushortw* Pw = &Pl[w][0];
    int xsw = (a15 & 7) << 2;                // P dword-XOR per q-row
    f32x4 zf = {0.f, 0.f, 0.f, 0.f};
    #pragma unroll 2
    for (int si = 0; si < 4; si++) {
        int strip = (w << 2) + si;
        short8v qf = *reinterpret_cast<const short8v*>(
            qkvP + (size_t)(base + strip * WW + a15) * QKVSTR + h * 32 + (kg << 3));
        float psum = 0.f;
        f32x4 o0 = zf, o1 = zf;
        const float* brow = biasN + ((size_t)h << 16) + (size_t)((strip << 4) + a15) * 256;
        #pragma unroll
        for (int half = 0; half < 2; half++) {
            f32x4 s[8];
            __builtin_amdgcn_s_setprio(1);
            #pragma unroll
            for (int j8 = 0; j8 < 8; j8++) {
                int jt = (half << 3) + j8;
                int row = (jt << 4) + a15;
                short8v ka = reinterpret_cast<const short8v*>(&Kc[row * 32])[kg ^ ((row >> 1) & 3)];
                s[j8] = __builtin_amdgcn_mfma_f32_16x16x32_bf16(ka, qf, zf, 0, 0, 0);
            }
            __builtin_amdgcn_s_setprio(0);
            #pragma unroll
            for (int j8 = 0; j8 < 8; j8++) {
                int jt = (half << 3) + j8;
                float4 b4 = *reinterpret_cast<const float4*>(brow + (jt << 4) + (kg << 2));
                float p0 = __expf(fmaf(s[j8][0], SCALE, b4.x));
                float p1 = __expf(fmaf(s[j8][1], SCALE, b4.y));
                float p2 = __expf(fmaf(s[j8][2], SCALE, b4.z));
                float p3 = __expf(fmaf(s[j8][3], SCALE, b4.w));
                psum += (p0 + p1) + (p2 + p3);
                unsigned int u0, u1;
                asm("v_cvt_pk_bf16_f32 %0, %1, %2" : "=v"(u0) : "v"(p0), "v"(p1));
                asm("v_cvt_pk_bf16_f32 %0, %1, %2" : "=v"(u1) : "v"(p2), "v"(p3));
                int dw0 = ((j8 << 3) + (kg << 1)) ^ xsw;
                unsigned long long pk64 = (unsigned long long)u0 | ((unsigned long long)u1 << 32);
                *reinterpret_cast<unsigned long long*>(&Pw[(a15 << 7) + (dw0 << 1)]) = pk64;
            }
            __builtin_amdgcn_s_setprio(1);
            #pragma unroll
            for (int ks4 = 0; ks4 < 4; ks4++) {
                int dwr = ((ks4 << 4) + (kg << 2)) ^ xsw;
                short8v pa = *reinterpret_cast<const short8v*>(&Pw[(a15 << 7) + (dwr << 1)]);
                int kc = (((half << 2) + ks4) << 2) + kg;
                short8v v0 = *reinterpret_cast<const short8v*>(&Vc[(kc * 33 + a15) * 8]);
                short8v v1 = *reinterpret_cast<const short8v*>(&Vc[(kc * 33 + 16 + a15) * 8]);
                o0 = __builtin_amdgcn_mfma_f32_16x16x32_bf16(pa, v0, o0, 0, 0, 0);
                o1 = __builtin_amdgcn_mfma_f32_16x16x32_bf16(pa, v1, o1, 0, 0, 0);
            }
            __builtin_amdgcn_s_setprio(0);
        }
        psum += __shfl_xor(psum, 16);
        psum += __shfl_xor(psum, 32);
        #pragma unroll
        for (int r = 0; r < 4; r++) {
            float pt = __shfl(psum, (kg << 2) + r);
            float inv = 1.f / pt;
            int g = base + strip * WW + (kg << 2) + r;
            ushortw* orow = out + (size_t)g * 192 + h * HD;
            orow[a15] = f2bf(o0[r] * inv);
            if (a15 < 14) orow[16 + a15] = f2bf(o1[r] * inv);
        }
    }
    if (h == 0) {   // zero pad cols 180..191
        for (int idx2 = tid; idx2 < NTOKW * 12; idx2 += 256) {
            int j = idx2 / 12, d = idx2 - (idx2 / 12) * 12;
            int gj = base + (j >> 4) * WW + (j & 15);
            out[(size_t)gj * 192 + 180 + d] = 0;
        }
    }
}

// ---------------- register-tiled depthwise 3x3 conv: 4 pixels x 4 channels / thread ----------------
template<int CIN_S, int COP, int OSTR, int DIL, int ACT, int OUTBF>
__global__ __launch_bounds__(256) void dwconv4_kernel(
    const ushortw* __restrict__ in, const float* __restrict__ wt,
    const float* __restrict__ bias, void* __restrict__ out)
{
    constexpr int NC4 = COP >> 2;
    constexpr int NX = 4 + 2 * DIL;
    int idx = blockIdx.x * 256 + threadIdx.x;
    int c4 = idx % NC4;
    int quad = idx / NC4;
    int c = c4 << 2;
    int pix0 = quad << 2;
    int p = pix0 & (IMG - 1);
    int imgbase = pix0 - p;
    int px0 = p & (WW - 1), py = p >> 7;

    float4 w9[9];
    #pragma unroll
    for (int t = 0; t < 9; t++)
        w9[t] = *reinterpret_cast<const float4*>(wt + t * COP + c);
    float4 bi4 = *reinterpret_cast<const float4*>(bias + c);
    float acc[4][4];
    #pragma unroll
    for (int i = 0; i < 4; i++) {
        acc[i][0] = bi4.x; acc[i][1] = bi4.y; acc[i][2] = bi4.z; acc[i][3] = bi4.w;
    }
    #pragma unroll
    for (int ky = 0; ky < 3; ky++) {
        int iy = py + (ky - 1) * DIL;
        if (iy < 0 || iy >= HH) continue;
        const ushortw* rowp = in + (size_t)(imgbase + (iy << 7)) * CIN_S + c;
        #pragma unroll
        for (int xx = 0; xx < NX; xx++) {
            int ix = px0 + xx - DIL;
            if (ix < 0 || ix >= WW) continue;
            short4v v = *reinterpret_cast<const short4v*>(rowp + (size_t)ix * CIN_S);
            float f0 = bf2f((ushortw)v[0]);
            float f1 = bf2f((ushortw)v[1]);
            float f2 = bf2f((ushortw)v[2]);
            float f3 = bf2f((ushortw)v[3]);
            #pragma unroll
            for (int kx = 0; kx < 3; kx++) {
                int i = xx - DIL * kx;
                if (i < 0 || i > 3) continue;
                float4 wv = w9[ky * 3 + kx];
                acc[i][0] = fmaf(f0, wv.x, acc[i][0]);
                acc[i][1] = fmaf(f1, wv.y, acc[i][1]);
                acc[i][2] = fmaf(f2, wv.z, acc[i][2]);
                acc[i][3] = fmaf(f3, wv.w, acc[i][3]);
            }
        }
    }
    if (COP != OSTR && c >= OSTR) return;
    #pragma unroll
    for (int i = 0; i < 4; i++) {
        #pragma unroll
        for (int e = 0; e < 4; e++) {
            float v = acc[i][e];
            if (ACT == 1) v = gelu_exact(v);
            else if (ACT == 2) v = fmaxf(v, 0.f);
            acc[i][e] = v;
        }
        if (OUTBF) {
            short4v o;
            o[0] = (short)f2bf(acc[i][0]); o[1] = (short)f2bf(acc[i][1]);
            o[2] = (short)f2bf(acc[i][2]); o[3] = (short)f2bf(acc[i][3]);
            *reinterpret_cast<short4v*>((ushortw*)out + (size_t)(pix0 + i) * OSTR + c) = o;
        } else {
            float4 o = make_float4(acc[i][0], acc[i][1], acc[i][2], acc[i][3]);
            *reinterpret_cast<float4*>((float*)out + (size_t)(pix0 + i) * OSTR + c) = o;
        }
    }
}

// ---------------- GAP partial sums over bf16 y4 (128-pixel chunks, 512 blocks) ----------------
__global__ void gap_kernel(const ushortw* __restrict__ y, float* __restrict__ part)
{
    int blk = blockIdx.x;              // 0..511
    int b = blk >> 7, chunk = blk & 127;
    int c = threadIdx.x;
    if (c >= CC) return;
    size_t basep = ((size_t)b * IMG + (size_t)chunk * 128) * CC;
    float s = 0.f;
    for (int p = 0; p < 128; p++) s += bf2f(y[basep + (size_t)p * CC + c]);
    part[((size_t)b * 128 + chunk) * CC + c] = s;
}

// ---------------- channel attention (tiny) ----------------
__global__ void ca_kernel(const float* __restrict__ part,
                          const float* __restrict__ w1, const float* __restrict__ b1,
                          const float* __restrict__ w2, const float* __restrict__ b2,
                          float* __restrict__ ca)
{
    __shared__ float gap[BB * CC];
    __shared__ float s1[BB * 6];
    int tid = threadIdx.x;
    for (int idx = tid; idx < BB * CC; idx += 256) {
        int b = idx / CC, c = idx % CC;
        float s = 0.f;
        for (int ch = 0; ch < 128; ch++) s += part[((size_t)b * 128 + ch) * CC + c];
        gap[idx] = s * (1.f / IMG);
    }
    __syncthreads();
    if (tid < BB * 6) {
        int b = tid / 6, cs = tid % 6;
        float s = 0.f;
        for (int c = 0; c < CC; c++) s += w1[cs * CC + c] * gap[b * CC + c];
        s1[tid] = fmaxf(s + b1[cs], 0.f);
    }
    __syncthreads();
    for (int idx = tid; idx < BB * CC; idx += 256) {
        int b = idx / CC, c = idx % CC;
        float s = b2[c];
        #pragma unroll
        for (int cs = 0; cs < 6; cs++) s += w2[c * 6 + cs] * s1[b * 6 + cs];
        ca[idx] = 1.f / (1.f + __expf(-s));
    }
}

// ---------------- x1(bf16) += 0.01*y4*ca; LN2 -> bf16 xn2 (stride 192) ----------------
__global__ __launch_bounds__(256) void resid_ln_kernel(
    ushortw* __restrict__ x1, const ushortw* __restrict__ y4, const float* __restrict__ ca,
    const float* __restrict__ g, const float* __restrict__ bb,
    ushortw* __restrict__ xn2)
{
    int wid = threadIdx.x >> 6, lane = threadIdx.x & 63;
    int t = blockIdx.x * 4 + wid;
    int b = t >> 14;
    size_t off = (size_t)t * CC;
    size_t off2 = (size_t)t * 192;
    bool has2 = lane < (CC - 128);
    float v0 = bf2f(x1[off+lane])    + 0.01f * bf2f(y4[off+lane])    * ca[b*CC + lane];
    float v1 = bf2f(x1[off+lane+64]) + 0.01f * bf2f(y4[off+lane+64]) * ca[b*CC + lane+64];
    float v2 = 0.f;
    if (has2) v2 = bf2f(x1[off+lane+128]) + 0.01f * bf2f(y4[off+lane+128]) * ca[b*CC + lane+128];
    x1[off+lane] = f2bf(v0); x1[off+lane+64] = f2bf(v1);
    if (has2) x1[off+lane+128] = f2bf(v2);
    float s = warp_sum(v0 + v1 + v2);
    float mu = s * (1.f / CC);
    float d0 = v0-mu, d1 = v1-mu, d2 = has2 ? v2-mu : 0.f;
    float var = warp_sum(d0*d0 + d1*d1 + d2*d2) * (1.f / CC);
    float rs = rsqrtf(var + 1e-5f);
    xn2[off2+lane]      = f2bf(d0 * rs * g[lane]      + bb[lane]);
    xn2[off2+lane+64]   = f2bf(d1 * rs * g[lane+64]   + bb[lane+64]);
    xn2[off2+lane+128]  = has2 ? f2bf(d2 * rs * g[lane+128] + bb[lane+128]) : (ushortw)0;
}

// ---------------- max/mean over channels per pixel (bf16 h3, stride 768, 720 cols) ----------------
__global__ __launch_bounds__(256) void mpap_kernel(
    const ushortw* __restrict__ h, float* __restrict__ mp, float* __restrict__ ap)
{
    int wid = threadIdx.x >> 6, lane = threadIdx.x & 63;
    int p = blockIdx.x * 4 + wid;
    const ushortw* row = h + (size_t)p * 768;
    float mx = -1e30f, s = 0.f;
    #pragma unroll
    for (int it = 0; it < 3; it++) {
        int j = (lane << 2) + it * 256;
        if (j < HID) {
            short4v v = *reinterpret_cast<const short4v*>(row + j);
            float f0 = bf2f((ushortw)v[0]), f1 = bf2f((ushortw)v[1]);
            float f2 = bf2f((ushortw)v[2]), f3 = bf2f((ushortw)v[3]);
            mx = fmaxf(mx, fmaxf(fmaxf(f0, f1), fmaxf(f2, f3)));
            s += (f0 + f1) + (f2 + f3);
        }
    }
    mx = warp_max(mx); s = warp_sum(s);
    if (lane == 0) { mp[p] = mx; ap[p] = s * (1.f / HID); }
}

// ---------------- 7x7 spatial-attention conv + sigmoid, LDS-tiled (16x16 tile + 22x22 halo) ----
__global__ __launch_bounds__(256) void saconv_kernel(
    const float* __restrict__ mp, const float* __restrict__ ap,
    const float* __restrict__ w, float* __restrict__ sa)
{
    __shared__ float smp[22][22];
    __shared__ float sap[22][22];
    int t = blockIdx.x;               // 0..127 (2 images x 64 tiles)
    int img = t >> 6;
    int ty = (t >> 3) & 7, tx = t & 7;
    int y0 = ty * 16 - 3, x0 = tx * 16 - 3;
    int tid = threadIdx.x;
    for (int i = tid; i < 22 * 22; i += 256) {
        int ly = i / 22, lx = i - ly * 22;
        int gy = y0 + ly, gx = x0 + lx;
        bool ok = (gy >= 0 && gy < HH && gx >= 0 && gx < WW);
        int pid = img * IMG + gy * WW + gx;
        smp[ly][lx] = ok ? mp[pid] : 0.f;
        sap[ly][lx] = ok ? ap[pid] : 0.f;
    }
    __syncthreads();
    int py = tid >> 4, px = tid & 15;
    float acc = 0.f;
    #pragma unroll
    for (int ky = 0; ky < 7; ky++) {
        #pragma unroll
        for (int kx = 0; kx < 7; kx++) {
            acc += smp[py + ky][px + kx] * w[ky * 7 + kx]
                 + sap[py + ky][px + kx] * w[49 + ky * 7 + kx];
        }
    }
    int p = img * IMG + (ty * 16 + py) * WW + (tx * 16 + px);
    sa[p] = 1.f / (1.f + __expf(-acc));
}

extern "C" void kernel_launch(void* const* d_in, const int* in_sizes, int n_in,
                              void* d_out, int out_size, void* d_ws, size_t ws_size,
                              hipStream_t stream)
{
    const float* x      = (const float*)d_in[0];
    const int*   rpi    = (const int*)d_in[3];
    const float* n1g    = (const float*)d_in[4];
    const float* n1b    = (const float*)d_in[5];
    const float* rpb    = (const float*)d_in[6];
    const float* qkv_w  = (const float*)d_in[7];
    const float* qkv_b  = (const float*)d_in[8];
    const float* proj_w = (const float*)d_in[9];
    const float* proj_b = (const float*)d_in[10];
    const float* cab_w0 = (const float*)d_in[11];
    const float* cab_b0 = (const float*)d_in[12];
    const float* cab_w1 = (const float*)d_in[13];
    const float* cab_b1 = (const float*)d_in[14];
    const float* cab_w2 = (const float*)d_in[15];
    const float* cab_b2 = (const float*)d_in[16];
    const float* cab_w3 = (const float*)d_in[17];
    const float* cab_b3 = (const float*)d_in[18];
    const float* ca_w1  = (const float*)d_in[19];
    const float* ca_b1  = (const float*)d_in[20];
    const float* ca_w2  = (const float*)d_in[21];
    const float* ca_b2  = (const float*)d_in[22];
    const float* n2g    = (const float*)d_in[23];
    const float* n2b    = (const float*)d_in[24];
    const float* fc1_w  = (const float*)d_in[25];
    const float* fc1_b  = (const float*)d_in[26];
    const float* dw_w   = (const float*)d_in[27];
    const float* dw_b   = (const float*)d_in[28];
    const float* pw_w   = (const float*)d_in[29];
    const float* pw_b   = (const float*)d_in[30];
    const float* sa_w   = (const float*)d_in[31];
    const float* fc2_w  = (const float*)d_in[32];
    const float* fc2_b  = (const float*)d_in[33];
    float* outp = (float*)d_out;
    (void)in_sizes; (void)n_in; (void)out_size; (void)ws_size;

    char* ws = (char*)d_ws;
    const size_t S0 = (size_t)NTOK * 192 * 2;            // xnb -> xn2b
    const size_t S1 = (size_t)NTOK * QKVSTR * 2 + 256;   // qkvP -> h1(half) -> h3(half)
    const size_t S2 = (size_t)NTOK * 192 * 2;            // attnbb -> y3b
    const size_t S3 = (size_t)NTOK * 180 * 2;            // x1b bf16
    const size_t S4 = (size_t)NTOK * 128 * 2;            // y2b ; h2(half) spans S4+S5
    const size_t S5 = (size_t)NTOK * 180 * 4;            // xb -> y4 bf16 (region kept for h2 span)
    char* pA0 = ws;
    char* pA1 = pA0 + S0;
    char* pA2 = pA1 + S1;
    char* pA3 = pA2 + S2;
    char* pA4 = pA3 + S3;
    char* pA5 = pA4 + S4;
    char* tail = pA5 + S5;

    ushortw* xnb    = (ushortw*)pA0;           // [NTOK][192]
    ushortw* xn2b   = (ushortw*)pA0;
    ushortw* qkvP   = (ushortw*)pA1;           // [NTOK][672] (cols 576.. = cab0 out)
    ushortw* h1     = (ushortw*)pA1;           // [HALFTOK][720]
    ushortw* h3     = (ushortw*)pA1;           // [HALFTOK][768]
    ushortw* attnbb = (ushortw*)pA2;           // [NTOK][192]
    ushortw* y3b    = (ushortw*)pA2;           // [NTOK][192]
    ushortw* x1b    = (ushortw*)pA3;           // [NTOK][180] bf16
    ushortw* y2b    = (ushortw*)pA4;           // [NTOK][128]
    ushortw* h2     = (ushortw*)pA4;           // [HALFTOK][768] spans S4+S5
    ushortw* xb     = (ushortw*)pA5;           // [NTOK][180] bf16 (x copy; dead after proj)
    ushortw* y4     = (ushortw*)pA5;           // [NTOK][180] bf16 (written by dw2, after proj)

    // bf16 gemm weights
    ushortw* wqkvc = (ushortw*)tail;                        // 672 x 192
    ushortw* wproj = wqkvc + 672 * 192;                     // 256 x 192
    ushortw* wcab2 = wproj + 256 * 192;                     // 256 x 128
    ushortw* wfc1  = wcab2 + 256 * 128;                     // 768 x 192
    ushortw* wpw   = wfc1  + 768 * 192;                     // 768 x 768
    ushortw* wfc2  = wpw   + 768 * 768;                     // 256 x 768
    char* tail2 = (char*)(wfc2 + 256 * 768);
    float* dwt1 = (float*)tail2;                 float* db1 = dwt1 + 9*128;
    float* dwt2 = db1 + 128;                     float* db2 = dwt2 + 9*192;
    float* dwt3 = db2 + 192;                     float* db3 = dwt3 + 9*768;
    float* qb672 = db3 + 768;
    char* tail3 = (char*)(qb672 + 672);
    float* biasN = (float*)tail3;                           // 6*65536 fp32
    float* part  = (float*)(tail3 + 1572864);               // 4*128*180 fp32
    float* cabuf = (float*)(tail3 + 1572864 + 393216);
    float* mp    = (float*)(tail3 + 1572864 + 393216 + 4096);
    float* ap    = (float*)(tail3 + 1572864 + 393216 + 4096 + (size_t)HALFTOK * 4);
    float* sab   = (float*)(tail3 + 1572864 + 393216 + 4096 + 2*(size_t)HALFTOK * 4);

    auto gemm = [&](const ushortw* A, const ushortw* Wt, const float* bi, void* Cp,
                    int M, int N, int Kp, int ldc, int outbf, int zfill, int act, int residbf,
                    const float* rs, const void* resid) {
        int nM = M >> 7, nN = (N + 127) >> 7;
        mgemm_kernel<<<dim3(nM * nN), dim3(256), 0, stream>>>(
            A, Wt, bi, Cp, M, N, Kp, ldc, outbf, zfill, act, residbf, nN, rs, resid);
    };

    // 0) all weight/bias prep in one launch
    prep_kernel<<<dim3((1220832 + 255) / 256), dim3(256), 0, stream>>>(
        qkv_w, proj_w, cab_w0, cab_b0, cab_w2, fc1_w, pw_w, fc2_w,
        cab_w1, cab_b1, cab_w3, cab_b3, dw_w, dw_b, qkv_b, rpi, rpb,
        wqkvc, wproj, wcab2, wfc1, wpw, wfc2,
        dwt1, db1, dwt2, db2, dwt3, db3, qb672, biasN);

    // 1) LN1 -> bf16 xnb (+ bf16 copy of x for proj residual)
    ln_kernel<<<dim3(NTOK / 4), dim3(256), 0, stream>>>(x, n1g, n1b, xnb, xb);
    // 2) merged qkv+cab0 GEMM -> qkvP[NTOK][672]; then attention + CAB dwconv1
    gemm(xnb, wqkvc, qb672, qkvP, NTOK, 672, 192, QKVSTR, 1, 0, 0, 0, nullptr, nullptr);
    attn_mfma_kernel<<<dim3(BB * 64 * NHEADS), dim3(256), 0, stream>>>(qkvP, biasN, attnbb);
    dwconv4_kernel<672, 128, 128, 1, 1, 1><<<dim3(NTOK / 4 * 32 / 256), dim3(256), 0, stream>>>(
        qkvP + 576, dwt1, db1, y2b);
    // 3) proj with bf16 residual xb -> x1b (bf16)
    gemm(attnbb, wproj, proj_b, x1b, NTOK, 180, 192, 180, 1, 0, 0, 1, nullptr, xb);
    // 4) CAB part 2 (y4 overwrites xb region -- xb dead after proj)
    gemm(y2b, wcab2, cab_b2, y3b, NTOK, 180, 128, 192, 1, 1, 0, 0, nullptr, nullptr);
    dwconv4_kernel<192, 192, 180, 2, 0, 1><<<dim3(NTOK / 4 * 48 / 256), dim3(256), 0, stream>>>(
        y3b, dwt2, db2, y4);
    gap_kernel<<<dim3(BB * 128), dim3(192), 0, stream>>>(y4, part);
    ca_kernel<<<dim3(1), dim3(256), 0, stream>>>(part, ca_w1, ca_b1, ca_w2, ca_b2, cabuf);
    // 5) x1 += 0.01*y4*ca; LN2 -> bf16 xn2b
    resid_ln_kernel<<<dim3(NTOK / 4), dim3(256), 0, stream>>>(x1b, y4, cabuf, n2g, n2b, xn2b);
    // 6) FFN in two half-batches (2 images each)
    for (int half = 0; half < 2; half++) {
        size_t toff = (size_t)half * HALFTOK;
        gemm(xn2b + toff * 192, wfc1, fc1_b, h1, HALFTOK, 720, 192, 720, 1, 0, 1, 0, nullptr, nullptr);
        dwconv4_kernel<720, 768, 768, 1, 2, 1><<<dim3(HALFTOK / 4 * 192 / 256), dim3(256), 0, stream>>>(
            h1, dwt3, db3, h2);
        gemm(h2, wpw, pw_b, h3, HALFTOK, 720, 768, 768, 1, 1, 2, 0, nullptr, nullptr);
        mpap_kernel<<<dim3(HALFTOK / 4), dim3(256), 0, stream>>>(h3, mp, ap);
        saconv_kernel<<<dim3(HALFTOK / 256), dim3(256), 0, stream>>>(mp, ap, sa_w, sab);
        gemm(h3, wfc2, fc2_b, outp + toff * 180, HALFTOK, 180, 768, 180, 0, 0, 0, 1,
             sab, x1b + toff * 180);
    }
}

// Round 22
// 619.880 us; speedup vs baseline: 1.1019x; 1.1019x over previous
//
#include <hip/hip_runtime.h>
#include <math.h>

#define HH 128
#define WW 128
#define CC 180
#define BB 4
#define IMG (HH*WW)          // 16384 tokens per image
#define NTOK (BB*IMG)        // 65536
#define HALFTOK (2*IMG)      // 32768
#define NHEADS 6
#define HD 30
#define WSZ 16
#define NTOKW (WSZ*WSZ)      // 256
#define HID 720
#define QKVSTR 672           // merged row: q/k/v (3x192) + cab0 (96)

typedef __attribute__((ext_vector_type(8))) short short8v;
typedef __attribute__((ext_vector_type(4))) short short4v;
typedef __attribute__((ext_vector_type(4))) float f32x4;
typedef unsigned short ushortw;

__device__ __forceinline__ float warp_sum(float v) {
    #pragma unroll
    for (int o = 32; o > 0; o >>= 1) v += __shfl_xor(v, o);
    return v;
}
__device__ __forceinline__ float warp_max(float v) {
    #pragma unroll
    for (int o = 32; o > 0; o >>= 1) v = fmaxf(v, __shfl_xor(v, o));
    return v;
}
__device__ __forceinline__ float gelu_exact(float v) {
    return 0.5f * v * (1.f + erff(v * 0.70710678118654752f));
}
__device__ __forceinline__ ushortw f2bf(float f) {
    union { float f; unsigned int u; } c; c.f = f;
    unsigned int r = (c.u + 0x7FFFu + ((c.u >> 16) & 1u)) >> 16;
    return (ushortw)r;
}
__device__ __forceinline__ float bf2f(ushortw u) {
    union { unsigned int u; float f; } c; c.u = ((unsigned int)u) << 16; return c.f;
}

// ---------------- fused weight/bias prep (one launch) ----------------
__global__ __launch_bounds__(256) void prep_kernel(
    const float* __restrict__ qkv_w, const float* __restrict__ proj_w,
    const float* __restrict__ cab_w0, const float* __restrict__ cab_b0,
    const float* __restrict__ cab_w2,
    const float* __restrict__ fc1_w, const float* __restrict__ pw_w,
    const float* __restrict__ fc2_w,
    const float* __restrict__ cab_w1, const float* __restrict__ cab_b1,
    const float* __restrict__ cab_w3, const float* __restrict__ cab_b3,
    const float* __restrict__ dw_w, const float* __restrict__ dw_b,
    const float* __restrict__ qkv_b, const int* __restrict__ rpi,
    const float* __restrict__ rpb,
    ushortw* __restrict__ wqkvc, ushortw* __restrict__ wproj,
    ushortw* __restrict__ wcab2,
    ushortw* __restrict__ wfc1, ushortw* __restrict__ wpw, ushortw* __restrict__ wfc2,
    float* __restrict__ dwt1, float* __restrict__ db1,
    float* __restrict__ dwt2, float* __restrict__ db2,
    float* __restrict__ dwt3, float* __restrict__ db3,
    float* __restrict__ qb672, float* __restrict__ biasN)
{
    int idx = blockIdx.x * 256 + threadIdx.x;
    if (idx < 129024) {                              // J0: wqkvc [672][192]
        int r = idx / 192, k = idx - r * 192;
        float v = 0.f;
        if (r < 576) {
            int sub = r / 192, rem = r - sub * 192;
            int hh = rem >> 5, dd = rem & 31;
            if (dd < 30 && k < 180) v = qkv_w[(sub * 180 + hh * 30 + dd) * 180 + k];
        } else if (r < 666) {
            if (k < 180) v = cab_w0[(r - 576) * 180 + k];
        }
        wqkvc[idx] = f2bf(v);
    } else if (idx < 178176) {                       // J1: wproj [256][192]
        int l = idx - 129024; int r = l / 192, k = l - r * 192;
        wproj[l] = f2bf((r < 180 && k < 180) ? proj_w[r * 180 + k] : 0.f);
    } else if (idx < 210944) {                       // J2: wcab2 [256][128]
        int l = idx - 178176; int r = l / 128, k = l - r * 128;
        wcab2[l] = f2bf((r < 180 && k < 90) ? cab_w2[r * 90 + k] : 0.f);
    } else if (idx < 358400) {                       // J3: wfc1 [768][192]
        int l = idx - 210944; int r = l / 192, k = l - r * 192;
        wfc1[l] = f2bf((r < 720 && k < 180) ? fc1_w[r * 180 + k] : 0.f);
    } else if (idx < 948224) {                       // J4: wpw [768][768]
        int l = idx - 358400; int r = l / 768, k = l - r * 768;
        wpw[l] = f2bf((r < 720 && k < 720) ? pw_w[r * 720 + k] : 0.f);
    } else if (idx < 1144832) {                      // J5: wfc2 [256][768]
        int l = idx - 948224; int r = l / 768, k = l - r * 768;
        wfc2[l] = f2bf((r < 180 && k < 720) ? fc2_w[r * 720 + k] : 0.f);
    } else if (idx < 1145984) {                      // J6: dwt1 [9][128]
        int l = idx - 1144832; int c = l / 9, k = l - c * 9;
        dwt1[k * 128 + c] = (c < 90) ? cab_w1[c * 9 + k] : 0.f;
        if (k == 0) db1[c] = (c < 90) ? cab_b1[c] : 0.f;
    } else if (idx < 1147712) {                      // J7: dwt2 [9][192]
        int l = idx - 1145984; int c = l / 9, k = l - c * 9;
        dwt2[k * 192 + c] = (c < 180) ? cab_w3[c * 9 + k] : 0.f;
        if (k == 0) db2[c] = (c < 180) ? cab_b3[c] : 0.f;
    } else if (idx < 1154624) {                      // J8: dwt3 [9][768]
        int l = idx - 1147712; int c = l / 9, k = l - c * 9;
        dwt3[k * 768 + c] = (c < 720) ? dw_w[c * 9 + k] : 0.f;
        if (k == 0) db3[c] = (c < 720) ? dw_b[c] : 0.f;
    } else if (idx < 1155296) {                      // J9: qb672
        int l = idx - 1154624;
        float v = 0.f;
        if (l < 576) {
            int sub = l / 192, rem = l - sub * 192;
            int hh = rem >> 5, dd = rem & 31;
            if (dd < 30) v = qkv_b[sub * 180 + hh * 30 + dd];
        } else if (l < 666) {
            v = cab_b0[l - 576];
        }
        qb672[l] = v;
    } else if (idx < 1220832) {                      // J10: biasN [6][65536]
        int l = idx - 1155296;
        int r = rpi[l];
        #pragma unroll
        for (int h = 0; h < NHEADS; h++)
            biasN[((size_t)h << 16) + l] = rpb[r * NHEADS + h];
    }
}

// ---------------- LayerNorm -> bf16 xn (stride 192, pads 0) + bf16 copy of x ----------------
__global__ __launch_bounds__(256) void ln_kernel(
    const float* __restrict__ x, const float* __restrict__ g,
    const float* __restrict__ b, ushortw* __restrict__ out, ushortw* __restrict__ xb)
{
    int wid = threadIdx.x >> 6, lane = threadIdx.x & 63;
    int t = blockIdx.x * 4 + wid;
    size_t off = (size_t)t * CC;
    size_t off2 = (size_t)t * 192;
    bool has2 = lane < (CC - 128);
    float v0 = x[off + lane];
    float v1 = x[off + lane + 64];
    float v2 = has2 ? x[off + lane + 128] : 0.f;
    xb[off + lane] = f2bf(v0);
    xb[off + lane + 64] = f2bf(v1);
    if (has2) xb[off + lane + 128] = f2bf(v2);
    float s = warp_sum(v0 + v1 + v2);
    float mu = s * (1.f / CC);
    float d0 = v0 - mu, d1 = v1 - mu, d2 = has2 ? v2 - mu : 0.f;
    float var = warp_sum(d0*d0 + d1*d1 + d2*d2) * (1.f / CC);
    float rs = rsqrtf(var + 1e-5f);
    out[off2 + lane]      = f2bf(d0 * rs * g[lane]      + b[lane]);
    out[off2 + lane + 64] = f2bf(d1 * rs * g[lane + 64] + b[lane + 64]);
    out[off2 + lane + 128] = has2 ? f2bf(d2 * rs * g[lane + 128] + b[lane + 128]) : (ushortw)0;
}

// ---------------- bf16 MFMA GEMM: BK=32 dbuf + XOR swizzle + transposed-acc epilogue ----------
__global__ __launch_bounds__(256) void mgemm_kernel(
    const ushortw* __restrict__ A, const ushortw* __restrict__ Wt,
    const float* __restrict__ bias, void* __restrict__ Cout,
    int M, int N, int Kp, int ldc, int outbf, int zfill, int act, int residbf, int nN,
    const float* __restrict__ rowscale, const void* __restrict__ residv)
{
    __shared__ ushortw sA[2][128 * 32];
    __shared__ ushortw sB[2][128 * 32];
    int tid = threadIdx.x, lane = tid & 63, wid = tid >> 6;
    int total = (int)gridDim.x;
    int orig = blockIdx.x;
    int q = total >> 3, r = total & 7;
    int xcd = orig & 7, slot = orig >> 3;
    int wgid = (xcd < r ? xcd * (q + 1) : r * (q + 1) + (xcd - r) * q) + slot;
    int mp = wgid / nN, np = wgid - mp * nN;
    int m0 = mp << 7, n0 = np << 7;
    int wm = (wid >> 1) << 6, wn = (wid & 1) << 6;
    int lrow = lane & 15, kgrp = lane >> 4;

    f32x4 acc[4][4];
    #pragma unroll
    for (int i = 0; i < 4; i++)
        #pragma unroll
        for (int j = 0; j < 4; j++)
            #pragma unroll
            for (int rr = 0; rr < 4; rr++) acc[i][j][rr] = 0.f;

    int nk = Kp >> 5;
    #pragma unroll
    for (int qq = 0; qq < 2; qq++) {
        int seg = (wid << 1) + qq;                 // 0..7
        int row = (seg << 4) + (lane >> 2);        // 0..127
        int cg = (lane & 3) ^ (row & 3) ^ ((row >> 2) & 3);
        const ushortw* ga = A + (size_t)(m0 + row) * Kp + (cg << 3);
        __builtin_amdgcn_global_load_lds(
            (const __attribute__((address_space(1))) void*)ga,
            (__attribute__((address_space(3))) void*)&sA[0][seg << 9], 16, 0, 0);
        const ushortw* gb = Wt + (size_t)(n0 + row) * Kp + (cg << 3);
        __builtin_amdgcn_global_load_lds(
            (const __attribute__((address_space(1))) void*)gb,
            (__attribute__((address_space(3))) void*)&sB[0][seg << 9], 16, 0, 0);
    }
    __syncthreads();

    int cur = 0;
    for (int t = 0; t < nk; t++) {
        if (t + 1 < nk) {
            int kk2 = (t + 1) << 5;
            #pragma unroll
            for (int qq = 0; qq < 2; qq++) {
                int seg = (wid << 1) + qq;
                int row = (seg << 4) + (lane >> 2);
                int cg = (lane & 3) ^ (row & 3) ^ ((row >> 2) & 3);
                const ushortw* ga = A + (size_t)(m0 + row) * Kp + kk2 + (cg << 3);
                __builtin_amdgcn_global_load_lds(
                    (const __attribute__((address_space(1))) void*)ga,
                    (__attribute__((address_space(3))) void*)&sA[cur ^ 1][seg << 9], 16, 0, 0);
                const ushortw* gb = Wt + (size_t)(n0 + row) * Kp + kk2 + (cg << 3);
                __builtin_amdgcn_global_load_lds(
                    (const __attribute__((address_space(1))) void*)gb,
                    (__attribute__((address_space(3))) void*)&sB[cur ^ 1][seg << 9], 16, 0, 0);
            }
        }
        short8v a[4], b[4];
        #pragma unroll
        for (int i = 0; i < 4; i++) {
            int rr = wm + (i << 4) + lrow;
            int slot2 = kgrp ^ (rr & 3) ^ ((rr >> 2) & 3);
            a[i] = *reinterpret_cast<const short8v*>(&sA[cur][(rr << 5) + (slot2 << 3)]);
        }
        #pragma unroll
        for (int j = 0; j < 4; j++) {
            int rr = wn + (j << 4) + lrow;
            int slot2 = kgrp ^ (rr & 3) ^ ((rr >> 2) & 3);
            b[j] = *reinterpret_cast<const short8v*>(&sB[cur][(rr << 5) + (slot2 << 3)]);
        }
        #pragma unroll
        for (int i = 0; i < 4; i++)
            #pragma unroll
            for (int j = 0; j < 4; j++)
                acc[i][j] = __builtin_amdgcn_mfma_f32_16x16x32_bf16(b[j], a[i], acc[i][j], 0, 0, 0);
        __syncthreads();
        cur ^= 1;
    }
    // transposed-acc epilogue: row = token (lane), 4 consecutive cols per reg
    #pragma unroll
    for (int i = 0; i < 4; i++) {
        int row = m0 + wm + (i << 4) + lrow;
        float rsv = rowscale ? rowscale[row] : 1.f;
        #pragma unroll
        for (int j = 0; j < 4; j++) {
            int colb = n0 + wn + (j << 4) + (kgrp << 2);
            if (colb < N) {
                float4 bi4 = *reinterpret_cast<const float4*>(bias + colb);
                float vv[4];
                vv[0] = acc[i][j][0]; vv[1] = acc[i][j][1];
                vv[2] = acc[i][j][2]; vv[3] = acc[i][j][3];
                if (rowscale) {
                    vv[0] *= rsv; vv[1] *= rsv; vv[2] *= rsv; vv[3] *= rsv;
                }
                vv[0] += bi4.x; vv[1] += bi4.y; vv[2] += bi4.z; vv[3] += bi4.w;
                if (act == 1) {
                    vv[0] = gelu_exact(vv[0]); vv[1] = gelu_exact(vv[1]);
                    vv[2] = gelu_exact(vv[2]); vv[3] = gelu_exact(vv[3]);
                } else if (act == 2) {
                    vv[0] = fmaxf(vv[0], 0.f); vv[1] = fmaxf(vv[1], 0.f);
                    vv[2] = fmaxf(vv[2], 0.f); vv[3] = fmaxf(vv[3], 0.f);
                }
                if (residv) {
                    if (residbf) {
                        short4v rv = *reinterpret_cast<const short4v*>(
                            (const ushortw*)residv + (size_t)row * N + colb);
                        vv[0] += bf2f((ushortw)rv[0]); vv[1] += bf2f((ushortw)rv[1]);
                        vv[2] += bf2f((ushortw)rv[2]); vv[3] += bf2f((ushortw)rv[3]);
                    } else {
                        float4 rv = *reinterpret_cast<const float4*>(
                            (const float*)residv + (size_t)row * N + colb);
                        vv[0] += rv.x; vv[1] += rv.y; vv[2] += rv.z; vv[3] += rv.w;
                    }
                }
                if (outbf) {
                    short4v o;
                    o[0] = (short)f2bf(vv[0]); o[1] = (short)f2bf(vv[1]);
                    o[2] = (short)f2bf(vv[2]); o[3] = (short)f2bf(vv[3]);
                    *reinterpret_cast<short4v*>((ushortw*)Cout + (size_t)row * ldc + colb) = o;
                } else {
                    float4 o = make_float4(vv[0], vv[1], vv[2], vv[3]);
                    *reinterpret_cast<float4*>((float*)Cout + (size_t)row * ldc + colb) = o;
                }
            } else if (zfill && colb < ldc) {
                if (outbf) {
                    short4v o; o[0] = 0; o[1] = 0; o[2] = 0; o[3] = 0;
                    *reinterpret_cast<short4v*>((ushortw*)Cout + (size_t)row * ldc + colb) = o;
                } else {
                    *reinterpret_cast<float4*>((float*)Cout + (size_t)row * ldc + colb) =
                        make_float4(0.f, 0.f, 0.f, 0.f);
                }
            }
        }
    }
}

// ---------------- MFMA window attention (swapped QK^T): block = (img, win, head) ----------------
// r18/r20-proven config: 4 waves, K in LDS with (row>>1)&3 XOR, strip loop unroll 1.
__global__ __launch_bounds__(256, 3) void attn_mfma_kernel(
    const ushortw* __restrict__ qkvP, const float* __restrict__ biasN,
    ushortw* __restrict__ out)
{
    __shared__ ushortw Vc[32 * 33 * 8];      // 16896 B
    __shared__ ushortw Kc[256 * 32];         // 16384 B
    __shared__ ushortw Pl[4][2048];          // 16384 B
    const float SCALE = 0.18257418583505536f;   // 30^-0.5
    int blk = blockIdx.x;
    int img = blk / 384;
    int rem = blk - img * 384;
    int win = rem / NHEADS;
    int h = rem - win * NHEADS;
    int base = img * IMG + (win >> 3) * WSZ * WW + (win & 7) * WSZ;
    int tid = threadIdx.x;
    int lane = tid & 63, w = tid >> 6;
    int a15 = lane & 15, kg = lane >> 4;

    {
        int j = tid;
        int g = base + (j >> 4) * WW + (j & 15);
        const ushortw* vp = qkvP + (size_t)g * QKVSTR + 384 + h * 32;
        short8v c0 = *reinterpret_cast<const short8v*>(vp);
        short8v c1 = *reinterpret_cast<const short8v*>(vp + 8);
        short8v c2 = *reinterpret_cast<const short8v*>(vp + 16);
        short8v c3 = *reinterpret_cast<const short8v*>(vp + 24);
        int bo = (j >> 3) * 264 + (j & 7);
        #pragma unroll
        for (int e = 0; e < 8; e++)  Vc[bo + (e) * 8]      = (ushortw)c0[e];
        #pragma unroll
        for (int e = 0; e < 8; e++)  Vc[bo + (8 + e) * 8]  = (ushortw)c1[e];
        #pragma unroll
        for (int e = 0; e < 8; e++)  Vc[bo + (16 + e) * 8] = (ushortw)c2[e];
        #pragma unroll
        for (int e = 0; e < 8; e++)  Vc[bo + (24 + e) * 8] = (ushortw)c3[e];
        const ushortw* kp = qkvP + (size_t)g * QKVSTR + 192 + h * 32;
        short8v k0 = *reinterpret_cast<const short8v*>(kp);
        short8v k1 = *reinterpret_cast<const short8v*>(kp + 8);
        short8v k2 = *reinterpret_cast<const short8v*>(kp + 16);
        short8v k3 = *reinterpret_cast<const short8v*>(kp + 24);
        short8v* krow = reinterpret_cast<short8v*>(&Kc[j * 32]);
        int jsw = (j >> 1) & 3;
        krow[0 ^ jsw] = k0; krow[1 ^ jsw] = k1; krow[2 ^ jsw] = k2; krow[3 ^ jsw] = k3;
    }
    __syncthreads();

    ushortw* Pw = &Pl[w][0];
    int xsw = (a15 & 7) << 2;                // P dword-XOR per q-row
    f32x4 zf = {0.f, 0.f, 0.f, 0.f};
    #pragma unroll 1
    for (int si = 0; si < 4; si++) {
        int strip = (w << 2) + si;
        short8v qf = *reinterpret_cast<const short8v*>(
            qkvP + (size_t)(base + strip * WW + a15) * QKVSTR + h * 32 + (kg << 3));
        float psum = 0.f;
        f32x4 o0 = zf, o1 = zf;
        const float* brow = biasN + ((size_t)h << 16) + (size_t)((strip << 4) + a15) * 256;
        #pragma unroll
        for (int half = 0; half < 2; half++) {
            f32x4 s[8];
            __builtin_amdgcn_s_setprio(1);
            #pragma unroll
            for (int j8 = 0; j8 < 8; j8++) {
                int jt = (half << 3) + j8;
                int row = (jt << 4) + a15;
                short8v ka = reinterpret_cast<const short8v*>(&Kc[row * 32])[kg ^ ((row >> 1) & 3)];
                s[j8] = __builtin_amdgcn_mfma_f32_16x16x32_bf16(ka, qf, zf, 0, 0, 0);
            }
            __builtin_amdgcn_s_setprio(0);
            #pragma unroll
            for (int j8 = 0; j8 < 8; j8++) {
                int jt = (half << 3) + j8;
                float4 b4 = *reinterpret_cast<const float4*>(brow + (jt << 4) + (kg << 2));
                float p0 = __expf(fmaf(s[j8][0], SCALE, b4.x));
                float p1 = __expf(fmaf(s[j8][1], SCALE, b4.y));
                float p2 = __expf(fmaf(s[j8][2], SCALE, b4.z));
                float p3 = __expf(fmaf(s[j8][3], SCALE, b4.w));
                psum += (p0 + p1) + (p2 + p3);
                unsigned int u0, u1;
                asm("v_cvt_pk_bf16_f32 %0, %1, %2" : "=v"(u0) : "v"(p0), "v"(p1));
                asm("v_cvt_pk_bf16_f32 %0, %1, %2" : "=v"(u1) : "v"(p2), "v"(p3));
                int dw0 = ((j8 << 3) + (kg << 1)) ^ xsw;
                unsigned long long pk64 = (unsigned long long)u0 | ((unsigned long long)u1 << 32);
                *reinterpret_cast<unsigned long long*>(&Pw[(a15 << 7) + (dw0 << 1)]) = pk64;
            }
            __builtin_amdgcn_s_setprio(1);
            #pragma unroll
            for (int ks4 = 0; ks4 < 4; ks4++) {
                int dwr = ((ks4 << 4) + (kg << 2)) ^ xsw;
                short8v pa = *reinterpret_cast<const short8v*>(&Pw[(a15 << 7) + (dwr << 1)]);
                int kc = (((half << 2) + ks4) << 2) + kg;
                short8v v0 = *reinterpret_cast<const short8v*>(&Vc[(kc * 33 + a15) * 8]);
                short8v v1 = *reinterpret_cast<const short8v*>(&Vc[(kc * 33 + 16 + a15) * 8]);
                o0 = __builtin_amdgcn_mfma_f32_16x16x32_bf16(pa, v0, o0, 0, 0, 0);
                o1 = __builtin_amdgcn_mfma_f32_16x16x32_bf16(pa, v1, o1, 0, 0, 0);
            }
            __builtin_amdgcn_s_setprio(0);
        }
        psum += __shfl_xor(psum, 16);
        psum += __shfl_xor(psum, 32);
        #pragma unroll
        for (int r = 0; r < 4; r++) {
            float pt = __shfl(psum, (kg << 2) + r);
            float inv = 1.f / pt;
            int g = base + strip * WW + (kg << 2) + r;
            ushortw* orow = out + (size_t)g * 192 + h * HD;
            orow[a15] = f2bf(o0[r] * inv);
            if (a15 < 14) orow[16 + a15] = f2bf(o1[r] * inv);
        }
    }
    if (h == 0) {   // zero pad cols 180..191
        for (int idx2 = tid; idx2 < NTOKW * 12; idx2 += 256) {
            int j = idx2 / 12, d = idx2 - (idx2 / 12) * 12;
            int gj = base + (j >> 4) * WW + (j & 15);
            out[(size_t)gj * 192 + 180 + d] = 0;
        }
    }
}

// ---------------- register-tiled depthwise 3x3 conv: 4 pixels x 4 channels / thread ----------------
template<int CIN_S, int COP, int OSTR, int DIL, int ACT, int OUTBF>
__global__ __launch_bounds__(256) void dwconv4_kernel(
    const ushortw* __restrict__ in, const float* __restrict__ wt,
    const float* __restrict__ bias, void* __restrict__ out)
{
    constexpr int NC4 = COP >> 2;
    constexpr int NX = 4 + 2 * DIL;
    int idx = blockIdx.x * 256 + threadIdx.x;
    int c4 = idx % NC4;
    int quad = idx / NC4;
    int c = c4 << 2;
    int pix0 = quad << 2;
    int p = pix0 & (IMG - 1);
    int imgbase = pix0 - p;
    int px0 = p & (WW - 1), py = p >> 7;

    float4 w9[9];
    #pragma unroll
    for (int t = 0; t < 9; t++)
        w9[t] = *reinterpret_cast<const float4*>(wt + t * COP + c);
    float4 bi4 = *reinterpret_cast<const float4*>(bias + c);
    float acc[4][4];
    #pragma unroll
    for (int i = 0; i < 4; i++) {
        acc[i][0] = bi4.x; acc[i][1] = bi4.y; acc[i][2] = bi4.z; acc[i][3] = bi4.w;
    }
    #pragma unroll
    for (int ky = 0; ky < 3; ky++) {
        int iy = py + (ky - 1) * DIL;
        if (iy < 0 || iy >= HH) continue;
        const ushortw* rowp = in + (size_t)(imgbase + (iy << 7)) * CIN_S + c;
        #pragma unroll
        for (int xx = 0; xx < NX; xx++) {
            int ix = px0 + xx - DIL;
            if (ix < 0 || ix >= WW) continue;
            short4v v = *reinterpret_cast<const short4v*>(rowp + (size_t)ix * CIN_S);
            float f0 = bf2f((ushortw)v[0]);
            float f1 = bf2f((ushortw)v[1]);
            float f2 = bf2f((ushortw)v[2]);
            float f3 = bf2f((ushortw)v[3]);
            #pragma unroll
            for (int kx = 0; kx < 3; kx++) {
                int i = xx - DIL * kx;
                if (i < 0 || i > 3) continue;
                float4 wv = w9[ky * 3 + kx];
                acc[i][0] = fmaf(f0, wv.x, acc[i][0]);
                acc[i][1] = fmaf(f1, wv.y, acc[i][1]);
                acc[i][2] = fmaf(f2, wv.z, acc[i][2]);
                acc[i][3] = fmaf(f3, wv.w, acc[i][3]);
            }
        }
    }
    if (COP != OSTR && c >= OSTR) return;
    #pragma unroll
    for (int i = 0; i < 4; i++) {
        #pragma unroll
        for (int e = 0; e < 4; e++) {
            float v = acc[i][e];
            if (ACT == 1) v = gelu_exact(v);
            else if (ACT == 2) v = fmaxf(v, 0.f);
            acc[i][e] = v;
        }
        if (OUTBF) {
            short4v o;
            o[0] = (short)f2bf(acc[i][0]); o[1] = (short)f2bf(acc[i][1]);
            o[2] = (short)f2bf(acc[i][2]); o[3] = (short)f2bf(acc[i][3]);
            *reinterpret_cast<short4v*>((ushortw*)out + (size_t)(pix0 + i) * OSTR + c) = o;
        } else {
            float4 o = make_float4(acc[i][0], acc[i][1], acc[i][2], acc[i][3]);
            *reinterpret_cast<float4*>((float*)out + (size_t)(pix0 + i) * OSTR + c) = o;
        }
    }
}

// ---------------- GAP partial sums over bf16 y4 (128-pixel chunks, 512 blocks) ----------------
__global__ void gap_kernel(const ushortw* __restrict__ y, float* __restrict__ part)
{
    int blk = blockIdx.x;              // 0..511
    int b = blk >> 7, chunk = blk & 127;
    int c = threadIdx.x;
    if (c >= CC) return;
    size_t basep = ((size_t)b * IMG + (size_t)chunk * 128) * CC;
    float s = 0.f;
    for (int p = 0; p < 128; p++) s += bf2f(y[basep + (size_t)p * CC + c]);
    part[((size_t)b * 128 + chunk) * CC + c] = s;
}

// ---------------- channel attention (tiny) ----------------
__global__ void ca_kernel(const float* __restrict__ part,
                          const float* __restrict__ w1, const float* __restrict__ b1,
                          const float* __restrict__ w2, const float* __restrict__ b2,
                          float* __restrict__ ca)
{
    __shared__ float gap[BB * CC];
    __shared__ float s1[BB * 6];
    int tid = threadIdx.x;
    for (int idx = tid; idx < BB * CC; idx += 256) {
        int b = idx / CC, c = idx % CC;
        float s = 0.f;
        for (int ch = 0; ch < 128; ch++) s += part[((size_t)b * 128 + ch) * CC + c];
        gap[idx] = s * (1.f / IMG);
    }
    __syncthreads();
    if (tid < BB * 6) {
        int b = tid / 6, cs = tid % 6;
        float s = 0.f;
        for (int c = 0; c < CC; c++) s += w1[cs * CC + c] * gap[b * CC + c];
        s1[tid] = fmaxf(s + b1[cs], 0.f);
    }
    __syncthreads();
    for (int idx = tid; idx < BB * CC; idx += 256) {
        int b = idx / CC, c = idx % CC;
        float s = b2[c];
        #pragma unroll
        for (int cs = 0; cs < 6; cs++) s += w2[c * 6 + cs] * s1[b * 6 + cs];
        ca[idx] = 1.f / (1.f + __expf(-s));
    }
}

// ---------------- x1(bf16) += 0.01*y4*ca; LN2 -> bf16 xn2 (stride 192) ----------------
__global__ __launch_bounds__(256) void resid_ln_kernel(
    ushortw* __restrict__ x1, const ushortw* __restrict__ y4, const float* __restrict__ ca,
    const float* __restrict__ g, const float* __restrict__ bb,
    ushortw* __restrict__ xn2)
{
    int wid = threadIdx.x >> 6, lane = threadIdx.x & 63;
    int t = blockIdx.x * 4 + wid;
    int b = t >> 14;
    size_t off = (size_t)t * CC;
    size_t off2 = (size_t)t * 192;
    bool has2 = lane < (CC - 128);
    float v0 = bf2f(x1[off+lane])    + 0.01f * bf2f(y4[off+lane])    * ca[b*CC + lane];
    float v1 = bf2f(x1[off+lane+64]) + 0.01f * bf2f(y4[off+lane+64]) * ca[b*CC + lane+64];
    float v2 = 0.f;
    if (has2) v2 = bf2f(x1[off+lane+128]) + 0.01f * bf2f(y4[off+lane+128]) * ca[b*CC + lane+128];
    x1[off+lane] = f2bf(v0); x1[off+lane+64] = f2bf(v1);
    if (has2) x1[off+lane+128] = f2bf(v2);
    float s = warp_sum(v0 + v1 + v2);
    float mu = s * (1.f / CC);
    float d0 = v0-mu, d1 = v1-mu, d2 = has2 ? v2-mu : 0.f;
    float var = warp_sum(d0*d0 + d1*d1 + d2*d2) * (1.f / CC);
    float rs = rsqrtf(var + 1e-5f);
    xn2[off2+lane]      = f2bf(d0 * rs * g[lane]      + bb[lane]);
    xn2[off2+lane+64]   = f2bf(d1 * rs * g[lane+64]   + bb[lane+64]);
    xn2[off2+lane+128]  = has2 ? f2bf(d2 * rs * g[lane+128] + bb[lane+128]) : (ushortw)0;
}

// ---------------- max/mean over channels per pixel (bf16 h3, stride 768, 720 cols) ----------------
__global__ __launch_bounds__(256) void mpap_kernel(
    const ushortw* __restrict__ h, float* __restrict__ mp, float* __restrict__ ap)
{
    int wid = threadIdx.x >> 6, lane = threadIdx.x & 63;
    int p = blockIdx.x * 4 + wid;
    const ushortw* row = h + (size_t)p * 768;
    float mx = -1e30f, s = 0.f;
    #pragma unroll
    for (int it = 0; it < 3; it++) {
        int j = (lane << 2) + it * 256;
        if (j < HID) {
            short4v v = *reinterpret_cast<const short4v*>(row + j);
            float f0 = bf2f((ushortw)v[0]), f1 = bf2f((ushortw)v[1]);
            float f2 = bf2f((ushortw)v[2]), f3 = bf2f((ushortw)v[3]);
            mx = fmaxf(mx, fmaxf(fmaxf(f0, f1), fmaxf(f2, f3)));
            s += (f0 + f1) + (f2 + f3);
        }
    }
    mx = warp_max(mx); s = warp_sum(s);
    if (lane == 0) { mp[p] = mx; ap[p] = s * (1.f / HID); }
}

// ---------------- 7x7 spatial-attention conv + sigmoid, LDS-tiled (16x16 tile + 22x22 halo) ----
__global__ __launch_bounds__(256) void saconv_kernel(
    const float* __restrict__ mp, const float* __restrict__ ap,
    const float* __restrict__ w, float* __restrict__ sa)
{
    __shared__ float smp[22][22];
    __shared__ float sap[22][22];
    int t = blockIdx.x;               // 0..127 (2 images x 64 tiles)
    int img = t >> 6;
    int ty = (t >> 3) & 7, tx = t & 7;
    int y0 = ty * 16 - 3, x0 = tx * 16 - 3;
    int tid = threadIdx.x;
    for (int i = tid; i < 22 * 22; i += 256) {
        int ly = i / 22, lx = i - ly * 22;
        int gy = y0 + ly, gx = x0 + lx;
        bool ok = (gy >= 0 && gy < HH && gx >= 0 && gx < WW);
        int pid = img * IMG + gy * WW + gx;
        smp[ly][lx] = ok ? mp[pid] : 0.f;
        sap[ly][lx] = ok ? ap[pid] : 0.f;
    }
    __syncthreads();
    int py = tid >> 4, px = tid & 15;
    float acc = 0.f;
    #pragma unroll
    for (int ky = 0; ky < 7; ky++) {
        #pragma unroll
        for (int kx = 0; kx < 7; kx++) {
            acc += smp[py + ky][px + kx] * w[ky * 7 + kx]
                 + sap[py + ky][px + kx] * w[49 + ky * 7 + kx];
        }
    }
    int p = img * IMG + (ty * 16 + py) * WW + (tx * 16 + px);
    sa[p] = 1.f / (1.f + __expf(-acc));
}

extern "C" void kernel_launch(void* const* d_in, const int* in_sizes, int n_in,
                              void* d_out, int out_size, void* d_ws, size_t ws_size,
                              hipStream_t stream)
{
    const float* x      = (const float*)d_in[0];
    const int*   rpi    = (const int*)d_in[3];
    const float* n1g    = (const float*)d_in[4];
    const float* n1b    = (const float*)d_in[5];
    const float* rpb    = (const float*)d_in[6];
    const float* qkv_w  = (const float*)d_in[7];
    const float* qkv_b  = (const float*)d_in[8];
    const float* proj_w = (const float*)d_in[9];
    const float* proj_b = (const float*)d_in[10];
    const float* cab_w0 = (const float*)d_in[11];
    const float* cab_b0 = (const float*)d_in[12];
    const float* cab_w1 = (const float*)d_in[13];
    const float* cab_b1 = (const float*)d_in[14];
    const float* cab_w2 = (const float*)d_in[15];
    const float* cab_b2 = (const float*)d_in[16];
    const float* cab_w3 = (const float*)d_in[17];
    const float* cab_b3 = (const float*)d_in[18];
    const float* ca_w1  = (const float*)d_in[19];
    const float* ca_b1  = (const float*)d_in[20];
    const float* ca_w2  = (const float*)d_in[21];
    const float* ca_b2  = (const float*)d_in[22];
    const float* n2g    = (const float*)d_in[23];
    const float* n2b    = (const float*)d_in[24];
    const float* fc1_w  = (const float*)d_in[25];
    const float* fc1_b  = (const float*)d_in[26];
    const float* dw_w   = (const float*)d_in[27];
    const float* dw_b   = (const float*)d_in[28];
    const float* pw_w   = (const float*)d_in[29];
    const float* pw_b   = (const float*)d_in[30];
    const float* sa_w   = (const float*)d_in[31];
    const float* fc2_w  = (const float*)d_in[32];
    const float* fc2_b  = (const float*)d_in[33];
    float* outp = (float*)d_out;
    (void)in_sizes; (void)n_in; (void)out_size; (void)ws_size;

    char* ws = (char*)d_ws;
    const size_t S0 = (size_t)NTOK * 192 * 2;            // xnb -> xn2b
    const size_t S1 = (size_t)NTOK * QKVSTR * 2 + 256;   // qkvP -> h1(half) -> h3(half)
    const size_t S2 = (size_t)NTOK * 192 * 2;            // attnbb -> y3b
    const size_t S3 = (size_t)NTOK * 180 * 2;            // x1b bf16
    const size_t S4 = (size_t)NTOK * 128 * 2;            // y2b ; h2(half) spans S4+S5
    const size_t S5 = (size_t)NTOK * 180 * 4;            // xb -> y4 bf16 (region kept for h2 span)
    char* pA0 = ws;
    char* pA1 = pA0 + S0;
    char* pA2 = pA1 + S1;
    char* pA3 = pA2 + S2;
    char* pA4 = pA3 + S3;
    char* pA5 = pA4 + S4;
    char* tail = pA5 + S5;

    ushortw* xnb    = (ushortw*)pA0;           // [NTOK][192]
    ushortw* xn2b   = (ushortw*)pA0;
    ushortw* qkvP   = (ushortw*)pA1;           // [NTOK][672] (cols 576.. = cab0 out)
    ushortw* h1     = (ushortw*)pA1;           // [HALFTOK][720]
    ushortw* h3     = (ushortw*)pA1;           // [HALFTOK][768]
    ushortw* attnbb = (ushortw*)pA2;           // [NTOK][192]
    ushortw* y3b    = (ushortw*)pA2;           // [NTOK][192]
    ushortw* x1b    = (ushortw*)pA3;           // [NTOK][180] bf16
    ushortw* y2b    = (ushortw*)pA4;           // [NTOK][128]
    ushortw* h2     = (ushortw*)pA4;           // [HALFTOK][768] spans S4+S5
    ushortw* xb     = (ushortw*)pA5;           // [NTOK][180] bf16 (x copy; dead after proj)
    ushortw* y4     = (ushortw*)pA5;           // [NTOK][180] bf16 (written by dw2, after proj)

    // bf16 gemm weights
    ushortw* wqkvc = (ushortw*)tail;                        // 672 x 192
    ushortw* wproj = wqkvc + 672 * 192;                     // 256 x 192
    ushortw* wcab2 = wproj + 256 * 192;                     // 256 x 128
    ushortw* wfc1  = wcab2 + 256 * 128;                     // 768 x 192
    ushortw* wpw   = wfc1  + 768 * 192;                     // 768 x 768
    ushortw* wfc2  = wpw   + 768 * 768;                     // 256 x 768
    char* tail2 = (char*)(wfc2 + 256 * 768);
    float* dwt1 = (float*)tail2;                 float* db1 = dwt1 + 9*128;
    float* dwt2 = db1 + 128;                     float* db2 = dwt2 + 9*192;
    float* dwt3 = db2 + 192;                     float* db3 = dwt3 + 9*768;
    float* qb672 = db3 + 768;
    char* tail3 = (char*)(qb672 + 672);
    float* biasN = (float*)tail3;                           // 6*65536 fp32
    float* part  = (float*)(tail3 + 1572864);               // 4*128*180 fp32
    float* cabuf = (float*)(tail3 + 1572864 + 393216);
    float* mp    = (float*)(tail3 + 1572864 + 393216 + 4096);
    float* ap    = (float*)(tail3 + 1572864 + 393216 + 4096 + (size_t)HALFTOK * 4);
    float* sab   = (float*)(tail3 + 1572864 + 393216 + 4096 + 2*(size_t)HALFTOK * 4);

    auto gemm = [&](const ushortw* A, const ushortw* Wt, const float* bi, void* Cp,
                    int M, int N, int Kp, int ldc, int outbf, int zfill, int act, int residbf,
                    const float* rs, const void* resid) {
        int nM = M >> 7, nN = (N + 127) >> 7;
        mgemm_kernel<<<dim3(nM * nN), dim3(256), 0, stream>>>(
            A, Wt, bi, Cp, M, N, Kp, ldc, outbf, zfill, act, residbf, nN, rs, resid);
    };

    // 0) all weight/bias prep in one launch
    prep_kernel<<<dim3((1220832 + 255) / 256), dim3(256), 0, stream>>>(
        qkv_w, proj_w, cab_w0, cab_b0, cab_w2, fc1_w, pw_w, fc2_w,
        cab_w1, cab_b1, cab_w3, cab_b3, dw_w, dw_b, qkv_b, rpi, rpb,
        wqkvc, wproj, wcab2, wfc1, wpw, wfc2,
        dwt1, db1, dwt2, db2, dwt3, db3, qb672, biasN);

    // 1) LN1 -> bf16 xnb (+ bf16 copy of x for proj residual)
    ln_kernel<<<dim3(NTOK / 4), dim3(256), 0, stream>>>(x, n1g, n1b, xnb, xb);
    // 2) merged qkv+cab0 GEMM -> qkvP[NTOK][672]; then attention + CAB dwconv1
    gemm(xnb, wqkvc, qb672, qkvP, NTOK, 672, 192, QKVSTR, 1, 0, 0, 0, nullptr, nullptr);
    attn_mfma_kernel<<<dim3(BB * 64 * NHEADS), dim3(256), 0, stream>>>(qkvP, biasN, attnbb);
    dwconv4_kernel<672, 128, 128, 1, 1, 1><<<dim3(NTOK / 4 * 32 / 256), dim3(256), 0, stream>>>(
        qkvP + 576, dwt1, db1, y2b);
    // 3) proj with bf16 residual xb -> x1b (bf16)
    gemm(attnbb, wproj, proj_b, x1b, NTOK, 180, 192, 180, 1, 0, 0, 1, nullptr, xb);
    // 4) CAB part 2 (y4 overwrites xb region -- xb dead after proj)
    gemm(y2b, wcab2, cab_b2, y3b, NTOK, 180, 128, 192, 1, 1, 0, 0, nullptr, nullptr);
    dwconv4_kernel<192, 192, 180, 2, 0, 1><<<dim3(NTOK / 4 * 48 / 256), dim3(256), 0, stream>>>(
        y3b, dwt2, db2, y4);
    gap_kernel<<<dim3(BB * 128), dim3(192), 0, stream>>>(y4, part);
    ca_kernel<<<dim3(1), dim3(256), 0, stream>>>(part, ca_w1, ca_b1, ca_w2, ca_b2, cabuf);
    // 5) x1 += 0.01*y4*ca; LN2 -> bf16 xn2b
    resid_ln_kernel<<<dim3(NTOK / 4), dim3(256), 0, stream>>>(x1b, y4, cabuf, n2g, n2b, xn2b);
    // 6) FFN in two half-batches (2 images each)
    for (int half = 0; half < 2; half++) {
        size_t toff = (size_t)half * HALFTOK;
        gemm(xn2b + toff * 192, wfc1, fc1_b, h1, HALFTOK, 720, 192, 720, 1, 0, 1, 0, nullptr, nullptr);
        dwconv4_kernel<720, 768, 768, 1, 2, 1><<<dim3(HALFTOK / 4 * 192 / 256), dim3(256), 0, stream>>>(
            h1, dwt3, db3, h2);
        gemm(h2, wpw, pw_b, h3, HALFTOK, 720, 768, 768, 1, 1, 2, 0, nullptr, nullptr);
        mpap_kernel<<<dim3(HALFTOK / 4), dim3(256), 0, stream>>>(h3, mp, ap);
        saconv_kernel<<<dim3(128), dim3(256), 0, stream>>>(mp, ap, sa_w, sab);
        gemm(h3, wfc2, fc2_b, outp + toff * 180, HALFTOK, 180, 768, 180, 0, 0, 0, 1,
             sab, x1b + toff * 180);
    }
}

// Round 23
// 617.745 us; speedup vs baseline: 1.1057x; 1.0035x over previous
//
#include <hip/hip_runtime.h>
#include <math.h>

#define HH 128
#define WW 128
#define CC 180
#define BB 4
#define IMG (HH*WW)          // 16384 tokens per image
#define NTOK (BB*IMG)        // 65536
#define HALFTOK (2*IMG)      // 32768
#define NHEADS 6
#define HD 30
#define WSZ 16
#define NTOKW (WSZ*WSZ)      // 256
#define HID 720
#define QKVSTR 672           // merged row: q/k/v (3x192) + cab0 (96)

typedef __attribute__((ext_vector_type(8))) short short8v;
typedef __attribute__((ext_vector_type(4))) short short4v;
typedef __attribute__((ext_vector_type(4))) float f32x4;
typedef unsigned short ushortw;

__device__ __forceinline__ float warp_sum(float v) {
    #pragma unroll
    for (int o = 32; o > 0; o >>= 1) v += __shfl_xor(v, o);
    return v;
}
__device__ __forceinline__ float warp_max(float v) {
    #pragma unroll
    for (int o = 32; o > 0; o >>= 1) v = fmaxf(v, __shfl_xor(v, o));
    return v;
}
__device__ __forceinline__ float gelu_exact(float v) {
    return 0.5f * v * (1.f + erff(v * 0.70710678118654752f));
}
__device__ __forceinline__ ushortw f2bf(float f) {
    union { float f; unsigned int u; } c; c.f = f;
    unsigned int r = (c.u + 0x7FFFu + ((c.u >> 16) & 1u)) >> 16;
    return (ushortw)r;
}
__device__ __forceinline__ float bf2f(ushortw u) {
    union { unsigned int u; float f; } c; c.u = ((unsigned int)u) << 16; return c.f;
}

// ---------------- fused weight/bias prep (one launch) ----------------
__global__ __launch_bounds__(256) void prep_kernel(
    const float* __restrict__ qkv_w, const float* __restrict__ proj_w,
    const float* __restrict__ cab_w0, const float* __restrict__ cab_b0,
    const float* __restrict__ cab_w2,
    const float* __restrict__ fc1_w, const float* __restrict__ pw_w,
    const float* __restrict__ fc2_w,
    const float* __restrict__ cab_w1, const float* __restrict__ cab_b1,
    const float* __restrict__ cab_w3, const float* __restrict__ cab_b3,
    const float* __restrict__ dw_w, const float* __restrict__ dw_b,
    const float* __restrict__ qkv_b, const int* __restrict__ rpi,
    const float* __restrict__ rpb,
    ushortw* __restrict__ wqkvc, ushortw* __restrict__ wproj,
    ushortw* __restrict__ wcab2,
    ushortw* __restrict__ wfc1, ushortw* __restrict__ wpw, ushortw* __restrict__ wfc2,
    float* __restrict__ dwt1, float* __restrict__ db1,
    float* __restrict__ dwt2, float* __restrict__ db2,
    float* __restrict__ dwt3, float* __restrict__ db3,
    float* __restrict__ qb672, float* __restrict__ biasN)
{
    int idx = blockIdx.x * 256 + threadIdx.x;
    if (idx < 129024) {                              // J0: wqkvc [672][192]
        int r = idx / 192, k = idx - r * 192;
        float v = 0.f;
        if (r < 576) {
            int sub = r / 192, rem = r - sub * 192;
            int hh = rem >> 5, dd = rem & 31;
            if (dd < 30 && k < 180) v = qkv_w[(sub * 180 + hh * 30 + dd) * 180 + k];
        } else if (r < 666) {
            if (k < 180) v = cab_w0[(r - 576) * 180 + k];
        }
        wqkvc[idx] = f2bf(v);
    } else if (idx < 178176) {                       // J1: wproj [256][192]
        int l = idx - 129024; int r = l / 192, k = l - r * 192;
        wproj[l] = f2bf((r < 180 && k < 180) ? proj_w[r * 180 + k] : 0.f);
    } else if (idx < 210944) {                       // J2: wcab2 [256][128]
        int l = idx - 178176; int r = l / 128, k = l - r * 128;
        wcab2[l] = f2bf((r < 180 && k < 90) ? cab_w2[r * 90 + k] : 0.f);
    } else if (idx < 358400) {                       // J3: wfc1 [768][192]
        int l = idx - 210944; int r = l / 192, k = l - r * 192;
        wfc1[l] = f2bf((r < 720 && k < 180) ? fc1_w[r * 180 + k] : 0.f);
    } else if (idx < 948224) {                       // J4: wpw [768][768]
        int l = idx - 358400; int r = l / 768, k = l - r * 768;
        wpw[l] = f2bf((r < 720 && k < 720) ? pw_w[r * 720 + k] : 0.f);
    } else if (idx < 1144832) {                      // J5: wfc2 [256][768]
        int l = idx - 948224; int r = l / 768, k = l - r * 768;
        wfc2[l] = f2bf((r < 180 && k < 720) ? fc2_w[r * 720 + k] : 0.f);
    } else if (idx < 1145984) {                      // J6: dwt1 [9][128]
        int l = idx - 1144832; int c = l / 9, k = l - c * 9;
        dwt1[k * 128 + c] = (c < 90) ? cab_w1[c * 9 + k] : 0.f;
        if (k == 0) db1[c] = (c < 90) ? cab_b1[c] : 0.f;
    } else if (idx < 1147712) {                      // J7: dwt2 [9][192]
        int l = idx - 1145984; int c = l / 9, k = l - c * 9;
        dwt2[k * 192 + c] = (c < 180) ? cab_w3[c * 9 + k] : 0.f;
        if (k == 0) db2[c] = (c < 180) ? cab_b3[c] : 0.f;
    } else if (idx < 1154624) {                      // J8: dwt3 [9][768]
        int l = idx - 1147712; int c = l / 9, k = l - c * 9;
        dwt3[k * 768 + c] = (c < 720) ? dw_w[c * 9 + k] : 0.f;
        if (k == 0) db3[c] = (c < 720) ? dw_b[c] : 0.f;
    } else if (idx < 1155296) {                      // J9: qb672
        int l = idx - 1154624;
        float v = 0.f;
        if (l < 576) {
            int sub = l / 192, rem = l - sub * 192;
            int hh = rem >> 5, dd = rem & 31;
            if (dd < 30) v = qkv_b[sub * 180 + hh * 30 + dd];
        } else if (l < 666) {
            v = cab_b0[l - 576];
        }
        qb672[l] = v;
    } else if (idx < 1220832) {                      // J10: biasN [6][65536]
        int l = idx - 1155296;
        int r = rpi[l];
        #pragma unroll
        for (int h = 0; h < NHEADS; h++)
            biasN[((size_t)h << 16) + l] = rpb[r * NHEADS + h];
    }
}

// ---------------- LayerNorm -> bf16 xn (stride 192, pads 0) + bf16 copy of x ----------------
__global__ __launch_bounds__(256) void ln_kernel(
    const float* __restrict__ x, const float* __restrict__ g,
    const float* __restrict__ b, ushortw* __restrict__ out, ushortw* __restrict__ xb)
{
    int wid = threadIdx.x >> 6, lane = threadIdx.x & 63;
    int t = blockIdx.x * 4 + wid;
    size_t off = (size_t)t * CC;
    size_t off2 = (size_t)t * 192;
    bool has2 = lane < (CC - 128);
    float v0 = x[off + lane];
    float v1 = x[off + lane + 64];
    float v2 = has2 ? x[off + lane + 128] : 0.f;
    xb[off + lane] = f2bf(v0);
    xb[off + lane + 64] = f2bf(v1);
    if (has2) xb[off + lane + 128] = f2bf(v2);
    float s = warp_sum(v0 + v1 + v2);
    float mu = s * (1.f / CC);
    float d0 = v0 - mu, d1 = v1 - mu, d2 = has2 ? v2 - mu : 0.f;
    float var = warp_sum(d0*d0 + d1*d1 + d2*d2) * (1.f / CC);
    float rs = rsqrtf(var + 1e-5f);
    out[off2 + lane]      = f2bf(d0 * rs * g[lane]      + b[lane]);
    out[off2 + lane + 64] = f2bf(d1 * rs * g[lane + 64] + b[lane + 64]);
    out[off2 + lane + 128] = has2 ? f2bf(d2 * rs * g[lane + 128] + b[lane + 128]) : (ushortw)0;
}

// ---------------- bf16 MFMA GEMM: BK=32 dbuf + XOR swizzle + transposed-acc epilogue ----------
__global__ __launch_bounds__(256) void mgemm_kernel(
    const ushortw* __restrict__ A, const ushortw* __restrict__ Wt,
    const float* __restrict__ bias, void* __restrict__ Cout,
    int M, int N, int Kp, int ldc, int outbf, int zfill, int act, int residbf, int nN,
    const float* __restrict__ rowscale, const void* __restrict__ residv)
{
    __shared__ ushortw sA[2][128 * 32];
    __shared__ ushortw sB[2][128 * 32];
    int tid = threadIdx.x, lane = tid & 63, wid = tid >> 6;
    int total = (int)gridDim.x;
    int orig = blockIdx.x;
    int q = total >> 3, r = total & 7;
    int xcd = orig & 7, slot = orig >> 3;
    int wgid = (xcd < r ? xcd * (q + 1) : r * (q + 1) + (xcd - r) * q) + slot;
    int mp = wgid / nN, np = wgid - mp * nN;
    int m0 = mp << 7, n0 = np << 7;
    int wm = (wid >> 1) << 6, wn = (wid & 1) << 6;
    int lrow = lane & 15, kgrp = lane >> 4;

    f32x4 acc[4][4];
    #pragma unroll
    for (int i = 0; i < 4; i++)
        #pragma unroll
        for (int j = 0; j < 4; j++)
            #pragma unroll
            for (int rr = 0; rr < 4; rr++) acc[i][j][rr] = 0.f;

    int nk = Kp >> 5;
    #pragma unroll
    for (int qq = 0; qq < 2; qq++) {
        int seg = (wid << 1) + qq;                 // 0..7
        int row = (seg << 4) + (lane >> 2);        // 0..127
        int cg = (lane & 3) ^ (row & 3) ^ ((row >> 2) & 3);
        const ushortw* ga = A + (size_t)(m0 + row) * Kp + (cg << 3);
        __builtin_amdgcn_global_load_lds(
            (const __attribute__((address_space(1))) void*)ga,
            (__attribute__((address_space(3))) void*)&sA[0][seg << 9], 16, 0, 0);
        const ushortw* gb = Wt + (size_t)(n0 + row) * Kp + (cg << 3);
        __builtin_amdgcn_global_load_lds(
            (const __attribute__((address_space(1))) void*)gb,
            (__attribute__((address_space(3))) void*)&sB[0][seg << 9], 16, 0, 0);
    }
    __syncthreads();

    int cur = 0;
    for (int t = 0; t < nk; t++) {
        if (t + 1 < nk) {
            int kk2 = (t + 1) << 5;
            #pragma unroll
            for (int qq = 0; qq < 2; qq++) {
                int seg = (wid << 1) + qq;
                int row = (seg << 4) + (lane >> 2);
                int cg = (lane & 3) ^ (row & 3) ^ ((row >> 2) & 3);
                const ushortw* ga = A + (size_t)(m0 + row) * Kp + kk2 + (cg << 3);
                __builtin_amdgcn_global_load_lds(
                    (const __attribute__((address_space(1))) void*)ga,
                    (__attribute__((address_space(3))) void*)&sA[cur ^ 1][seg << 9], 16, 0, 0);
                const ushortw* gb = Wt + (size_t)(n0 + row) * Kp + kk2 + (cg << 3);
                __builtin_amdgcn_global_load_lds(
                    (const __attribute__((address_space(1))) void*)gb,
                    (__attribute__((address_space(3))) void*)&sB[cur ^ 1][seg << 9], 16, 0, 0);
            }
        }
        short8v a[4], b[4];
        #pragma unroll
        for (int i = 0; i < 4; i++) {
            int rr = wm + (i << 4) + lrow;
            int slot2 = kgrp ^ (rr & 3) ^ ((rr >> 2) & 3);
            a[i] = *reinterpret_cast<const short8v*>(&sA[cur][(rr << 5) + (slot2 << 3)]);
        }
        #pragma unroll
        for (int j = 0; j < 4; j++) {
            int rr = wn + (j << 4) + lrow;
            int slot2 = kgrp ^ (rr & 3) ^ ((rr >> 2) & 3);
            b[j] = *reinterpret_cast<const short8v*>(&sB[cur][(rr << 5) + (slot2 << 3)]);
        }
        #pragma unroll
        for (int i = 0; i < 4; i++)
            #pragma unroll
            for (int j = 0; j < 4; j++)
                acc[i][j] = __builtin_amdgcn_mfma_f32_16x16x32_bf16(b[j], a[i], acc[i][j], 0, 0, 0);
        __syncthreads();
        cur ^= 1;
    }
    // transposed-acc epilogue: row = token (lane), 4 consecutive cols per reg
    #pragma unroll
    for (int i = 0; i < 4; i++) {
        int row = m0 + wm + (i << 4) + lrow;
        float rsv = rowscale ? rowscale[row] : 1.f;
        #pragma unroll
        for (int j = 0; j < 4; j++) {
            int colb = n0 + wn + (j << 4) + (kgrp << 2);
            if (colb < N) {
                float4 bi4 = *reinterpret_cast<const float4*>(bias + colb);
                float vv[4];
                vv[0] = acc[i][j][0]; vv[1] = acc[i][j][1];
                vv[2] = acc[i][j][2]; vv[3] = acc[i][j][3];
                if (rowscale) {
                    vv[0] *= rsv; vv[1] *= rsv; vv[2] *= rsv; vv[3] *= rsv;
                }
                vv[0] += bi4.x; vv[1] += bi4.y; vv[2] += bi4.z; vv[3] += bi4.w;
                if (act == 1) {
                    vv[0] = gelu_exact(vv[0]); vv[1] = gelu_exact(vv[1]);
                    vv[2] = gelu_exact(vv[2]); vv[3] = gelu_exact(vv[3]);
                } else if (act == 2) {
                    vv[0] = fmaxf(vv[0], 0.f); vv[1] = fmaxf(vv[1], 0.f);
                    vv[2] = fmaxf(vv[2], 0.f); vv[3] = fmaxf(vv[3], 0.f);
                }
                if (residv) {
                    if (residbf) {
                        short4v rv = *reinterpret_cast<const short4v*>(
                            (const ushortw*)residv + (size_t)row * N + colb);
                        vv[0] += bf2f((ushortw)rv[0]); vv[1] += bf2f((ushortw)rv[1]);
                        vv[2] += bf2f((ushortw)rv[2]); vv[3] += bf2f((ushortw)rv[3]);
                    } else {
                        float4 rv = *reinterpret_cast<const float4*>(
                            (const float*)residv + (size_t)row * N + colb);
                        vv[0] += rv.x; vv[1] += rv.y; vv[2] += rv.z; vv[3] += rv.w;
                    }
                }
                if (outbf) {
                    short4v o;
                    o[0] = (short)f2bf(vv[0]); o[1] = (short)f2bf(vv[1]);
                    o[2] = (short)f2bf(vv[2]); o[3] = (short)f2bf(vv[3]);
                    *reinterpret_cast<short4v*>((ushortw*)Cout + (size_t)row * ldc + colb) = o;
                } else {
                    float4 o = make_float4(vv[0], vv[1], vv[2], vv[3]);
                    *reinterpret_cast<float4*>((float*)Cout + (size_t)row * ldc + colb) = o;
                }
            } else if (zfill && colb < ldc) {
                if (outbf) {
                    short4v o; o[0] = 0; o[1] = 0; o[2] = 0; o[3] = 0;
                    *reinterpret_cast<short4v*>((ushortw*)Cout + (size_t)row * ldc + colb) = o;
                } else {
                    *reinterpret_cast<float4*>((float*)Cout + (size_t)row * ldc + colb) =
                        make_float4(0.f, 0.f, 0.f, 0.f);
                }
            }
        }
    }
}

// ---------------- MFMA window attention (swapped QK^T): block = (img, win, head) ----------------
// r22-proven config + bias loads hoisted ahead of the QK MFMA cluster (latency hides under MFMA).
__global__ __launch_bounds__(256, 3) void attn_mfma_kernel(
    const ushortw* __restrict__ qkvP, const float* __restrict__ biasN,
    ushortw* __restrict__ out)
{
    __shared__ ushortw Vc[32 * 33 * 8];      // 16896 B
    __shared__ ushortw Kc[256 * 32];         // 16384 B
    __shared__ ushortw Pl[4][2048];          // 16384 B
    const float SCALE = 0.18257418583505536f;   // 30^-0.5
    int blk = blockIdx.x;
    int img = blk / 384;
    int rem = blk - img * 384;
    int win = rem / NHEADS;
    int h = rem - win * NHEADS;
    int base = img * IMG + (win >> 3) * WSZ * WW + (win & 7) * WSZ;
    int tid = threadIdx.x;
    int lane = tid & 63, w = tid >> 6;
    int a15 = lane & 15, kg = lane >> 4;

    {
        int j = tid;
        int g = base + (j >> 4) * WW + (j & 15);
        const ushortw* vp = qkvP + (size_t)g * QKVSTR + 384 + h * 32;
        short8v c0 = *reinterpret_cast<const short8v*>(vp);
        short8v c1 = *reinterpret_cast<const short8v*>(vp + 8);
        short8v c2 = *reinterpret_cast<const short8v*>(vp + 16);
        short8v c3 = *reinterpret_cast<const short8v*>(vp + 24);
        int bo = (j >> 3) * 264 + (j & 7);
        #pragma unroll
        for (int e = 0; e < 8; e++)  Vc[bo + (e) * 8]      = (ushortw)c0[e];
        #pragma unroll
        for (int e = 0; e < 8; e++)  Vc[bo + (8 + e) * 8]  = (ushortw)c1[e];
        #pragma unroll
        for (int e = 0; e < 8; e++)  Vc[bo + (16 + e) * 8] = (ushortw)c2[e];
        #pragma unroll
        for (int e = 0; e < 8; e++)  Vc[bo + (24 + e) * 8] = (ushortw)c3[e];
        const ushortw* kp = qkvP + (size_t)g * QKVSTR + 192 + h * 32;
        short8v k0 = *reinterpret_cast<const short8v*>(kp);
        short8v k1 = *reinterpret_cast<const short8v*>(kp + 8);
        short8v k2 = *reinterpret_cast<const short8v*>(kp + 16);
        short8v k3 = *reinterpret_cast<const short8v*>(kp + 24);
        short8v* krow = reinterpret_cast<short8v*>(&Kc[j * 32]);
        int jsw = (j >> 1) & 3;
        krow[0 ^ jsw] = k0; krow[1 ^ jsw] = k1; krow[2 ^ jsw] = k2; krow[3 ^ jsw] = k3;
    }
    __syncthreads();

    ushortw* Pw = &Pl[w][0];
    int xsw = (a15 & 7) << 2;                // P dword-XOR per q-row
    f32x4 zf = {0.f, 0.f, 0.f, 0.f};
    #pragma unroll 1
    for (int si = 0; si < 4; si++) {
        int strip = (w << 2) + si;
        short8v qf = *reinterpret_cast<const short8v*>(
            qkvP + (size_t)(base + strip * WW + a15) * QKVSTR + h * 32 + (kg << 3));
        float psum = 0.f;
        f32x4 o0 = zf, o1 = zf;
        const float* brow = biasN + ((size_t)h << 16) + (size_t)((strip << 4) + a15) * 256;
        #pragma unroll
        for (int half = 0; half < 2; half++) {
            // hoist bias loads: in flight during the QK MFMA cluster
            float4 b4s[8];
            #pragma unroll
            for (int j8 = 0; j8 < 8; j8++) {
                int jt = (half << 3) + j8;
                b4s[j8] = *reinterpret_cast<const float4*>(brow + (jt << 4) + (kg << 2));
            }
            f32x4 s[8];
            __builtin_amdgcn_s_setprio(1);
            #pragma unroll
            for (int j8 = 0; j8 < 8; j8++) {
                int jt = (half << 3) + j8;
                int row = (jt << 4) + a15;
                short8v ka = reinterpret_cast<const short8v*>(&Kc[row * 32])[kg ^ ((row >> 1) & 3)];
                s[j8] = __builtin_amdgcn_mfma_f32_16x16x32_bf16(ka, qf, zf, 0, 0, 0);
            }
            __builtin_amdgcn_s_setprio(0);
            #pragma unroll
            for (int j8 = 0; j8 < 8; j8++) {
                float p0 = __expf(fmaf(s[j8][0], SCALE, b4s[j8].x));
                float p1 = __expf(fmaf(s[j8][1], SCALE, b4s[j8].y));
                float p2 = __expf(fmaf(s[j8][2], SCALE, b4s[j8].z));
                float p3 = __expf(fmaf(s[j8][3], SCALE, b4s[j8].w));
                psum += (p0 + p1) + (p2 + p3);
                unsigned int u0, u1;
                asm("v_cvt_pk_bf16_f32 %0, %1, %2" : "=v"(u0) : "v"(p0), "v"(p1));
                asm("v_cvt_pk_bf16_f32 %0, %1, %2" : "=v"(u1) : "v"(p2), "v"(p3));
                int dw0 = ((j8 << 3) + (kg << 1)) ^ xsw;
                unsigned long long pk64 = (unsigned long long)u0 | ((unsigned long long)u1 << 32);
                *reinterpret_cast<unsigned long long*>(&Pw[(a15 << 7) + (dw0 << 1)]) = pk64;
            }
            __builtin_amdgcn_s_setprio(1);
            #pragma unroll
            for (int ks4 = 0; ks4 < 4; ks4++) {
                int dwr = ((ks4 << 4) + (kg << 2)) ^ xsw;
                short8v pa = *reinterpret_cast<const short8v*>(&Pw[(a15 << 7) + (dwr << 1)]);
                int kc = (((half << 2) + ks4) << 2) + kg;
                short8v v0 = *reinterpret_cast<const short8v*>(&Vc[(kc * 33 + a15) * 8]);
                short8v v1 = *reinterpret_cast<const short8v*>(&Vc[(kc * 33 + 16 + a15) * 8]);
                o0 = __builtin_amdgcn_mfma_f32_16x16x32_bf16(pa, v0, o0, 0, 0, 0);
                o1 = __builtin_amdgcn_mfma_f32_16x16x32_bf16(pa, v1, o1, 0, 0, 0);
            }
            __builtin_amdgcn_s_setprio(0);
        }
        psum += __shfl_xor(psum, 16);
        psum += __shfl_xor(psum, 32);
        #pragma unroll
        for (int r = 0; r < 4; r++) {
            float pt = __shfl(psum, (kg << 2) + r);
            float inv = 1.f / pt;
            int g = base + strip * WW + (kg << 2) + r;
            ushortw* orow = out + (size_t)g * 192 + h * HD;
            orow[a15] = f2bf(o0[r] * inv);
            if (a15 < 14) orow[16 + a15] = f2bf(o1[r] * inv);
        }
    }
    if (h == 0) {   // zero pad cols 180..191
        for (int idx2 = tid; idx2 < NTOKW * 12; idx2 += 256) {
            int j = idx2 / 12, d = idx2 - (idx2 / 12) * 12;
            int gj = base + (j >> 4) * WW + (j & 15);
            out[(size_t)gj * 192 + 180 + d] = 0;
        }
    }
}

// ---------------- register-tiled depthwise 3x3 conv: 4 pixels x 4 channels / thread ----------------
template<int CIN_S, int COP, int OSTR, int DIL, int ACT, int OUTBF>
__global__ __launch_bounds__(256) void dwconv4_kernel(
    const ushortw* __restrict__ in, const float* __restrict__ wt,
    const float* __restrict__ bias, void* __restrict__ out)
{
    constexpr int NC4 = COP >> 2;
    constexpr int NX = 4 + 2 * DIL;
    int idx = blockIdx.x * 256 + threadIdx.x;
    int c4 = idx % NC4;
    int quad = idx / NC4;
    int c = c4 << 2;
    int pix0 = quad << 2;
    int p = pix0 & (IMG - 1);
    int imgbase = pix0 - p;
    int px0 = p & (WW - 1), py = p >> 7;

    float4 w9[9];
    #pragma unroll
    for (int t = 0; t < 9; t++)
        w9[t] = *reinterpret_cast<const float4*>(wt + t * COP + c);
    float4 bi4 = *reinterpret_cast<const float4*>(bias + c);
    float acc[4][4];
    #pragma unroll
    for (int i = 0; i < 4; i++) {
        acc[i][0] = bi4.x; acc[i][1] = bi4.y; acc[i][2] = bi4.z; acc[i][3] = bi4.w;
    }
    #pragma unroll
    for (int ky = 0; ky < 3; ky++) {
        int iy = py + (ky - 1) * DIL;
        if (iy < 0 || iy >= HH) continue;
        const ushortw* rowp = in + (size_t)(imgbase + (iy << 7)) * CIN_S + c;
        #pragma unroll
        for (int xx = 0; xx < NX; xx++) {
            int ix = px0 + xx - DIL;
            if (ix < 0 || ix >= WW) continue;
            short4v v = *reinterpret_cast<const short4v*>(rowp + (size_t)ix * CIN_S);
            float f0 = bf2f((ushortw)v[0]);
            float f1 = bf2f((ushortw)v[1]);
            float f2 = bf2f((ushortw)v[2]);
            float f3 = bf2f((ushortw)v[3]);
            #pragma unroll
            for (int kx = 0; kx < 3; kx++) {
                int i = xx - DIL * kx;
                if (i < 0 || i > 3) continue;
                float4 wv = w9[ky * 3 + kx];
                acc[i][0] = fmaf(f0, wv.x, acc[i][0]);
                acc[i][1] = fmaf(f1, wv.y, acc[i][1]);
                acc[i][2] = fmaf(f2, wv.z, acc[i][2]);
                acc[i][3] = fmaf(f3, wv.w, acc[i][3]);
            }
        }
    }
    if (COP != OSTR && c >= OSTR) return;
    #pragma unroll
    for (int i = 0; i < 4; i++) {
        #pragma unroll
        for (int e = 0; e < 4; e++) {
            float v = acc[i][e];
            if (ACT == 1) v = gelu_exact(v);
            else if (ACT == 2) v = fmaxf(v, 0.f);
            acc[i][e] = v;
        }
        if (OUTBF) {
            short4v o;
            o[0] = (short)f2bf(acc[i][0]); o[1] = (short)f2bf(acc[i][1]);
            o[2] = (short)f2bf(acc[i][2]); o[3] = (short)f2bf(acc[i][3]);
            *reinterpret_cast<short4v*>((ushortw*)out + (size_t)(pix0 + i) * OSTR + c) = o;
        } else {
            float4 o = make_float4(acc[i][0], acc[i][1], acc[i][2], acc[i][3]);
            *reinterpret_cast<float4*>((float*)out + (size_t)(pix0 + i) * OSTR + c) = o;
        }
    }
}

// ---------------- GAP partial sums over bf16 y4 (128-pixel chunks, 512 blocks) ----------------
__global__ void gap_kernel(const ushortw* __restrict__ y, float* __restrict__ part)
{
    int blk = blockIdx.x;              // 0..511
    int b = blk >> 7, chunk = blk & 127;
    int c = threadIdx.x;
    if (c >= CC) return;
    size_t basep = ((size_t)b * IMG + (size_t)chunk * 128) * CC;
    float s = 0.f;
    for (int p = 0; p < 128; p++) s += bf2f(y[basep + (size_t)p * CC + c]);
    part[((size_t)b * 128 + chunk) * CC + c] = s;
}

// ---------------- channel attention (tiny) ----------------
__global__ void ca_kernel(const float* __restrict__ part,
                          const float* __restrict__ w1, const float* __restrict__ b1,
                          const float* __restrict__ w2, const float* __restrict__ b2,
                          float* __restrict__ ca)
{
    __shared__ float gap[BB * CC];
    __shared__ float s1[BB * 6];
    int tid = threadIdx.x;
    for (int idx = tid; idx < BB * CC; idx += 256) {
        int b = idx / CC, c = idx % CC;
        float s = 0.f;
        for (int ch = 0; ch < 128; ch++) s += part[((size_t)b * 128 + ch) * CC + c];
        gap[idx] = s * (1.f / IMG);
    }
    __syncthreads();
    if (tid < BB * 6) {
        int b = tid / 6, cs = tid % 6;
        float s = 0.f;
        for (int c = 0; c < CC; c++) s += w1[cs * CC + c] * gap[b * CC + c];
        s1[tid] = fmaxf(s + b1[cs], 0.f);
    }
    __syncthreads();
    for (int idx = tid; idx < BB * CC; idx += 256) {
        int b = idx / CC, c = idx % CC;
        float s = b2[c];
        #pragma unroll
        for (int cs = 0; cs < 6; cs++) s += w2[c * 6 + cs] * s1[b * 6 + cs];
        ca[idx] = 1.f / (1.f + __expf(-s));
    }
}

// ---------------- x1(bf16) += 0.01*y4*ca; LN2 -> bf16 xn2 (stride 192) ----------------
__global__ __launch_bounds__(256) void resid_ln_kernel(
    ushortw* __restrict__ x1, const ushortw* __restrict__ y4, const float* __restrict__ ca,
    const float* __restrict__ g, const float* __restrict__ bb,
    ushortw* __restrict__ xn2)
{
    int wid = threadIdx.x >> 6, lane = threadIdx.x & 63;
    int t = blockIdx.x * 4 + wid;
    int b = t >> 14;
    size_t off = (size_t)t * CC;
    size_t off2 = (size_t)t * 192;
    bool has2 = lane < (CC - 128);
    float v0 = bf2f(x1[off+lane])    + 0.01f * bf2f(y4[off+lane])    * ca[b*CC + lane];
    float v1 = bf2f(x1[off+lane+64]) + 0.01f * bf2f(y4[off+lane+64]) * ca[b*CC + lane+64];
    float v2 = 0.f;
    if (has2) v2 = bf2f(x1[off+lane+128]) + 0.01f * bf2f(y4[off+lane+128]) * ca[b*CC + lane+128];
    x1[off+lane] = f2bf(v0); x1[off+lane+64] = f2bf(v1);
    if (has2) x1[off+lane+128] = f2bf(v2);
    float s = warp_sum(v0 + v1 + v2);
    float mu = s * (1.f / CC);
    float d0 = v0-mu, d1 = v1-mu, d2 = has2 ? v2-mu : 0.f;
    float var = warp_sum(d0*d0 + d1*d1 + d2*d2) * (1.f / CC);
    float rs = rsqrtf(var + 1e-5f);
    xn2[off2+lane]      = f2bf(d0 * rs * g[lane]      + bb[lane]);
    xn2[off2+lane+64]   = f2bf(d1 * rs * g[lane+64]   + bb[lane+64]);
    xn2[off2+lane+128]  = has2 ? f2bf(d2 * rs * g[lane+128] + bb[lane+128]) : (ushortw)0;
}

// ---------------- max/mean over channels per pixel (bf16 h3, stride 768, 720 cols) ----------------
__global__ __launch_bounds__(256) void mpap_kernel(
    const ushortw* __restrict__ h, float* __restrict__ mp, float* __restrict__ ap)
{
    int wid = threadIdx.x >> 6, lane = threadIdx.x & 63;
    int p = blockIdx.x * 4 + wid;
    const ushortw* row = h + (size_t)p * 768;
    float mx = -1e30f, s = 0.f;
    #pragma unroll
    for (int it = 0; it < 3; it++) {
        int j = (lane << 2) + it * 256;
        if (j < HID) {
            short4v v = *reinterpret_cast<const short4v*>(row + j);
            float f0 = bf2f((ushortw)v[0]), f1 = bf2f((ushortw)v[1]);
            float f2 = bf2f((ushortw)v[2]), f3 = bf2f((ushortw)v[3]);
            mx = fmaxf(mx, fmaxf(fmaxf(f0, f1), fmaxf(f2, f3)));
            s += (f0 + f1) + (f2 + f3);
        }
    }
    mx = warp_max(mx); s = warp_sum(s);
    if (lane == 0) { mp[p] = mx; ap[p] = s * (1.f / HID); }
}

// ---------------- 7x7 spatial-attention conv + sigmoid, LDS-tiled (16x16 tile + 22x22 halo) ----
__global__ __launch_bounds__(256) void saconv_kernel(
    const float* __restrict__ mp, const float* __restrict__ ap,
    const float* __restrict__ w, float* __restrict__ sa)
{
    __shared__ float smp[22][22];
    __shared__ float sap[22][22];
    int t = blockIdx.x;               // 0..127 (2 images x 64 tiles)
    int img = t >> 6;
    int ty = (t >> 3) & 7, tx = t & 7;
    int y0 = ty * 16 - 3, x0 = tx * 16 - 3;
    int tid = threadIdx.x;
    for (int i = tid; i < 22 * 22; i += 256) {
        int ly = i / 22, lx = i - ly * 22;
        int gy = y0 + ly, gx = x0 + lx;
        bool ok = (gy >= 0 && gy < HH && gx >= 0 && gx < WW);
        int pid = img * IMG + gy * WW + gx;
        smp[ly][lx] = ok ? mp[pid] : 0.f;
        sap[ly][lx] = ok ? ap[pid] : 0.f;
    }
    __syncthreads();
    int py = tid >> 4, px = tid & 15;
    float acc = 0.f;
    #pragma unroll
    for (int ky = 0; ky < 7; ky++) {
        #pragma unroll
        for (int kx = 0; kx < 7; kx++) {
            acc += smp[py + ky][px + kx] * w[ky * 7 + kx]
                 + sap[py + ky][px + kx] * w[49 + ky * 7 + kx];
        }
    }
    int p = img * IMG + (ty * 16 + py) * WW + (tx * 16 + px);
    sa[p] = 1.f / (1.f + __expf(-acc));
}

extern "C" void kernel_launch(void* const* d_in, const int* in_sizes, int n_in,
                              void* d_out, int out_size, void* d_ws, size_t ws_size,
                              hipStream_t stream)
{
    const float* x      = (const float*)d_in[0];
    const int*   rpi    = (const int*)d_in[3];
    const float* n1g    = (const float*)d_in[4];
    const float* n1b    = (const float*)d_in[5];
    const float* rpb    = (const float*)d_in[6];
    const float* qkv_w  = (const float*)d_in[7];
    const float* qkv_b  = (const float*)d_in[8];
    const float* proj_w = (const float*)d_in[9];
    const float* proj_b = (const float*)d_in[10];
    const float* cab_w0 = (const float*)d_in[11];
    const float* cab_b0 = (const float*)d_in[12];
    const float* cab_w1 = (const float*)d_in[13];
    const float* cab_b1 = (const float*)d_in[14];
    const float* cab_w2 = (const float*)d_in[15];
    const float* cab_b2 = (const float*)d_in[16];
    const float* cab_w3 = (const float*)d_in[17];
    const float* cab_b3 = (const float*)d_in[18];
    const float* ca_w1  = (const float*)d_in[19];
    const float* ca_b1  = (const float*)d_in[20];
    const float* ca_w2  = (const float*)d_in[21];
    const float* ca_b2  = (const float*)d_in[22];
    const float* n2g    = (const float*)d_in[23];
    const float* n2b    = (const float*)d_in[24];
    const float* fc1_w  = (const float*)d_in[25];
    const float* fc1_b  = (const float*)d_in[26];
    const float* dw_w   = (const float*)d_in[27];
    const float* dw_b   = (const float*)d_in[28];
    const float* pw_w   = (const float*)d_in[29];
    const float* pw_b   = (const float*)d_in[30];
    const float* sa_w   = (const float*)d_in[31];
    const float* fc2_w  = (const float*)d_in[32];
    const float* fc2_b  = (const float*)d_in[33];
    float* outp = (float*)d_out;
    (void)in_sizes; (void)n_in; (void)out_size; (void)ws_size;

    char* ws = (char*)d_ws;
    const size_t S0 = (size_t)NTOK * 192 * 2;            // xnb -> xn2b
    const size_t S1 = (size_t)NTOK * QKVSTR * 2 + 256;   // qkvP -> h1(half) -> h3(half)
    const size_t S2 = (size_t)NTOK * 192 * 2;            // attnbb -> y3b
    const size_t S3 = (size_t)NTOK * 180 * 2;            // x1b bf16
    const size_t S4 = (size_t)NTOK * 128 * 2;            // y2b ; h2(half) spans S4+S5
    const size_t S5 = (size_t)NTOK * 180 * 4;            // xb -> y4 bf16 (region kept for h2 span)
    char* pA0 = ws;
    char* pA1 = pA0 + S0;
    char* pA2 = pA1 + S1;
    char* pA3 = pA2 + S2;
    char* pA4 = pA3 + S3;
    char* pA5 = pA4 + S4;
    char* tail = pA5 + S5;

    ushortw* xnb    = (ushortw*)pA0;           // [NTOK][192]
    ushortw* xn2b   = (ushortw*)pA0;
    ushortw* qkvP   = (ushortw*)pA1;           // [NTOK][672] (cols 576.. = cab0 out)
    ushortw* h1     = (ushortw*)pA1;           // [HALFTOK][720]
    ushortw* h3     = (ushortw*)pA1;           // [HALFTOK][768]
    ushortw* attnbb = (ushortw*)pA2;           // [NTOK][192]
    ushortw* y3b    = (ushortw*)pA2;           // [NTOK][192]
    ushortw* x1b    = (ushortw*)pA3;           // [NTOK][180] bf16
    ushortw* y2b    = (ushortw*)pA4;           // [NTOK][128]
    ushortw* h2     = (ushortw*)pA4;           // [HALFTOK][768] spans S4+S5
    ushortw* xb     = (ushortw*)pA5;           // [NTOK][180] bf16 (x copy; dead after proj)
    ushortw* y4     = (ushortw*)pA5;           // [NTOK][180] bf16 (written by dw2, after proj)

    // bf16 gemm weights
    ushortw* wqkvc = (ushortw*)tail;                        // 672 x 192
    ushortw* wproj = wqkvc + 672 * 192;                     // 256 x 192
    ushortw* wcab2 = wproj + 256 * 192;                     // 256 x 128
    ushortw* wfc1  = wcab2 + 256 * 128;                     // 768 x 192
    ushortw* wpw   = wfc1  + 768 * 192;                     // 768 x 768
    ushortw* wfc2  = wpw   + 768 * 768;                     // 256 x 768
    char* tail2 = (char*)(wfc2 + 256 * 768);
    float* dwt1 = (float*)tail2;                 float* db1 = dwt1 + 9*128;
    float* dwt2 = db1 + 128;                     float* db2 = dwt2 + 9*192;
    float* dwt3 = db2 + 192;                     float* db3 = dwt3 + 9*768;
    float* qb672 = db3 + 768;
    char* tail3 = (char*)(qb672 + 672);
    float* biasN = (float*)tail3;                           // 6*65536 fp32
    float* part  = (float*)(tail3 + 1572864);               // 4*128*180 fp32
    float* cabuf = (float*)(tail3 + 1572864 + 393216);
    float* mp    = (float*)(tail3 + 1572864 + 393216 + 4096);
    float* ap    = (float*)(tail3 + 1572864 + 393216 + 4096 + (size_t)HALFTOK * 4);
    float* sab   = (float*)(tail3 + 1572864 + 393216 + 4096 + 2*(size_t)HALFTOK * 4);

    auto gemm = [&](const ushortw* A, const ushortw* Wt, const float* bi, void* Cp,
                    int M, int N, int Kp, int ldc, int outbf, int zfill, int act, int residbf,
                    const float* rs, const void* resid) {
        int nM = M >> 7, nN = (N + 127) >> 7;
        mgemm_kernel<<<dim3(nM * nN), dim3(256), 0, stream>>>(
            A, Wt, bi, Cp, M, N, Kp, ldc, outbf, zfill, act, residbf, nN, rs, resid);
    };

    // 0) all weight/bias prep in one launch
    prep_kernel<<<dim3((1220832 + 255) / 256), dim3(256), 0, stream>>>(
        qkv_w, proj_w, cab_w0, cab_b0, cab_w2, fc1_w, pw_w, fc2_w,
        cab_w1, cab_b1, cab_w3, cab_b3, dw_w, dw_b, qkv_b, rpi, rpb,
        wqkvc, wproj, wcab2, wfc1, wpw, wfc2,
        dwt1, db1, dwt2, db2, dwt3, db3, qb672, biasN);

    // 1) LN1 -> bf16 xnb (+ bf16 copy of x for proj residual)
    ln_kernel<<<dim3(NTOK / 4), dim3(256), 0, stream>>>(x, n1g, n1b, xnb, xb);
    // 2) merged qkv+cab0 GEMM -> qkvP[NTOK][672]; then attention + CAB dwconv1
    gemm(xnb, wqkvc, qb672, qkvP, NTOK, 672, 192, QKVSTR, 1, 0, 0, 0, nullptr, nullptr);
    attn_mfma_kernel<<<dim3(BB * 64 * NHEADS), dim3(256), 0, stream>>>(qkvP, biasN, attnbb);
    dwconv4_kernel<672, 128, 128, 1, 1, 1><<<dim3(NTOK / 4 * 32 / 256), dim3(256), 0, stream>>>(
        qkvP + 576, dwt1, db1, y2b);
    // 3) proj with bf16 residual xb -> x1b (bf16)
    gemm(attnbb, wproj, proj_b, x1b, NTOK, 180, 192, 180, 1, 0, 0, 1, nullptr, xb);
    // 4) CAB part 2 (y4 overwrites xb region -- xb dead after proj)
    gemm(y2b, wcab2, cab_b2, y3b, NTOK, 180, 128, 192, 1, 1, 0, 0, nullptr, nullptr);
    dwconv4_kernel<192, 192, 180, 2, 0, 1><<<dim3(NTOK / 4 * 48 / 256), dim3(256), 0, stream>>>(
        y3b, dwt2, db2, y4);
    gap_kernel<<<dim3(BB * 128), dim3(192), 0, stream>>>(y4, part);
    ca_kernel<<<dim3(1), dim3(256), 0, stream>>>(part, ca_w1, ca_b1, ca_w2, ca_b2, cabuf);
    // 5) x1 += 0.01*y4*ca; LN2 -> bf16 xn2b
    resid_ln_kernel<<<dim3(NTOK / 4), dim3(256), 0, stream>>>(x1b, y4, cabuf, n2g, n2b, xn2b);
    // 6) FFN in two half-batches (2 images each)
    for (int half = 0; half < 2; half++) {
        size_t toff = (size_t)half * HALFTOK;
        gemm(xn2b + toff * 192, wfc1, fc1_b, h1, HALFTOK, 720, 192, 720, 1, 0, 1, 0, nullptr, nullptr);
        dwconv4_kernel<720, 768, 768, 1, 2, 1><<<dim3(HALFTOK / 4 * 192 / 256), dim3(256), 0, stream>>>(
            h1, dwt3, db3, h2);
        gemm(h2, wpw, pw_b, h3, HALFTOK, 720, 768, 768, 1, 1, 2, 0, nullptr, nullptr);
        mpap_kernel<<<dim3(HALFTOK / 4), dim3(256), 0, stream>>>(h3, mp, ap);
        saconv_kernel<<<dim3(128), dim3(256), 0, stream>>>(mp, ap, sa_w, sab);
        gemm(h3, wfc2, fc2_b, outp + toff * 180, HALFTOK, 180, 768, 180, 0, 0, 0, 1,
             sab, x1b + toff * 180);
    }
}

// Round 24
// 616.956 us; speedup vs baseline: 1.1072x; 1.0013x over previous
//
#include <hip/hip_runtime.h>
#include <math.h>

#define HH 128
#define WW 128
#define CC 180
#define BB 4
#define IMG (HH*WW)          // 16384 tokens per image
#define NTOK (BB*IMG)        // 65536
#define HALFTOK (2*IMG)      // 32768
#define NHEADS 6
#define HD 30
#define WSZ 16
#define NTOKW (WSZ*WSZ)      // 256
#define HID 720
#define QKVSTR 672           // merged row: q/k/v (3x192) + cab0 (96)

typedef __attribute__((ext_vector_type(8))) short short8v;
typedef __attribute__((ext_vector_type(4))) short short4v;
typedef __attribute__((ext_vector_type(4))) float f32x4;
typedef unsigned short ushortw;

__device__ __forceinline__ float warp_sum(float v) {
    #pragma unroll
    for (int o = 32; o > 0; o >>= 1) v += __shfl_xor(v, o);
    return v;
}
__device__ __forceinline__ float warp_max(float v) {
    #pragma unroll
    for (int o = 32; o > 0; o >>= 1) v = fmaxf(v, __shfl_xor(v, o));
    return v;
}
__device__ __forceinline__ float gelu_exact(float v) {
    return 0.5f * v * (1.f + erff(v * 0.70710678118654752f));
}
__device__ __forceinline__ ushortw f2bf(float f) {
    union { float f; unsigned int u; } c; c.f = f;
    unsigned int r = (c.u + 0x7FFFu + ((c.u >> 16) & 1u)) >> 16;
    return (ushortw)r;
}
__device__ __forceinline__ float bf2f(ushortw u) {
    union { unsigned int u; float f; } c; c.u = ((unsigned int)u) << 16; return c.f;
}

// ---------------- fused weight/bias prep (one launch) ----------------
__global__ __launch_bounds__(256) void prep_kernel(
    const float* __restrict__ qkv_w, const float* __restrict__ proj_w,
    const float* __restrict__ cab_w0, const float* __restrict__ cab_b0,
    const float* __restrict__ cab_w2,
    const float* __restrict__ fc1_w, const float* __restrict__ pw_w,
    const float* __restrict__ fc2_w,
    const float* __restrict__ cab_w1, const float* __restrict__ cab_b1,
    const float* __restrict__ cab_w3, const float* __restrict__ cab_b3,
    const float* __restrict__ dw_w, const float* __restrict__ dw_b,
    const float* __restrict__ qkv_b, const int* __restrict__ rpi,
    const float* __restrict__ rpb,
    ushortw* __restrict__ wqkvc, ushortw* __restrict__ wproj,
    ushortw* __restrict__ wcab2,
    ushortw* __restrict__ wfc1, ushortw* __restrict__ wpw, ushortw* __restrict__ wfc2,
    float* __restrict__ dwt1, float* __restrict__ db1,
    float* __restrict__ dwt2, float* __restrict__ db2,
    float* __restrict__ dwt3, float* __restrict__ db3,
    float* __restrict__ qb672, float* __restrict__ biasN)
{
    int idx = blockIdx.x * 256 + threadIdx.x;
    if (idx < 129024) {                              // J0: wqkvc [672][192]
        int r = idx / 192, k = idx - r * 192;
        float v = 0.f;
        if (r < 576) {
            int sub = r / 192, rem = r - sub * 192;
            int hh = rem >> 5, dd = rem & 31;
            if (dd < 30 && k < 180) v = qkv_w[(sub * 180 + hh * 30 + dd) * 180 + k];
        } else if (r < 666) {
            if (k < 180) v = cab_w0[(r - 576) * 180 + k];
        }
        wqkvc[idx] = f2bf(v);
    } else if (idx < 178176) {                       // J1: wproj [256][192]
        int l = idx - 129024; int r = l / 192, k = l - r * 192;
        wproj[l] = f2bf((r < 180 && k < 180) ? proj_w[r * 180 + k] : 0.f);
    } else if (idx < 210944) {                       // J2: wcab2 [256][128]
        int l = idx - 178176; int r = l / 128, k = l - r * 128;
        wcab2[l] = f2bf((r < 180 && k < 90) ? cab_w2[r * 90 + k] : 0.f);
    } else if (idx < 358400) {                       // J3: wfc1 [768][192]
        int l = idx - 210944; int r = l / 192, k = l - r * 192;
        wfc1[l] = f2bf((r < 720 && k < 180) ? fc1_w[r * 180 + k] : 0.f);
    } else if (idx < 948224) {                       // J4: wpw [768][768]
        int l = idx - 358400; int r = l / 768, k = l - r * 768;
        wpw[l] = f2bf((r < 720 && k < 720) ? pw_w[r * 720 + k] : 0.f);
    } else if (idx < 1144832) {                      // J5: wfc2 [256][768]
        int l = idx - 948224; int r = l / 768, k = l - r * 768;
        wfc2[l] = f2bf((r < 180 && k < 720) ? fc2_w[r * 720 + k] : 0.f);
    } else if (idx < 1145984) {                      // J6: dwt1 [9][128]
        int l = idx - 1144832; int c = l / 9, k = l - c * 9;
        dwt1[k * 128 + c] = (c < 90) ? cab_w1[c * 9 + k] : 0.f;
        if (k == 0) db1[c] = (c < 90) ? cab_b1[c] : 0.f;
    } else if (idx < 1147712) {                      // J7: dwt2 [9][192]
        int l = idx - 1145984; int c = l / 9, k = l - c * 9;
        dwt2[k * 192 + c] = (c < 180) ? cab_w3[c * 9 + k] : 0.f;
        if (k == 0) db2[c] = (c < 180) ? cab_b3[c] : 0.f;
    } else if (idx < 1154624) {                      // J8: dwt3 [9][768]
        int l = idx - 1147712; int c = l / 9, k = l - c * 9;
        dwt3[k * 768 + c] = (c < 720) ? dw_w[c * 9 + k] : 0.f;
        if (k == 0) db3[c] = (c < 720) ? dw_b[c] : 0.f;
    } else if (idx < 1155296) {                      // J9: qb672
        int l = idx - 1154624;
        float v = 0.f;
        if (l < 576) {
            int sub = l / 192, rem = l - sub * 192;
            int hh = rem >> 5, dd = rem & 31;
            if (dd < 30) v = qkv_b[sub * 180 + hh * 30 + dd];
        } else if (l < 666) {
            v = cab_b0[l - 576];
        }
        qb672[l] = v;
    } else if (idx < 1220832) {                      // J10: biasN [6][65536]
        int l = idx - 1155296;
        int r = rpi[l];
        #pragma unroll
        for (int h = 0; h < NHEADS; h++)
            biasN[((size_t)h << 16) + l] = rpb[r * NHEADS + h];
    }
}

// ---------------- LayerNorm -> bf16 xn (stride 192, pads 0) + bf16 copy of x ----------------
__global__ __launch_bounds__(256) void ln_kernel(
    const float* __restrict__ x, const float* __restrict__ g,
    const float* __restrict__ b, ushortw* __restrict__ out, ushortw* __restrict__ xb)
{
    int wid = threadIdx.x >> 6, lane = threadIdx.x & 63;
    int t = blockIdx.x * 4 + wid;
    size_t off = (size_t)t * CC;
    size_t off2 = (size_t)t * 192;
    bool has2 = lane < (CC - 128);
    float v0 = x[off + lane];
    float v1 = x[off + lane + 64];
    float v2 = has2 ? x[off + lane + 128] : 0.f;
    xb[off + lane] = f2bf(v0);
    xb[off + lane + 64] = f2bf(v1);
    if (has2) xb[off + lane + 128] = f2bf(v2);
    float s = warp_sum(v0 + v1 + v2);
    float mu = s * (1.f / CC);
    float d0 = v0 - mu, d1 = v1 - mu, d2 = has2 ? v2 - mu : 0.f;
    float var = warp_sum(d0*d0 + d1*d1 + d2*d2) * (1.f / CC);
    float rs = rsqrtf(var + 1e-5f);
    out[off2 + lane]      = f2bf(d0 * rs * g[lane]      + b[lane]);
    out[off2 + lane + 64] = f2bf(d1 * rs * g[lane + 64] + b[lane + 64]);
    out[off2 + lane + 128] = has2 ? f2bf(d2 * rs * g[lane + 128] + b[lane + 128]) : (ushortw)0;
}

// ---------------- bf16 MFMA GEMM: BK=32 dbuf + XOR swizzle + transposed-acc epilogue ----------
__global__ __launch_bounds__(256) void mgemm_kernel(
    const ushortw* __restrict__ A, const ushortw* __restrict__ Wt,
    const float* __restrict__ bias, void* __restrict__ Cout,
    int M, int N, int Kp, int ldc, int outbf, int zfill, int act, int residbf, int nN,
    const float* __restrict__ rowscale, const void* __restrict__ residv)
{
    __shared__ ushortw sA[2][128 * 32];
    __shared__ ushortw sB[2][128 * 32];
    int tid = threadIdx.x, lane = tid & 63, wid = tid >> 6;
    int total = (int)gridDim.x;
    int orig = blockIdx.x;
    int q = total >> 3, r = total & 7;
    int xcd = orig & 7, slot = orig >> 3;
    int wgid = (xcd < r ? xcd * (q + 1) : r * (q + 1) + (xcd - r) * q) + slot;
    int mp = wgid / nN, np = wgid - mp * nN;
    int m0 = mp << 7, n0 = np << 7;
    int wm = (wid >> 1) << 6, wn = (wid & 1) << 6;
    int lrow = lane & 15, kgrp = lane >> 4;

    f32x4 acc[4][4];
    #pragma unroll
    for (int i = 0; i < 4; i++)
        #pragma unroll
        for (int j = 0; j < 4; j++)
            #pragma unroll
            for (int rr = 0; rr < 4; rr++) acc[i][j][rr] = 0.f;

    int nk = Kp >> 5;
    #pragma unroll
    for (int qq = 0; qq < 2; qq++) {
        int seg = (wid << 1) + qq;                 // 0..7
        int row = (seg << 4) + (lane >> 2);        // 0..127
        int cg = (lane & 3) ^ (row & 3) ^ ((row >> 2) & 3);
        const ushortw* ga = A + (size_t)(m0 + row) * Kp + (cg << 3);
        __builtin_amdgcn_global_load_lds(
            (const __attribute__((address_space(1))) void*)ga,
            (__attribute__((address_space(3))) void*)&sA[0][seg << 9], 16, 0, 0);
        const ushortw* gb = Wt + (size_t)(n0 + row) * Kp + (cg << 3);
        __builtin_amdgcn_global_load_lds(
            (const __attribute__((address_space(1))) void*)gb,
            (__attribute__((address_space(3))) void*)&sB[0][seg << 9], 16, 0, 0);
    }
    __syncthreads();

    int cur = 0;
    for (int t = 0; t < nk; t++) {
        if (t + 1 < nk) {
            int kk2 = (t + 1) << 5;
            #pragma unroll
            for (int qq = 0; qq < 2; qq++) {
                int seg = (wid << 1) + qq;
                int row = (seg << 4) + (lane >> 2);
                int cg = (lane & 3) ^ (row & 3) ^ ((row >> 2) & 3);
                const ushortw* ga = A + (size_t)(m0 + row) * Kp + kk2 + (cg << 3);
                __builtin_amdgcn_global_load_lds(
                    (const __attribute__((address_space(1))) void*)ga,
                    (__attribute__((address_space(3))) void*)&sA[cur ^ 1][seg << 9], 16, 0, 0);
                const ushortw* gb = Wt + (size_t)(n0 + row) * Kp + kk2 + (cg << 3);
                __builtin_amdgcn_global_load_lds(
                    (const __attribute__((address_space(1))) void*)gb,
                    (__attribute__((address_space(3))) void*)&sB[cur ^ 1][seg << 9], 16, 0, 0);
            }
        }
        short8v a[4], b[4];
        #pragma unroll
        for (int i = 0; i < 4; i++) {
            int rr = wm + (i << 4) + lrow;
            int slot2 = kgrp ^ (rr & 3) ^ ((rr >> 2) & 3);
            a[i] = *reinterpret_cast<const short8v*>(&sA[cur][(rr << 5) + (slot2 << 3)]);
        }
        #pragma unroll
        for (int j = 0; j < 4; j++) {
            int rr = wn + (j << 4) + lrow;
            int slot2 = kgrp ^ (rr & 3) ^ ((rr >> 2) & 3);
            b[j] = *reinterpret_cast<const short8v*>(&sB[cur][(rr << 5) + (slot2 << 3)]);
        }
        #pragma unroll
        for (int i = 0; i < 4; i++)
            #pragma unroll
            for (int j = 0; j < 4; j++)
                acc[i][j] = __builtin_amdgcn_mfma_f32_16x16x32_bf16(b[j], a[i], acc[i][j], 0, 0, 0);
        __syncthreads();
        cur ^= 1;
    }
    // transposed-acc epilogue: row = token (lane), 4 consecutive cols per reg
    #pragma unroll
    for (int i = 0; i < 4; i++) {
        int row = m0 + wm + (i << 4) + lrow;
        float rsv = rowscale ? rowscale[row] : 1.f;
        #pragma unroll
        for (int j = 0; j < 4; j++) {
            int colb = n0 + wn + (j << 4) + (kgrp << 2);
            if (colb < N) {
                float4 bi4 = *reinterpret_cast<const float4*>(bias + colb);
                float vv[4];
                vv[0] = acc[i][j][0]; vv[1] = acc[i][j][1];
                vv[2] = acc[i][j][2]; vv[3] = acc[i][j][3];
                if (rowscale) {
                    vv[0] *= rsv; vv[1] *= rsv; vv[2] *= rsv; vv[3] *= rsv;
                }
                vv[0] += bi4.x; vv[1] += bi4.y; vv[2] += bi4.z; vv[3] += bi4.w;
                if (act == 1) {
                    vv[0] = gelu_exact(vv[0]); vv[1] = gelu_exact(vv[1]);
                    vv[2] = gelu_exact(vv[2]); vv[3] = gelu_exact(vv[3]);
                } else if (act == 2) {
                    vv[0] = fmaxf(vv[0], 0.f); vv[1] = fmaxf(vv[1], 0.f);
                    vv[2] = fmaxf(vv[2], 0.f); vv[3] = fmaxf(vv[3], 0.f);
                }
                if (residv) {
                    if (residbf) {
                        short4v rv = *reinterpret_cast<const short4v*>(
                            (const ushortw*)residv + (size_t)row * N + colb);
                        vv[0] += bf2f((ushortw)rv[0]); vv[1] += bf2f((ushortw)rv[1]);
                        vv[2] += bf2f((ushortw)rv[2]); vv[3] += bf2f((ushortw)rv[3]);
                    } else {
                        float4 rv = *reinterpret_cast<const float4*>(
                            (const float*)residv + (size_t)row * N + colb);
                        vv[0] += rv.x; vv[1] += rv.y; vv[2] += rv.z; vv[3] += rv.w;
                    }
                }
                if (outbf) {
                    short4v o;
                    o[0] = (short)f2bf(vv[0]); o[1] = (short)f2bf(vv[1]);
                    o[2] = (short)f2bf(vv[2]); o[3] = (short)f2bf(vv[3]);
                    *reinterpret_cast<short4v*>((ushortw*)Cout + (size_t)row * ldc + colb) = o;
                } else {
                    float4 o = make_float4(vv[0], vv[1], vv[2], vv[3]);
                    *reinterpret_cast<float4*>((float*)Cout + (size_t)row * ldc + colb) = o;
                }
            } else if (zfill && colb < ldc) {
                if (outbf) {
                    short4v o; o[0] = 0; o[1] = 0; o[2] = 0; o[3] = 0;
                    *reinterpret_cast<short4v*>((ushortw*)Cout + (size_t)row * ldc + colb) = o;
                } else {
                    *reinterpret_cast<float4*>((float*)Cout + (size_t)row * ldc + colb) =
                        make_float4(0.f, 0.f, 0.f, 0.f);
                }
            }
        }
    }
}

// ---------------- MFMA window attention (swapped QK^T): block = (img, win, head) ----------------
// r22-proven config + bias loads hoisted ahead of the QK MFMA cluster (latency hides under MFMA).
__global__ __launch_bounds__(256, 3) void attn_mfma_kernel(
    const ushortw* __restrict__ qkvP, const float* __restrict__ biasN,
    ushortw* __restrict__ out)
{
    __shared__ ushortw Vc[32 * 33 * 8];      // 16896 B
    __shared__ ushortw Kc[256 * 32];         // 16384 B
    __shared__ ushortw Pl[4][2048];          // 16384 B
    const float SCALE = 0.18257418583505536f;   // 30^-0.5
    int blk = blockIdx.x;
    int img = blk / 384;
    int rem = blk - img * 384;
    int win = rem / NHEADS;
    int h = rem - win * NHEADS;
    int base = img * IMG + (win >> 3) * WSZ * WW + (win & 7) * WSZ;
    int tid = threadIdx.x;
    int lane = tid & 63, w = tid >> 6;
    int a15 = lane & 15, kg = lane >> 4;

    {
        int j = tid;
        int g = base + (j >> 4) * WW + (j & 15);
        const ushortw* vp = qkvP + (size_t)g * QKVSTR + 384 + h * 32;
        short8v c0 = *reinterpret_cast<const short8v*>(vp);
        short8v c1 = *reinterpret_cast<const short8v*>(vp + 8);
        short8v c2 = *reinterpret_cast<const short8v*>(vp + 16);
        short8v c3 = *reinterpret_cast<const short8v*>(vp + 24);
        int bo = (j >> 3) * 264 + (j & 7);
        #pragma unroll
        for (int e = 0; e < 8; e++)  Vc[bo + (e) * 8]      = (ushortw)c0[e];
        #pragma unroll
        for (int e = 0; e < 8; e++)  Vc[bo + (8 + e) * 8]  = (ushortw)c1[e];
        #pragma unroll
        for (int e = 0; e < 8; e++)  Vc[bo + (16 + e) * 8] = (ushortw)c2[e];
        #pragma unroll
        for (int e = 0; e < 8; e++)  Vc[bo + (24 + e) * 8] = (ushortw)c3[e];
        const ushortw* kp = qkvP + (size_t)g * QKVSTR + 192 + h * 32;
        short8v k0 = *reinterpret_cast<const short8v*>(kp);
        short8v k1 = *reinterpret_cast<const short8v*>(kp + 8);
        short8v k2 = *reinterpret_cast<const short8v*>(kp + 16);
        short8v k3 = *reinterpret_cast<const short8v*>(kp + 24);
        short8v* krow = reinterpret_cast<short8v*>(&Kc[j * 32]);
        int jsw = (j >> 1) & 3;
        krow[0 ^ jsw] = k0; krow[1 ^ jsw] = k1; krow[2 ^ jsw] = k2; krow[3 ^ jsw] = k3;
    }
    __syncthreads();

    ushortw* Pw = &Pl[w][0];
    int xsw = (a15 & 7) << 2;                // P dword-XOR per q-row
    f32x4 zf = {0.f, 0.f, 0.f, 0.f};
    #pragma unroll 1
    for (int si = 0; si < 4; si++) {
        int strip = (w << 2) + si;
        short8v qf = *reinterpret_cast<const short8v*>(
            qkvP + (size_t)(base + strip * WW + a15) * QKVSTR + h * 32 + (kg << 3));
        float psum = 0.f;
        f32x4 o0 = zf, o1 = zf;
        const float* brow = biasN + ((size_t)h << 16) + (size_t)((strip << 4) + a15) * 256;
        #pragma unroll
        for (int half = 0; half < 2; half++) {
            // hoist bias loads: in flight during the QK MFMA cluster
            float4 b4s[8];
            #pragma unroll
            for (int j8 = 0; j8 < 8; j8++) {
                int jt = (half << 3) + j8;
                b4s[j8] = *reinterpret_cast<const float4*>(brow + (jt << 4) + (kg << 2));
            }
            f32x4 s[8];
            __builtin_amdgcn_s_setprio(1);
            #pragma unroll
            for (int j8 = 0; j8 < 8; j8++) {
                int jt = (half << 3) + j8;
                int row = (jt << 4) + a15;
                short8v ka = reinterpret_cast<const short8v*>(&Kc[row * 32])[kg ^ ((row >> 1) & 3)];
                s[j8] = __builtin_amdgcn_mfma_f32_16x16x32_bf16(ka, qf, zf, 0, 0, 0);
            }
            __builtin_amdgcn_s_setprio(0);
            #pragma unroll
            for (int j8 = 0; j8 < 8; j8++) {
                float p0 = __expf(fmaf(s[j8][0], SCALE, b4s[j8].x));
                float p1 = __expf(fmaf(s[j8][1], SCALE, b4s[j8].y));
                float p2 = __expf(fmaf(s[j8][2], SCALE, b4s[j8].z));
                float p3 = __expf(fmaf(s[j8][3], SCALE, b4s[j8].w));
                psum += (p0 + p1) + (p2 + p3);
                unsigned int u0, u1;
                asm("v_cvt_pk_bf16_f32 %0, %1, %2" : "=v"(u0) : "v"(p0), "v"(p1));
                asm("v_cvt_pk_bf16_f32 %0, %1, %2" : "=v"(u1) : "v"(p2), "v"(p3));
                int dw0 = ((j8 << 3) + (kg << 1)) ^ xsw;
                unsigned long long pk64 = (unsigned long long)u0 | ((unsigned long long)u1 << 32);
                *reinterpret_cast<unsigned long long*>(&Pw[(a15 << 7) + (dw0 << 1)]) = pk64;
            }
            __builtin_amdgcn_s_setprio(1);
            #pragma unroll
            for (int ks4 = 0; ks4 < 4; ks4++) {
                int dwr = ((ks4 << 4) + (kg << 2)) ^ xsw;
                short8v pa = *reinterpret_cast<const short8v*>(&Pw[(a15 << 7) + (dwr << 1)]);
                int kc = (((half << 2) + ks4) << 2) + kg;
                short8v v0 = *reinterpret_cast<const short8v*>(&Vc[(kc * 33 + a15) * 8]);
                short8v v1 = *reinterpret_cast<const short8v*>(&Vc[(kc * 33 + 16 + a15) * 8]);
                o0 = __builtin_amdgcn_mfma_f32_16x16x32_bf16(pa, v0, o0, 0, 0, 0);
                o1 = __builtin_amdgcn_mfma_f32_16x16x32_bf16(pa, v1, o1, 0, 0, 0);
            }
            __builtin_amdgcn_s_setprio(0);
        }
        psum += __shfl_xor(psum, 16);
        psum += __shfl_xor(psum, 32);
        #pragma unroll
        for (int r = 0; r < 4; r++) {
            float pt = __shfl(psum, (kg << 2) + r);
            float inv = 1.f / pt;
            int g = base + strip * WW + (kg << 2) + r;
            ushortw* orow = out + (size_t)g * 192 + h * HD;
            orow[a15] = f2bf(o0[r] * inv);
            if (a15 < 14) orow[16 + a15] = f2bf(o1[r] * inv);
        }
    }
    if (h == 0) {   // zero pad cols 180..191
        for (int idx2 = tid; idx2 < NTOKW * 12; idx2 += 256) {
            int j = idx2 / 12, d = idx2 - (idx2 / 12) * 12;
            int gj = base + (j >> 4) * WW + (j & 15);
            out[(size_t)gj * 192 + 180 + d] = 0;
        }
    }
}

// ---------------- register-tiled depthwise 3x3 conv: 4 pixels x 4 channels / thread ----------------
template<int CIN_S, int COP, int OSTR, int DIL, int ACT, int OUTBF>
__global__ __launch_bounds__(256) void dwconv4_kernel(
    const ushortw* __restrict__ in, const float* __restrict__ wt,
    const float* __restrict__ bias, void* __restrict__ out)
{
    constexpr int NC4 = COP >> 2;
    constexpr int NX = 4 + 2 * DIL;
    int idx = blockIdx.x * 256 + threadIdx.x;
    int c4 = idx % NC4;
    int quad = idx / NC4;
    int c = c4 << 2;
    int pix0 = quad << 2;
    int p = pix0 & (IMG - 1);
    int imgbase = pix0 - p;
    int px0 = p & (WW - 1), py = p >> 7;

    float4 w9[9];
    #pragma unroll
    for (int t = 0; t < 9; t++)
        w9[t] = *reinterpret_cast<const float4*>(wt + t * COP + c);
    float4 bi4 = *reinterpret_cast<const float4*>(bias + c);
    float acc[4][4];
    #pragma unroll
    for (int i = 0; i < 4; i++) {
        acc[i][0] = bi4.x; acc[i][1] = bi4.y; acc[i][2] = bi4.z; acc[i][3] = bi4.w;
    }
    #pragma unroll
    for (int ky = 0; ky < 3; ky++) {
        int iy = py + (ky - 1) * DIL;
        if (iy < 0 || iy >= HH) continue;
        const ushortw* rowp = in + (size_t)(imgbase + (iy << 7)) * CIN_S + c;
        #pragma unroll
        for (int xx = 0; xx < NX; xx++) {
            int ix = px0 + xx - DIL;
            if (ix < 0 || ix >= WW) continue;
            short4v v = *reinterpret_cast<const short4v*>(rowp + (size_t)ix * CIN_S);
            float f0 = bf2f((ushortw)v[0]);
            float f1 = bf2f((ushortw)v[1]);
            float f2 = bf2f((ushortw)v[2]);
            float f3 = bf2f((ushortw)v[3]);
            #pragma unroll
            for (int kx = 0; kx < 3; kx++) {
                int i = xx - DIL * kx;
                if (i < 0 || i > 3) continue;
                float4 wv = w9[ky * 3 + kx];
                acc[i][0] = fmaf(f0, wv.x, acc[i][0]);
                acc[i][1] = fmaf(f1, wv.y, acc[i][1]);
                acc[i][2] = fmaf(f2, wv.z, acc[i][2]);
                acc[i][3] = fmaf(f3, wv.w, acc[i][3]);
            }
        }
    }
    if (COP != OSTR && c >= OSTR) return;
    #pragma unroll
    for (int i = 0; i < 4; i++) {
        #pragma unroll
        for (int e = 0; e < 4; e++) {
            float v = acc[i][e];
            if (ACT == 1) v = gelu_exact(v);
            else if (ACT == 2) v = fmaxf(v, 0.f);
            acc[i][e] = v;
        }
        if (OUTBF) {
            short4v o;
            o[0] = (short)f2bf(acc[i][0]); o[1] = (short)f2bf(acc[i][1]);
            o[2] = (short)f2bf(acc[i][2]); o[3] = (short)f2bf(acc[i][3]);
            *reinterpret_cast<short4v*>((ushortw*)out + (size_t)(pix0 + i) * OSTR + c) = o;
        } else {
            float4 o = make_float4(acc[i][0], acc[i][1], acc[i][2], acc[i][3]);
            *reinterpret_cast<float4*>((float*)out + (size_t)(pix0 + i) * OSTR + c) = o;
        }
    }
}

// ---------------- GAP partial sums over bf16 y4 (128-pixel chunks, 512 blocks) ----------------
__global__ void gap_kernel(const ushortw* __restrict__ y, float* __restrict__ part)
{
    int blk = blockIdx.x;              // 0..511
    int b = blk >> 7, chunk = blk & 127;
    int c = threadIdx.x;
    if (c >= CC) return;
    size_t basep = ((size_t)b * IMG + (size_t)chunk * 128) * CC;
    float s = 0.f;
    for (int p = 0; p < 128; p++) s += bf2f(y[basep + (size_t)p * CC + c]);
    part[((size_t)b * 128 + chunk) * CC + c] = s;
}

// ---------------- channel attention (tiny) ----------------
__global__ void ca_kernel(const float* __restrict__ part,
                          const float* __restrict__ w1, const float* __restrict__ b1,
                          const float* __restrict__ w2, const float* __restrict__ b2,
                          float* __restrict__ ca)
{
    __shared__ float gap[BB * CC];
    __shared__ float s1[BB * 6];
    int tid = threadIdx.x;
    for (int idx = tid; idx < BB * CC; idx += 256) {
        int b = idx / CC, c = idx % CC;
        float s = 0.f;
        for (int ch = 0; ch < 128; ch++) s += part[((size_t)b * 128 + ch) * CC + c];
        gap[idx] = s * (1.f / IMG);
    }
    __syncthreads();
    if (tid < BB * 6) {
        int b = tid / 6, cs = tid % 6;
        float s = 0.f;
        for (int c = 0; c < CC; c++) s += w1[cs * CC + c] * gap[b * CC + c];
        s1[tid] = fmaxf(s + b1[cs], 0.f);
    }
    __syncthreads();
    for (int idx = tid; idx < BB * CC; idx += 256) {
        int b = idx / CC, c = idx % CC;
        float s = b2[c];
        #pragma unroll
        for (int cs = 0; cs < 6; cs++) s += w2[c * 6 + cs] * s1[b * 6 + cs];
        ca[idx] = 1.f / (1.f + __expf(-s));
    }
}

// ---------------- x1(bf16) += 0.01*y4*ca; LN2 -> bf16 xn2 (stride 192) ----------------
__global__ __launch_bounds__(256) void resid_ln_kernel(
    ushortw* __restrict__ x1, const ushortw* __restrict__ y4, const float* __restrict__ ca,
    const float* __restrict__ g, const float* __restrict__ bb,
    ushortw* __restrict__ xn2)
{
    int wid = threadIdx.x >> 6, lane = threadIdx.x & 63;
    int t = blockIdx.x * 4 + wid;
    int b = t >> 14;
    size_t off = (size_t)t * CC;
    size_t off2 = (size_t)t * 192;
    bool has2 = lane < (CC - 128);
    float v0 = bf2f(x1[off+lane])    + 0.01f * bf2f(y4[off+lane])    * ca[b*CC + lane];
    float v1 = bf2f(x1[off+lane+64]) + 0.01f * bf2f(y4[off+lane+64]) * ca[b*CC + lane+64];
    float v2 = 0.f;
    if (has2) v2 = bf2f(x1[off+lane+128]) + 0.01f * bf2f(y4[off+lane+128]) * ca[b*CC + lane+128];
    x1[off+lane] = f2bf(v0); x1[off+lane+64] = f2bf(v1);
    if (has2) x1[off+lane+128] = f2bf(v2);
    float s = warp_sum(v0 + v1 + v2);
    float mu = s * (1.f / CC);
    float d0 = v0-mu, d1 = v1-mu, d2 = has2 ? v2-mu : 0.f;
    float var = warp_sum(d0*d0 + d1*d1 + d2*d2) * (1.f / CC);
    float rs = rsqrtf(var + 1e-5f);
    xn2[off2+lane]      = f2bf(d0 * rs * g[lane]      + bb[lane]);
    xn2[off2+lane+64]   = f2bf(d1 * rs * g[lane+64]   + bb[lane+64]);
    xn2[off2+lane+128]  = has2 ? f2bf(d2 * rs * g[lane+128] + bb[lane+128]) : (ushortw)0;
}

// ---------------- max/mean over channels per pixel (bf16 h3, stride 768, 720 cols) ----------------
__global__ __launch_bounds__(256) void mpap_kernel(
    const ushortw* __restrict__ h, float* __restrict__ mp, float* __restrict__ ap)
{
    int wid = threadIdx.x >> 6, lane = threadIdx.x & 63;
    int p = blockIdx.x * 4 + wid;
    const ushortw* row = h + (size_t)p * 768;
    float mx = -1e30f, s = 0.f;
    #pragma unroll
    for (int it = 0; it < 3; it++) {
        int j = (lane << 2) + it * 256;
        if (j < HID) {
            short4v v = *reinterpret_cast<const short4v*>(row + j);
            float f0 = bf2f((ushortw)v[0]), f1 = bf2f((ushortw)v[1]);
            float f2 = bf2f((ushortw)v[2]), f3 = bf2f((ushortw)v[3]);
            mx = fmaxf(mx, fmaxf(fmaxf(f0, f1), fmaxf(f2, f3)));
            s += (f0 + f1) + (f2 + f3);
        }
    }
    mx = warp_max(mx); s = warp_sum(s);
    if (lane == 0) { mp[p] = mx; ap[p] = s * (1.f / HID); }
}

// ---------------- 7x7 spatial-attention conv + sigmoid, LDS-tiled (16x16 tile + 22x22 halo) ----
__global__ __launch_bounds__(256) void saconv_kernel(
    const float* __restrict__ mp, const float* __restrict__ ap,
    const float* __restrict__ w, float* __restrict__ sa)
{
    __shared__ float smp[22][22];
    __shared__ float sap[22][22];
    int t = blockIdx.x;               // 0..127 (2 images x 64 tiles)
    int img = t >> 6;
    int ty = (t >> 3) & 7, tx = t & 7;
    int y0 = ty * 16 - 3, x0 = tx * 16 - 3;
    int tid = threadIdx.x;
    for (int i = tid; i < 22 * 22; i += 256) {
        int ly = i / 22, lx = i - ly * 22;
        int gy = y0 + ly, gx = x0 + lx;
        bool ok = (gy >= 0 && gy < HH && gx >= 0 && gx < WW);
        int pid = img * IMG + gy * WW + gx;
        smp[ly][lx] = ok ? mp[pid] : 0.f;
        sap[ly][lx] = ok ? ap[pid] : 0.f;
    }
    __syncthreads();
    int py = tid >> 4, px = tid & 15;
    float acc = 0.f;
    #pragma unroll
    for (int ky = 0; ky < 7; ky++) {
        #pragma unroll
        for (int kx = 0; kx < 7; kx++) {
            acc += smp[py + ky][px + kx] * w[ky * 7 + kx]
                 + sap[py + ky][px + kx] * w[49 + ky * 7 + kx];
        }
    }
    int p = img * IMG + (ty * 16 + py) * WW + (tx * 16 + px);
    sa[p] = 1.f / (1.f + __expf(-acc));
}

extern "C" void kernel_launch(void* const* d_in, const int* in_sizes, int n_in,
                              void* d_out, int out_size, void* d_ws, size_t ws_size,
                              hipStream_t stream)
{
    const float* x      = (const float*)d_in[0];
    const int*   rpi    = (const int*)d_in[3];
    const float* n1g    = (const float*)d_in[4];
    const float* n1b    = (const float*)d_in[5];
    const float* rpb    = (const float*)d_in[6];
    const float* qkv_w  = (const float*)d_in[7];
    const float* qkv_b  = (const float*)d_in[8];
    const float* proj_w = (const float*)d_in[9];
    const float* proj_b = (const float*)d_in[10];
    const float* cab_w0 = (const float*)d_in[11];
    const float* cab_b0 = (const float*)d_in[12];
    const float* cab_w1 = (const float*)d_in[13];
    const float* cab_b1 = (const float*)d_in[14];
    const float* cab_w2 = (const float*)d_in[15];
    const float* cab_b2 = (const float*)d_in[16];
    const float* cab_w3 = (const float*)d_in[17];
    const float* cab_b3 = (const float*)d_in[18];
    const float* ca_w1  = (const float*)d_in[19];
    const float* ca_b1  = (const float*)d_in[20];
    const float* ca_w2  = (const float*)d_in[21];
    const float* ca_b2  = (const float*)d_in[22];
    const float* n2g    = (const float*)d_in[23];
    const float* n2b    = (const float*)d_in[24];
    const float* fc1_w  = (const float*)d_in[25];
    const float* fc1_b  = (const float*)d_in[26];
    const float* dw_w   = (const float*)d_in[27];
    const float* dw_b   = (const float*)d_in[28];
    const float* pw_w   = (const float*)d_in[29];
    const float* pw_b   = (const float*)d_in[30];
    const float* sa_w   = (const float*)d_in[31];
    const float* fc2_w  = (const float*)d_in[32];
    const float* fc2_b  = (const float*)d_in[33];
    float* outp = (float*)d_out;
    (void)in_sizes; (void)n_in; (void)out_size; (void)ws_size;

    char* ws = (char*)d_ws;
    const size_t S0 = (size_t)NTOK * 192 * 2;            // xnb -> xn2b
    const size_t S1 = (size_t)NTOK * QKVSTR * 2 + 256;   // qkvP -> h1(half) -> h3(half)
    const size_t S2 = (size_t)NTOK * 192 * 2;            // attnbb -> y3b
    const size_t S3 = (size_t)NTOK * 180 * 2;            // x1b bf16
    const size_t S4 = (size_t)NTOK * 128 * 2;            // y2b ; h2(half) spans S4+S5
    const size_t S5 = (size_t)NTOK * 180 * 4;            // xb -> y4 bf16 (region kept for h2 span)
    char* pA0 = ws;
    char* pA1 = pA0 + S0;
    char* pA2 = pA1 + S1;
    char* pA3 = pA2 + S2;
    char* pA4 = pA3 + S3;
    char* pA5 = pA4 + S4;
    char* tail = pA5 + S5;

    ushortw* xnb    = (ushortw*)pA0;           // [NTOK][192]
    ushortw* xn2b   = (ushortw*)pA0;
    ushortw* qkvP   = (ushortw*)pA1;           // [NTOK][672] (cols 576.. = cab0 out)
    ushortw* h1     = (ushortw*)pA1;           // [HALFTOK][720]
    ushortw* h3     = (ushortw*)pA1;           // [HALFTOK][768]
    ushortw* attnbb = (ushortw*)pA2;           // [NTOK][192]
    ushortw* y3b    = (ushortw*)pA2;           // [NTOK][192]
    ushortw* x1b    = (ushortw*)pA3;           // [NTOK][180] bf16
    ushortw* y2b    = (ushortw*)pA4;           // [NTOK][128]
    ushortw* h2     = (ushortw*)pA4;           // [HALFTOK][768] spans S4+S5
    ushortw* xb     = (ushortw*)pA5;           // [NTOK][180] bf16 (x copy; dead after proj)
    ushortw* y4     = (ushortw*)pA5;           // [NTOK][180] bf16 (written by dw2, after proj)

    // bf16 gemm weights
    ushortw* wqkvc = (ushortw*)tail;                        // 672 x 192
    ushortw* wproj = wqkvc + 672 * 192;                     // 256 x 192
    ushortw* wcab2 = wproj + 256 * 192;                     // 256 x 128
    ushortw* wfc1  = wcab2 + 256 * 128;                     // 768 x 192
    ushortw* wpw   = wfc1  + 768 * 192;                     // 768 x 768
    ushortw* wfc2  = wpw   + 768 * 768;                     // 256 x 768
    char* tail2 = (char*)(wfc2 + 256 * 768);
    float* dwt1 = (float*)tail2;                 float* db1 = dwt1 + 9*128;
    float* dwt2 = db1 + 128;                     float* db2 = dwt2 + 9*192;
    float* dwt3 = db2 + 192;                     float* db3 = dwt3 + 9*768;
    float* qb672 = db3 + 768;
    char* tail3 = (char*)(qb672 + 672);
    float* biasN = (float*)tail3;                           // 6*65536 fp32
    float* part  = (float*)(tail3 + 1572864);               // 4*128*180 fp32
    float* cabuf = (float*)(tail3 + 1572864 + 393216);
    float* mp    = (float*)(tail3 + 1572864 + 393216 + 4096);
    float* ap    = (float*)(tail3 + 1572864 + 393216 + 4096 + (size_t)HALFTOK * 4);
    float* sab   = (float*)(tail3 + 1572864 + 393216 + 4096 + 2*(size_t)HALFTOK * 4);

    auto gemm = [&](const ushortw* A, const ushortw* Wt, const float* bi, void* Cp,
                    int M, int N, int Kp, int ldc, int outbf, int zfill, int act, int residbf,
                    const float* rs, const void* resid) {
        int nM = M >> 7, nN = (N + 127) >> 7;
        mgemm_kernel<<<dim3(nM * nN), dim3(256), 0, stream>>>(
            A, Wt, bi, Cp, M, N, Kp, ldc, outbf, zfill, act, residbf, nN, rs, resid);
    };

    // 0) all weight/bias prep in one launch
    prep_kernel<<<dim3((1220832 + 255) / 256), dim3(256), 0, stream>>>(
        qkv_w, proj_w, cab_w0, cab_b0, cab_w2, fc1_w, pw_w, fc2_w,
        cab_w1, cab_b1, cab_w3, cab_b3, dw_w, dw_b, qkv_b, rpi, rpb,
        wqkvc, wproj, wcab2, wfc1, wpw, wfc2,
        dwt1, db1, dwt2, db2, dwt3, db3, qb672, biasN);

    // 1) LN1 -> bf16 xnb (+ bf16 copy of x for proj residual)
    ln_kernel<<<dim3(NTOK / 4), dim3(256), 0, stream>>>(x, n1g, n1b, xnb, xb);
    // 2) merged qkv+cab0 GEMM -> qkvP[NTOK][672]; then attention + CAB dwconv1
    gemm(xnb, wqkvc, qb672, qkvP, NTOK, 672, 192, QKVSTR, 1, 0, 0, 0, nullptr, nullptr);
    attn_mfma_kernel<<<dim3(BB * 64 * NHEADS), dim3(256), 0, stream>>>(qkvP, biasN, attnbb);
    dwconv4_kernel<672, 128, 128, 1, 1, 1><<<dim3(NTOK / 4 * 32 / 256), dim3(256), 0, stream>>>(
        qkvP + 576, dwt1, db1, y2b);
    // 3) proj with bf16 residual xb -> x1b (bf16)
    gemm(attnbb, wproj, proj_b, x1b, NTOK, 180, 192, 180, 1, 0, 0, 1, nullptr, xb);
    // 4) CAB part 2 (y4 overwrites xb region -- xb dead after proj)
    gemm(y2b, wcab2, cab_b2, y3b, NTOK, 180, 128, 192, 1, 1, 0, 0, nullptr, nullptr);
    dwconv4_kernel<192, 192, 180, 2, 0, 1><<<dim3(NTOK / 4 * 48 / 256), dim3(256), 0, stream>>>(
        y3b, dwt2, db2, y4);
    gap_kernel<<<dim3(BB * 128), dim3(192), 0, stream>>>(y4, part);
    ca_kernel<<<dim3(1), dim3(256), 0, stream>>>(part, ca_w1, ca_b1, ca_w2, ca_b2, cabuf);
    // 5) x1 += 0.01*y4*ca; LN2 -> bf16 xn2b
    resid_ln_kernel<<<dim3(NTOK / 4), dim3(256), 0, stream>>>(x1b, y4, cabuf, n2g, n2b, xn2b);
    // 6) FFN in two half-batches (2 images each)
    for (int half = 0; half < 2; half++) {
        size_t toff = (size_t)half * HALFTOK;
        gemm(xn2b + toff * 192, wfc1, fc1_b, h1, HALFTOK, 720, 192, 720, 1, 0, 1, 0, nullptr, nullptr);
        dwconv4_kernel<720, 768, 768, 1, 2, 1><<<dim3(HALFTOK / 4 * 192 / 256), dim3(256), 0, stream>>>(
            h1, dwt3, db3, h2);
        gemm(h2, wpw, pw_b, h3, HALFTOK, 720, 768, 768, 1, 1, 2, 0, nullptr, nullptr);
        mpap_kernel<<<dim3(HALFTOK / 4), dim3(256), 0, stream>>>(h3, mp, ap);
        saconv_kernel<<<dim3(128), dim3(256), 0, stream>>>(mp, ap, sa_w, sab);
        gemm(h3, wfc2, fc2_b, outp + toff * 180, HALFTOK, 180, 768, 180, 0, 0, 0, 1,
             sab, x1b + toff * 180);
    }
}

// Round 25
// 611.798 us; speedup vs baseline: 1.1165x; 1.0084x over previous
//
#include <hip/hip_runtime.h>
#include <math.h>

#define HH 128
#define WW 128
#define CC 180
#define BB 4
#define IMG (HH*WW)          // 16384 tokens per image
#define NTOK (BB*IMG)        // 65536
#define HALFTOK (2*IMG)      // 32768
#define NHEADS 6
#define HD 30
#define WSZ 16
#define NTOKW (WSZ*WSZ)      // 256
#define HID 720
#define QKVSTR 672           // merged row: q/k/v (3x192) + cab0 (96)

typedef __attribute__((ext_vector_type(8))) short short8v;
typedef __attribute__((ext_vector_type(4))) short short4v;
typedef __attribute__((ext_vector_type(4))) float f32x4;
typedef unsigned short ushortw;

__device__ __forceinline__ float warp_sum(float v) {
    #pragma unroll
    for (int o = 32; o > 0; o >>= 1) v += __shfl_xor(v, o);
    return v;
}
__device__ __forceinline__ float warp_max(float v) {
    #pragma unroll
    for (int o = 32; o > 0; o >>= 1) v = fmaxf(v, __shfl_xor(v, o));
    return v;
}
__device__ __forceinline__ float gelu_exact(float v) {
    return 0.5f * v * (1.f + erff(v * 0.70710678118654752f));
}
__device__ __forceinline__ ushortw f2bf(float f) {
    union { float f; unsigned int u; } c; c.f = f;
    unsigned int r = (c.u + 0x7FFFu + ((c.u >> 16) & 1u)) >> 16;
    return (ushortw)r;
}
__device__ __forceinline__ float bf2f(ushortw u) {
    union { unsigned int u; float f; } c; c.u = ((unsigned int)u) << 16; return c.f;
}

// ---------------- fused weight/bias prep (one launch) ----------------
__global__ __launch_bounds__(256) void prep_kernel(
    const float* __restrict__ qkv_w, const float* __restrict__ proj_w,
    const float* __restrict__ cab_w0, const float* __restrict__ cab_b0,
    const float* __restrict__ cab_w2,
    const float* __restrict__ fc1_w, const float* __restrict__ pw_w,
    const float* __restrict__ fc2_w,
    const float* __restrict__ cab_w1, const float* __restrict__ cab_b1,
    const float* __restrict__ cab_w3, const float* __restrict__ cab_b3,
    const float* __restrict__ dw_w, const float* __restrict__ dw_b,
    const float* __restrict__ qkv_b, const int* __restrict__ rpi,
    const float* __restrict__ rpb,
    ushortw* __restrict__ wqkvc, ushortw* __restrict__ wproj,
    ushortw* __restrict__ wcab2,
    ushortw* __restrict__ wfc1, ushortw* __restrict__ wpw, ushortw* __restrict__ wfc2,
    float* __restrict__ dwt1, float* __restrict__ db1,
    float* __restrict__ dwt2, float* __restrict__ db2,
    float* __restrict__ dwt3, float* __restrict__ db3,
    float* __restrict__ qb672, float* __restrict__ biasN)
{
    int idx = blockIdx.x * 256 + threadIdx.x;
    if (idx < 129024) {                              // J0: wqkvc [672][192]
        int r = idx / 192, k = idx - r * 192;
        float v = 0.f;
        if (r < 576) {
            int sub = r / 192, rem = r - sub * 192;
            int hh = rem >> 5, dd = rem & 31;
            if (dd < 30 && k < 180) v = qkv_w[(sub * 180 + hh * 30 + dd) * 180 + k];
        } else if (r < 666) {
            if (k < 180) v = cab_w0[(r - 576) * 180 + k];
        }
        wqkvc[idx] = f2bf(v);
    } else if (idx < 178176) {                       // J1: wproj [256][192]
        int l = idx - 129024; int r = l / 192, k = l - r * 192;
        wproj[l] = f2bf((r < 180 && k < 180) ? proj_w[r * 180 + k] : 0.f);
    } else if (idx < 210944) {                       // J2: wcab2 [256][128]
        int l = idx - 178176; int r = l / 128, k = l - r * 128;
        wcab2[l] = f2bf((r < 180 && k < 90) ? cab_w2[r * 90 + k] : 0.f);
    } else if (idx < 358400) {                       // J3: wfc1 [768][192]
        int l = idx - 210944; int r = l / 192, k = l - r * 192;
        wfc1[l] = f2bf((r < 720 && k < 180) ? fc1_w[r * 180 + k] : 0.f);
    } else if (idx < 948224) {                       // J4: wpw [768][768]
        int l = idx - 358400; int r = l / 768, k = l - r * 768;
        wpw[l] = f2bf((r < 720 && k < 720) ? pw_w[r * 720 + k] : 0.f);
    } else if (idx < 1144832) {                      // J5: wfc2 [256][768]
        int l = idx - 948224; int r = l / 768, k = l - r * 768;
        wfc2[l] = f2bf((r < 180 && k < 720) ? fc2_w[r * 720 + k] : 0.f);
    } else if (idx < 1145984) {                      // J6: dwt1 [9][128]
        int l = idx - 1144832; int c = l / 9, k = l - c * 9;
        dwt1[k * 128 + c] = (c < 90) ? cab_w1[c * 9 + k] : 0.f;
        if (k == 0) db1[c] = (c < 90) ? cab_b1[c] : 0.f;
    } else if (idx < 1147712) {                      // J7: dwt2 [9][192]
        int l = idx - 1145984; int c = l / 9, k = l - c * 9;
        dwt2[k * 192 + c] = (c < 180) ? cab_w3[c * 9 + k] : 0.f;
        if (k == 0) db2[c] = (c < 180) ? cab_b3[c] : 0.f;
    } else if (idx < 1154624) {                      // J8: dwt3 [9][768]
        int l = idx - 1147712; int c = l / 9, k = l - c * 9;
        dwt3[k * 768 + c] = (c < 720) ? dw_w[c * 9 + k] : 0.f;
        if (k == 0) db3[c] = (c < 720) ? dw_b[c] : 0.f;
    } else if (idx < 1155296) {                      // J9: qb672
        int l = idx - 1154624;
        float v = 0.f;
        if (l < 576) {
            int sub = l / 192, rem = l - sub * 192;
            int hh = rem >> 5, dd = rem & 31;
            if (dd < 30) v = qkv_b[sub * 180 + hh * 30 + dd];
        } else if (l < 666) {
            v = cab_b0[l - 576];
        }
        qb672[l] = v;
    } else if (idx < 1220832) {                      // J10: biasN [6][65536]
        int l = idx - 1155296;
        int r = rpi[l];
        #pragma unroll
        for (int h = 0; h < NHEADS; h++)
            biasN[((size_t)h << 16) + l] = rpb[r * NHEADS + h];
    }
}

// ---------------- LayerNorm -> bf16 xn (stride 192, pads 0) + bf16 copy of x ----------------
__global__ __launch_bounds__(256) void ln_kernel(
    const float* __restrict__ x, const float* __restrict__ g,
    const float* __restrict__ b, ushortw* __restrict__ out, ushortw* __restrict__ xb)
{
    int wid = threadIdx.x >> 6, lane = threadIdx.x & 63;
    int t = blockIdx.x * 4 + wid;
    size_t off = (size_t)t * CC;
    size_t off2 = (size_t)t * 192;
    bool has2 = lane < (CC - 128);
    float v0 = x[off + lane];
    float v1 = x[off + lane + 64];
    float v2 = has2 ? x[off + lane + 128] : 0.f;
    xb[off + lane] = f2bf(v0);
    xb[off + lane + 64] = f2bf(v1);
    if (has2) xb[off + lane + 128] = f2bf(v2);
    float s = warp_sum(v0 + v1 + v2);
    float mu = s * (1.f / CC);
    float d0 = v0 - mu, d1 = v1 - mu, d2 = has2 ? v2 - mu : 0.f;
    float var = warp_sum(d0*d0 + d1*d1 + d2*d2) * (1.f / CC);
    float rs = rsqrtf(var + 1e-5f);
    out[off2 + lane]      = f2bf(d0 * rs * g[lane]      + b[lane]);
    out[off2 + lane + 64] = f2bf(d1 * rs * g[lane + 64] + b[lane + 64]);
    out[off2 + lane + 128] = has2 ? f2bf(d2 * rs * g[lane + 128] + b[lane + 128]) : (ushortw)0;
}

// ---------------- bf16 MFMA GEMM: counted-vmcnt triple-buffer (prefetch depth 2) ----------------
// Per step: issue tile t+2 -> s_waitcnt vmcnt(8) (tile t landed; t+1,t+2 stay in flight)
// -> s_barrier -> ds_read+MFMA tile t -> s_barrier (slot-reuse guard). No vmcnt(0) drain in loop.
__global__ __launch_bounds__(256) void mgemm_kernel(
    const ushortw* __restrict__ A, const ushortw* __restrict__ Wt,
    const float* __restrict__ bias, void* __restrict__ Cout,
    int M, int N, int Kp, int ldc, int outbf, int zfill, int act, int residbf, int nN,
    const float* __restrict__ rowscale, const void* __restrict__ residv)
{
    __shared__ ushortw sA[3][128 * 32];
    __shared__ ushortw sB[3][128 * 32];
    int tid = threadIdx.x, lane = tid & 63, wid = tid >> 6;
    int total = (int)gridDim.x;
    int orig = blockIdx.x;
    int q = total >> 3, r = total & 7;
    int xcd = orig & 7, slot = orig >> 3;
    int wgid = (xcd < r ? xcd * (q + 1) : r * (q + 1) + (xcd - r) * q) + slot;
    int mp = wgid / nN, np = wgid - mp * nN;
    int m0 = mp << 7, n0 = np << 7;
    int wm = (wid >> 1) << 6, wn = (wid & 1) << 6;
    int lrow = lane & 15, kgrp = lane >> 4;

    f32x4 acc[4][4];
    #pragma unroll
    for (int i = 0; i < 4; i++)
        #pragma unroll
        for (int j = 0; j < 4; j++)
            #pragma unroll
            for (int rr = 0; rr < 4; rr++) acc[i][j][rr] = 0.f;

    int nk = Kp >> 5;
    // staging geometry (per thread): 2 segs x (A,B) = 4 global_load_lds per tile
    int seg0 = wid << 1;
    int row0 = (seg0 << 4) + (lane >> 2);
    int row1 = ((seg0 + 1) << 4) + (lane >> 2);
    int cg0 = (lane & 3) ^ (row0 & 3) ^ ((row0 >> 2) & 3);
    int cg1 = (lane & 3) ^ (row1 & 3) ^ ((row1 >> 2) & 3);
    const ushortw* ga0 = A + (size_t)(m0 + row0) * Kp + (cg0 << 3);
    const ushortw* ga1 = A + (size_t)(m0 + row1) * Kp + (cg1 << 3);
    const ushortw* gb0 = Wt + (size_t)(n0 + row0) * Kp + (cg0 << 3);
    const ushortw* gb1 = Wt + (size_t)(n0 + row1) * Kp + (cg1 << 3);

    #define ISSUE_TILE(slotidx, kk)                                                        \
        do {                                                                               \
            __builtin_amdgcn_global_load_lds(                                              \
                (const __attribute__((address_space(1))) void*)(ga0 + (kk)),               \
                (__attribute__((address_space(3))) void*)&sA[slotidx][seg0 << 9], 16, 0, 0);\
            __builtin_amdgcn_global_load_lds(                                              \
                (const __attribute__((address_space(1))) void*)(gb0 + (kk)),               \
                (__attribute__((address_space(3))) void*)&sB[slotidx][seg0 << 9], 16, 0, 0);\
            __builtin_amdgcn_global_load_lds(                                              \
                (const __attribute__((address_space(1))) void*)(ga1 + (kk)),               \
                (__attribute__((address_space(3))) void*)&sA[slotidx][(seg0 + 1) << 9], 16, 0, 0);\
            __builtin_amdgcn_global_load_lds(                                              \
                (const __attribute__((address_space(1))) void*)(gb1 + (kk)),               \
                (__attribute__((address_space(3))) void*)&sB[slotidx][(seg0 + 1) << 9], 16, 0, 0);\
        } while (0)

    // prologue: tiles 0 and 1 in flight
    ISSUE_TILE(0, 0);
    if (nk > 1) ISSUE_TILE(1, 32);

    int cur = 0, pre = 2;
    for (int t = 0; t < nk; t++) {
        if (t + 2 < nk) {
            ISSUE_TILE(pre, (t + 2) << 5);
            asm volatile("s_waitcnt vmcnt(8)" ::: "memory");
        } else {
            asm volatile("s_waitcnt vmcnt(0)" ::: "memory");
        }
        __builtin_amdgcn_s_barrier();
        asm volatile("" ::: "memory");
        short8v a[4], b[4];
        #pragma unroll
        for (int i = 0; i < 4; i++) {
            int rr = wm + (i << 4) + lrow;
            int slot2 = kgrp ^ (rr & 3) ^ ((rr >> 2) & 3);
            a[i] = *reinterpret_cast<const short8v*>(&sA[cur][(rr << 5) + (slot2 << 3)]);
        }
        #pragma unroll
        for (int j = 0; j < 4; j++) {
            int rr = wn + (j << 4) + lrow;
            int slot2 = kgrp ^ (rr & 3) ^ ((rr >> 2) & 3);
            b[j] = *reinterpret_cast<const short8v*>(&sB[cur][(rr << 5) + (slot2 << 3)]);
        }
        #pragma unroll
        for (int i = 0; i < 4; i++)
            #pragma unroll
            for (int j = 0; j < 4; j++)
                acc[i][j] = __builtin_amdgcn_mfma_f32_16x16x32_bf16(b[j], a[i], acc[i][j], 0, 0, 0);
        asm volatile("" ::: "memory");
        __builtin_amdgcn_s_barrier();
        cur = (cur == 2) ? 0 : cur + 1;
        pre = (pre == 2) ? 0 : pre + 1;
    }
    #undef ISSUE_TILE
    // transposed-acc epilogue: row = token (lane), 4 consecutive cols per reg
    #pragma unroll
    for (int i = 0; i < 4; i++) {
        int row = m0 + wm + (i << 4) + lrow;
        float rsv = rowscale ? rowscale[row] : 1.f;
        #pragma unroll
        for (int j = 0; j < 4; j++) {
            int colb = n0 + wn + (j << 4) + (kgrp << 2);
            if (colb < N) {
                float4 bi4 = *reinterpret_cast<const float4*>(bias + colb);
                float vv[4];
                vv[0] = acc[i][j][0]; vv[1] = acc[i][j][1];
                vv[2] = acc[i][j][2]; vv[3] = acc[i][j][3];
                if (rowscale) {
                    vv[0] *= rsv; vv[1] *= rsv; vv[2] *= rsv; vv[3] *= rsv;
                }
                vv[0] += bi4.x; vv[1] += bi4.y; vv[2] += bi4.z; vv[3] += bi4.w;
                if (act == 1) {
                    vv[0] = gelu_exact(vv[0]); vv[1] = gelu_exact(vv[1]);
                    vv[2] = gelu_exact(vv[2]); vv[3] = gelu_exact(vv[3]);
                } else if (act == 2) {
                    vv[0] = fmaxf(vv[0], 0.f); vv[1] = fmaxf(vv[1], 0.f);
                    vv[2] = fmaxf(vv[2], 0.f); vv[3] = fmaxf(vv[3], 0.f);
                }
                if (residv) {
                    if (residbf) {
                        short4v rv = *reinterpret_cast<const short4v*>(
                            (const ushortw*)residv + (size_t)row * N + colb);
                        vv[0] += bf2f((ushortw)rv[0]); vv[1] += bf2f((ushortw)rv[1]);
                        vv[2] += bf2f((ushortw)rv[2]); vv[3] += bf2f((ushortw)rv[3]);
                    } else {
                        float4 rv = *reinterpret_cast<const float4*>(
                            (const float*)residv + (size_t)row * N + colb);
                        vv[0] += rv.x; vv[1] += rv.y; vv[2] += rv.z; vv[3] += rv.w;
                    }
                }
                if (outbf) {
                    short4v o;
                    o[0] = (short)f2bf(vv[0]); o[1] = (short)f2bf(vv[1]);
                    o[2] = (short)f2bf(vv[2]); o[3] = (short)f2bf(vv[3]);
                    *reinterpret_cast<short4v*>((ushortw*)Cout + (size_t)row * ldc + colb) = o;
                } else {
                    float4 o = make_float4(vv[0], vv[1], vv[2], vv[3]);
                    *reinterpret_cast<float4*>((float*)Cout + (size_t)row * ldc + colb) = o;
                }
            } else if (zfill && colb < ldc) {
                if (outbf) {
                    short4v o; o[0] = 0; o[1] = 0; o[2] = 0; o[3] = 0;
                    *reinterpret_cast<short4v*>((ushortw*)Cout + (size_t)row * ldc + colb) = o;
                } else {
                    *reinterpret_cast<float4*>((float*)Cout + (size_t)row * ldc + colb) =
                        make_float4(0.f, 0.f, 0.f, 0.f);
                }
            }
        }
    }
}

// ---------------- MFMA window attention (swapped QK^T): block = (img, win, head) ----------------
// r22-proven config + bias loads hoisted ahead of the QK MFMA cluster (latency hides under MFMA).
__global__ __launch_bounds__(256, 3) void attn_mfma_kernel(
    const ushortw* __restrict__ qkvP, const float* __restrict__ biasN,
    ushortw* __restrict__ out)
{
    __shared__ ushortw Vc[32 * 33 * 8];      // 16896 B
    __shared__ ushortw Kc[256 * 32];         // 16384 B
    __shared__ ushortw Pl[4][2048];          // 16384 B
    const float SCALE = 0.18257418583505536f;   // 30^-0.5
    int blk = blockIdx.x;
    int img = blk / 384;
    int rem = blk - img * 384;
    int win = rem / NHEADS;
    int h = rem - win * NHEADS;
    int base = img * IMG + (win >> 3) * WSZ * WW + (win & 7) * WSZ;
    int tid = threadIdx.x;
    int lane = tid & 63, w = tid >> 6;
    int a15 = lane & 15, kg = lane >> 4;

    {
        int j = tid;
        int g = base + (j >> 4) * WW + (j & 15);
        const ushortw* vp = qkvP + (size_t)g * QKVSTR + 384 + h * 32;
        short8v c0 = *reinterpret_cast<const short8v*>(vp);
        short8v c1 = *reinterpret_cast<const short8v*>(vp + 8);
        short8v c2 = *reinterpret_cast<const short8v*>(vp + 16);
        short8v c3 = *reinterpret_cast<const short8v*>(vp + 24);
        int bo = (j >> 3) * 264 + (j & 7);
        #pragma unroll
        for (int e = 0; e < 8; e++)  Vc[bo + (e) * 8]      = (ushortw)c0[e];
        #pragma unroll
        for (int e = 0; e < 8; e++)  Vc[bo + (8 + e) * 8]  = (ushortw)c1[e];
        #pragma unroll
        for (int e = 0; e < 8; e++)  Vc[bo + (16 + e) * 8] = (ushortw)c2[e];
        #pragma unroll
        for (int e = 0; e < 8; e++)  Vc[bo + (24 + e) * 8] = (ushortw)c3[e];
        const ushortw* kp = qkvP + (size_t)g * QKVSTR + 192 + h * 32;
        short8v k0 = *reinterpret_cast<const short8v*>(kp);
        short8v k1 = *reinterpret_cast<const short8v*>(kp + 8);
        short8v k2 = *reinterpret_cast<const short8v*>(kp + 16);
        short8v k3 = *reinterpret_cast<const short8v*>(kp + 24);
        short8v* krow = reinterpret_cast<short8v*>(&Kc[j * 32]);
        int jsw = (j >> 1) & 3;
        krow[0 ^ jsw] = k0; krow[1 ^ jsw] = k1; krow[2 ^ jsw] = k2; krow[3 ^ jsw] = k3;
    }
    __syncthreads();

    ushortw* Pw = &Pl[w][0];
    int xsw = (a15 & 7) << 2;                // P dword-XOR per q-row
    f32x4 zf = {0.f, 0.f, 0.f, 0.f};
    #pragma unroll 1
    for (int si = 0; si < 4; si++) {
        int strip = (w << 2) + si;
        short8v qf = *reinterpret_cast<const short8v*>(
            qkvP + (size_t)(base + strip * WW + a15) * QKVSTR + h * 32 + (kg << 3));
        float psum = 0.f;
        f32x4 o0 = zf, o1 = zf;
        const float* brow = biasN + ((size_t)h << 16) + (size_t)((strip << 4) + a15) * 256;
        #pragma unroll
        for (int half = 0; half < 2; half++) {
            // hoist bias loads: in flight during the QK MFMA cluster
            float4 b4s[8];
            #pragma unroll
            for (int j8 = 0; j8 < 8; j8++) {
                int jt = (half << 3) + j8;
                b4s[j8] = *reinterpret_cast<const float4*>(brow + (jt << 4) + (kg << 2));
            }
            f32x4 s[8];
            __builtin_amdgcn_s_setprio(1);
            #pragma unroll
            for (int j8 = 0; j8 < 8; j8++) {
                int jt = (half << 3) + j8;
                int row = (jt << 4) + a15;
                short8v ka = reinterpret_cast<const short8v*>(&Kc[row * 32])[kg ^ ((row >> 1) & 3)];
                s[j8] = __builtin_amdgcn_mfma_f32_16x16x32_bf16(ka, qf, zf, 0, 0, 0);
            }
            __builtin_amdgcn_s_setprio(0);
            #pragma unroll
            for (int j8 = 0; j8 < 8; j8++) {
                float p0 = __expf(fmaf(s[j8][0], SCALE, b4s[j8].x));
                float p1 = __expf(fmaf(s[j8][1], SCALE, b4s[j8].y));
                float p2 = __expf(fmaf(s[j8][2], SCALE, b4s[j8].z));
                float p3 = __expf(fmaf(s[j8][3], SCALE, b4s[j8].w));
                psum += (p0 + p1) + (p2 + p3);
                unsigned int u0, u1;
                asm("v_cvt_pk_bf16_f32 %0, %1, %2" : "=v"(u0) : "v"(p0), "v"(p1));
                asm("v_cvt_pk_bf16_f32 %0, %1, %2" : "=v"(u1) : "v"(p2), "v"(p3));
                int dw0 = ((j8 << 3) + (kg << 1)) ^ xsw;
                unsigned long long pk64 = (unsigned long long)u0 | ((unsigned long long)u1 << 32);
                *reinterpret_cast<unsigned long long*>(&Pw[(a15 << 7) + (dw0 << 1)]) = pk64;
            }
            __builtin_amdgcn_s_setprio(1);
            #pragma unroll
            for (int ks4 = 0; ks4 < 4; ks4++) {
                int dwr = ((ks4 << 4) + (kg << 2)) ^ xsw;
                short8v pa = *reinterpret_cast<const short8v*>(&Pw[(a15 << 7) + (dwr << 1)]);
                int kc = (((half << 2) + ks4) << 2) + kg;
                short8v v0 = *reinterpret_cast<const short8v*>(&Vc[(kc * 33 + a15) * 8]);
                short8v v1 = *reinterpret_cast<const short8v*>(&Vc[(kc * 33 + 16 + a15) * 8]);
                o0 = __builtin_amdgcn_mfma_f32_16x16x32_bf16(pa, v0, o0, 0, 0, 0);
                o1 = __builtin_amdgcn_mfma_f32_16x16x32_bf16(pa, v1, o1, 0, 0, 0);
            }
            __builtin_amdgcn_s_setprio(0);
        }
        psum += __shfl_xor(psum, 16);
        psum += __shfl_xor(psum, 32);
        #pragma unroll
        for (int r = 0; r < 4; r++) {
            float pt = __shfl(psum, (kg << 2) + r);
            float inv = 1.f / pt;
            int g = base + strip * WW + (kg << 2) + r;
            ushortw* orow = out + (size_t)g * 192 + h * HD;
            orow[a15] = f2bf(o0[r] * inv);
            if (a15 < 14) orow[16 + a15] = f2bf(o1[r] * inv);
        }
    }
    if (h == 0) {   // zero pad cols 180..191
        for (int idx2 = tid; idx2 < NTOKW * 12; idx2 += 256) {
            int j = idx2 / 12, d = idx2 - (idx2 / 12) * 12;
            int gj = base + (j >> 4) * WW + (j & 15);
            out[(size_t)gj * 192 + 180 + d] = 0;
        }
    }
}

// ---------------- register-tiled depthwise 3x3 conv: 4 pixels x 4 channels / thread ----------------
template<int CIN_S, int COP, int OSTR, int DIL, int ACT, int OUTBF>
__global__ __launch_bounds__(256) void dwconv4_kernel(
    const ushortw* __restrict__ in, const float* __restrict__ wt,
    const float* __restrict__ bias, void* __restrict__ out)
{
    constexpr int NC4 = COP >> 2;
    constexpr int NX = 4 + 2 * DIL;
    int idx = blockIdx.x * 256 + threadIdx.x;
    int c4 = idx % NC4;
    int quad = idx / NC4;
    int c = c4 << 2;
    int pix0 = quad << 2;
    int p = pix0 & (IMG - 1);
    int imgbase = pix0 - p;
    int px0 = p & (WW - 1), py = p >> 7;

    float4 w9[9];
    #pragma unroll
    for (int t = 0; t < 9; t++)
        w9[t] = *reinterpret_cast<const float4*>(wt + t * COP + c);
    float4 bi4 = *reinterpret_cast<const float4*>(bias + c);
    float acc[4][4];
    #pragma unroll
    for (int i = 0; i < 4; i++) {
        acc[i][0] = bi4.x; acc[i][1] = bi4.y; acc[i][2] = bi4.z; acc[i][3] = bi4.w;
    }
    #pragma unroll
    for (int ky = 0; ky < 3; ky++) {
        int iy = py + (ky - 1) * DIL;
        if (iy < 0 || iy >= HH) continue;
        const ushortw* rowp = in + (size_t)(imgbase + (iy << 7)) * CIN_S + c;
        #pragma unroll
        for (int xx = 0; xx < NX; xx++) {
            int ix = px0 + xx - DIL;
            if (ix < 0 || ix >= WW) continue;
            short4v v = *reinterpret_cast<const short4v*>(rowp + (size_t)ix * CIN_S);
            float f0 = bf2f((ushortw)v[0]);
            float f1 = bf2f((ushortw)v[1]);
            float f2 = bf2f((ushortw)v[2]);
            float f3 = bf2f((ushortw)v[3]);
            #pragma unroll
            for (int kx = 0; kx < 3; kx++) {
                int i = xx - DIL * kx;
                if (i < 0 || i > 3) continue;
                float4 wv = w9[ky * 3 + kx];
                acc[i][0] = fmaf(f0, wv.x, acc[i][0]);
                acc[i][1] = fmaf(f1, wv.y, acc[i][1]);
                acc[i][2] = fmaf(f2, wv.z, acc[i][2]);
                acc[i][3] = fmaf(f3, wv.w, acc[i][3]);
            }
        }
    }
    if (COP != OSTR && c >= OSTR) return;
    #pragma unroll
    for (int i = 0; i < 4; i++) {
        #pragma unroll
        for (int e = 0; e < 4; e++) {
            float v = acc[i][e];
            if (ACT == 1) v = gelu_exact(v);
            else if (ACT == 2) v = fmaxf(v, 0.f);
            acc[i][e] = v;
        }
        if (OUTBF) {
            short4v o;
            o[0] = (short)f2bf(acc[i][0]); o[1] = (short)f2bf(acc[i][1]);
            o[2] = (short)f2bf(acc[i][2]); o[3] = (short)f2bf(acc[i][3]);
            *reinterpret_cast<short4v*>((ushortw*)out + (size_t)(pix0 + i) * OSTR + c) = o;
        } else {
            float4 o = make_float4(acc[i][0], acc[i][1], acc[i][2], acc[i][3]);
            *reinterpret_cast<float4*>((float*)out + (size_t)(pix0 + i) * OSTR + c) = o;
        }
    }
}

// ---------------- GAP partial sums over bf16 y4 (128-pixel chunks, 512 blocks) ----------------
__global__ void gap_kernel(const ushortw* __restrict__ y, float* __restrict__ part)
{
    int blk = blockIdx.x;              // 0..511
    int b = blk >> 7, chunk = blk & 127;
    int c = threadIdx.x;
    if (c >= CC) return;
    size_t basep = ((size_t)b * IMG + (size_t)chunk * 128) * CC;
    float s = 0.f;
    for (int p = 0; p < 128; p++) s += bf2f(y[basep + (size_t)p * CC + c]);
    part[((size_t)b * 128 + chunk) * CC + c] = s;
}

// ---------------- channel attention (tiny) ----------------
__global__ void ca_kernel(const float* __restrict__ part,
                          const float* __restrict__ w1, const float* __restrict__ b1,
                          const float* __restrict__ w2, const float* __restrict__ b2,
                          float* __restrict__ ca)
{
    __shared__ float gap[BB * CC];
    __shared__ float s1[BB * 6];
    int tid = threadIdx.x;
    for (int idx = tid; idx < BB * CC; idx += 256) {
        int b = idx / CC, c = idx % CC;
        float s = 0.f;
        for (int ch = 0; ch < 128; ch++) s += part[((size_t)b * 128 + ch) * CC + c];
        gap[idx] = s * (1.f / IMG);
    }
    __syncthreads();
    if (tid < BB * 6) {
        int b = tid / 6, cs = tid % 6;
        float s = 0.f;
        for (int c = 0; c < CC; c++) s += w1[cs * CC + c] * gap[b * CC + c];
        s1[tid] = fmaxf(s + b1[cs], 0.f);
    }
    __syncthreads();
    for (int idx = tid; idx < BB * CC; idx += 256) {
        int b = idx / CC, c = idx % CC;
        float s = b2[c];
        #pragma unroll
        for (int cs = 0; cs < 6; cs++) s += w2[c * 6 + cs] * s1[b * 6 + cs];
        ca[idx] = 1.f / (1.f + __expf(-s));
    }
}

// ---------------- x1(bf16) += 0.01*y4*ca; LN2 -> bf16 xn2 (stride 192) ----------------
__global__ __launch_bounds__(256) void resid_ln_kernel(
    ushortw* __restrict__ x1, const ushortw* __restrict__ y4, const float* __restrict__ ca,
    const float* __restrict__ g, const float* __restrict__ bb,
    ushortw* __restrict__ xn2)
{
    int wid = threadIdx.x >> 6, lane = threadIdx.x & 63;
    int t = blockIdx.x * 4 + wid;
    int b = t >> 14;
    size_t off = (size_t)t * CC;
    size_t off2 = (size_t)t * 192;
    bool has2 = lane < (CC - 128);
    float v0 = bf2f(x1[off+lane])    + 0.01f * bf2f(y4[off+lane])    * ca[b*CC + lane];
    float v1 = bf2f(x1[off+lane+64]) + 0.01f * bf2f(y4[off+lane+64]) * ca[b*CC + lane+64];
    float v2 = 0.f;
    if (has2) v2 = bf2f(x1[off+lane+128]) + 0.01f * bf2f(y4[off+lane+128]) * ca[b*CC + lane+128];
    x1[off+lane] = f2bf(v0); x1[off+lane+64] = f2bf(v1);
    if (has2) x1[off+lane+128] = f2bf(v2);
    float s = warp_sum(v0 + v1 + v2);
    float mu = s * (1.f / CC);
    float d0 = v0-mu, d1 = v1-mu, d2 = has2 ? v2-mu : 0.f;
    float var = warp_sum(d0*d0 + d1*d1 + d2*d2) * (1.f / CC);
    float rs = rsqrtf(var + 1e-5f);
    xn2[off2+lane]      = f2bf(d0 * rs * g[lane]      + bb[lane]);
    xn2[off2+lane+64]   = f2bf(d1 * rs * g[lane+64]   + bb[lane+64]);
    xn2[off2+lane+128]  = has2 ? f2bf(d2 * rs * g[lane+128] + bb[lane+128]) : (ushortw)0;
}

// ---------------- max/mean over channels per pixel (bf16 h3, stride 768, 720 cols) ----------------
__global__ __launch_bounds__(256) void mpap_kernel(
    const ushortw* __restrict__ h, float* __restrict__ mp, float* __restrict__ ap)
{
    int wid = threadIdx.x >> 6, lane = threadIdx.x & 63;
    int p = blockIdx.x * 4 + wid;
    const ushortw* row = h + (size_t)p * 768;
    float mx = -1e30f, s = 0.f;
    #pragma unroll
    for (int it = 0; it < 3; it++) {
        int j = (lane << 2) + it * 256;
        if (j < HID) {
            short4v v = *reinterpret_cast<const short4v*>(row + j);
            float f0 = bf2f((ushortw)v[0]), f1 = bf2f((ushortw)v[1]);
            float f2 = bf2f((ushortw)v[2]), f3 = bf2f((ushortw)v[3]);
            mx = fmaxf(mx, fmaxf(fmaxf(f0, f1), fmaxf(f2, f3)));
            s += (f0 + f1) + (f2 + f3);
        }
    }
    mx = warp_max(mx); s = warp_sum(s);
    if (lane == 0) { mp[p] = mx; ap[p] = s * (1.f / HID); }
}

// ---------------- 7x7 spatial-attention conv + sigmoid, LDS-tiled (16x16 tile + 22x22 halo) ----
__global__ __launch_bounds__(256) void saconv_kernel(
    const float* __restrict__ mp, const float* __restrict__ ap,
    const float* __restrict__ w, float* __restrict__ sa)
{
    __shared__ float smp[22][22];
    __shared__ float sap[22][22];
    int t = blockIdx.x;               // 0..127 (2 images x 64 tiles)
    int img = t >> 6;
    int ty = (t >> 3) & 7, tx = t & 7;
    int y0 = ty * 16 - 3, x0 = tx * 16 - 3;
    int tid = threadIdx.x;
    for (int i = tid; i < 22 * 22; i += 256) {
        int ly = i / 22, lx = i - ly * 22;
        int gy = y0 + ly, gx = x0 + lx;
        bool ok = (gy >= 0 && gy < HH && gx >= 0 && gx < WW);
        int pid = img * IMG + gy * WW + gx;
        smp[ly][lx] = ok ? mp[pid] : 0.f;
        sap[ly][lx] = ok ? ap[pid] : 0.f;
    }
    __syncthreads();
    int py = tid >> 4, px = tid & 15;
    float acc = 0.f;
    #pragma unroll
    for (int ky = 0; ky < 7; ky++) {
        #pragma unroll
        for (int kx = 0; kx < 7; kx++) {
            acc += smp[py + ky][px + kx] * w[ky * 7 + kx]
                 + sap[py + ky][px + kx] * w[49 + ky * 7 + kx];
        }
    }
    int p = img * IMG + (ty * 16 + py) * WW + (tx * 16 + px);
    sa[p] = 1.f / (1.f + __expf(-acc));
}

extern "C" void kernel_launch(void* const* d_in, const int* in_sizes, int n_in,
                              void* d_out, int out_size, void* d_ws, size_t ws_size,
                              hipStream_t stream)
{
    const float* x      = (const float*)d_in[0];
    const int*   rpi    = (const int*)d_in[3];
    const float* n1g    = (const float*)d_in[4];
    const float* n1b    = (const float*)d_in[5];
    const float* rpb    = (const float*)d_in[6];
    const float* qkv_w  = (const float*)d_in[7];
    const float* qkv_b  = (const float*)d_in[8];
    const float* proj_w = (const float*)d_in[9];
    const float* proj_b = (const float*)d_in[10];
    const float* cab_w0 = (const float*)d_in[11];
    const float* cab_b0 = (const float*)d_in[12];
    const float* cab_w1 = (const float*)d_in[13];
    const float* cab_b1 = (const float*)d_in[14];
    const float* cab_w2 = (const float*)d_in[15];
    const float* cab_b2 = (const float*)d_in[16];
    const float* cab_w3 = (const float*)d_in[17];
    const float* cab_b3 = (const float*)d_in[18];
    const float* ca_w1  = (const float*)d_in[19];
    const float* ca_b1  = (const float*)d_in[20];
    const float* ca_w2  = (const float*)d_in[21];
    const float* ca_b2  = (const float*)d_in[22];
    const float* n2g    = (const float*)d_in[23];
    const float* n2b    = (const float*)d_in[24];
    const float* fc1_w  = (const float*)d_in[25];
    const float* fc1_b  = (const float*)d_in[26];
    const float* dw_w   = (const float*)d_in[27];
    const float* dw_b   = (const float*)d_in[28];
    const float* pw_w   = (const float*)d_in[29];
    const float* pw_b   = (const float*)d_in[30];
    const float* sa_w   = (const float*)d_in[31];
    const float* fc2_w  = (const float*)d_in[32];
    const float* fc2_b  = (const float*)d_in[33];
    float* outp = (float*)d_out;
    (void)in_sizes; (void)n_in; (void)out_size; (void)ws_size;

    char* ws = (char*)d_ws;
    const size_t S0 = (size_t)NTOK * 192 * 2;            // xnb -> xn2b
    const size_t S1 = (size_t)NTOK * QKVSTR * 2 + 256;   // qkvP -> h1(half) -> h3(half)
    const size_t S2 = (size_t)NTOK * 192 * 2;            // attnbb -> y3b
    const size_t S3 = (size_t)NTOK * 180 * 2;            // x1b bf16
    const size_t S4 = (size_t)NTOK * 128 * 2;            // y2b ; h2(half) spans S4+S5
    const size_t S5 = (size_t)NTOK * 180 * 4;            // xb -> y4 bf16 (region kept for h2 span)
    char* pA0 = ws;
    char* pA1 = pA0 + S0;
    char* pA2 = pA1 + S1;
    char* pA3 = pA2 + S2;
    char* pA4 = pA3 + S3;
    char* pA5 = pA4 + S4;
    char* tail = pA5 + S5;

    ushortw* xnb    = (ushortw*)pA0;           // [NTOK][192]
    ushortw* xn2b   = (ushortw*)pA0;
    ushortw* qkvP   = (ushortw*)pA1;           // [NTOK][672] (cols 576.. = cab0 out)
    ushortw* h1     = (ushortw*)pA1;           // [HALFTOK][720]
    ushortw* h3     = (ushortw*)pA1;           // [HALFTOK][768]
    ushortw* attnbb = (ushortw*)pA2;           // [NTOK][192]
    ushortw* y3b    = (ushortw*)pA2;           // [NTOK][192]
    ushortw* x1b    = (ushortw*)pA3;           // [NTOK][180] bf16
    ushortw* y2b    = (ushortw*)pA4;           // [NTOK][128]
    ushortw* h2     = (ushortw*)pA4;           // [HALFTOK][768] spans S4+S5
    ushortw* xb     = (ushortw*)pA5;           // [NTOK][180] bf16 (x copy; dead after proj)
    ushortw* y4     = (ushortw*)pA5;           // [NTOK][180] bf16 (written by dw2, after proj)

    // bf16 gemm weights
    ushortw* wqkvc = (ushortw*)tail;                        // 672 x 192
    ushortw* wproj = wqkvc + 672 * 192;                     // 256 x 192
    ushortw* wcab2 = wproj + 256 * 192;                     // 256 x 128
    ushortw* wfc1  = wcab2 + 256 * 128;                     // 768 x 192
    ushortw* wpw   = wfc1  + 768 * 192;                     // 768 x 768
    ushortw* wfc2  = wpw   + 768 * 768;                     // 256 x 768
    char* tail2 = (char*)(wfc2 + 256 * 768);
    float* dwt1 = (float*)tail2;                 float* db1 = dwt1 + 9*128;
    float* dwt2 = db1 + 128;                     float* db2 = dwt2 + 9*192;
    float* dwt3 = db2 + 192;                     float* db3 = dwt3 + 9*768;
    float* qb672 = db3 + 768;
    char* tail3 = (char*)(qb672 + 672);
    float* biasN = (float*)tail3;                           // 6*65536 fp32
    float* part  = (float*)(tail3 + 1572864);               // 4*128*180 fp32
    float* cabuf = (float*)(tail3 + 1572864 + 393216);
    float* mp    = (float*)(tail3 + 1572864 + 393216 + 4096);
    float* ap    = (float*)(tail3 + 1572864 + 393216 + 4096 + (size_t)HALFTOK * 4);
    float* sab   = (float*)(tail3 + 1572864 + 393216 + 4096 + 2*(size_t)HALFTOK * 4);

    auto gemm = [&](const ushortw* A, const ushortw* Wt, const float* bi, void* Cp,
                    int M, int N, int Kp, int ldc, int outbf, int zfill, int act, int residbf,
                    const float* rs, const void* resid) {
        int nM = M >> 7, nN = (N + 127) >> 7;
        mgemm_kernel<<<dim3(nM * nN), dim3(256), 0, stream>>>(
            A, Wt, bi, Cp, M, N, Kp, ldc, outbf, zfill, act, residbf, nN, rs, resid);
    };

    // 0) all weight/bias prep in one launch
    prep_kernel<<<dim3((1220832 + 255) / 256), dim3(256), 0, stream>>>(
        qkv_w, proj_w, cab_w0, cab_b0, cab_w2, fc1_w, pw_w, fc2_w,
        cab_w1, cab_b1, cab_w3, cab_b3, dw_w, dw_b, qkv_b, rpi, rpb,
        wqkvc, wproj, wcab2, wfc1, wpw, wfc2,
        dwt1, db1, dwt2, db2, dwt3, db3, qb672, biasN);

    // 1) LN1 -> bf16 xnb (+ bf16 copy of x for proj residual)
    ln_kernel<<<dim3(NTOK / 4), dim3(256), 0, stream>>>(x, n1g, n1b, xnb, xb);
    // 2) merged qkv+cab0 GEMM -> qkvP[NTOK][672]; then attention + CAB dwconv1
    gemm(xnb, wqkvc, qb672, qkvP, NTOK, 672, 192, QKVSTR, 1, 0, 0, 0, nullptr, nullptr);
    attn_mfma_kernel<<<dim3(BB * 64 * NHEADS), dim3(256), 0, stream>>>(qkvP, biasN, attnbb);
    dwconv4_kernel<672, 128, 128, 1, 1, 1><<<dim3(NTOK / 4 * 32 / 256), dim3(256), 0, stream>>>(
        qkvP + 576, dwt1, db1, y2b);
    // 3) proj with bf16 residual xb -> x1b (bf16)
    gemm(attnbb, wproj, proj_b, x1b, NTOK, 180, 192, 180, 1, 0, 0, 1, nullptr, xb);
    // 4) CAB part 2 (y4 overwrites xb region -- xb dead after proj)
    gemm(y2b, wcab2, cab_b2, y3b, NTOK, 180, 128, 192, 1, 1, 0, 0, nullptr, nullptr);
    dwconv4_kernel<192, 192, 180, 2, 0, 1><<<dim3(NTOK / 4 * 48 / 256), dim3(256), 0, stream>>>(
        y3b, dwt2, db2, y4);
    gap_kernel<<<dim3(BB * 128), dim3(192), 0, stream>>>(y4, part);
    ca_kernel<<<dim3(1), dim3(256), 0, stream>>>(part, ca_w1, ca_b1, ca_w2, ca_b2, cabuf);
    // 5) x1 += 0.01*y4*ca; LN2 -> bf16 xn2b
    resid_ln_kernel<<<dim3(NTOK / 4), dim3(256), 0, stream>>>(x1b, y4, cabuf, n2g, n2b, xn2b);
    // 6) FFN in two half-batches (2 images each)
    for (int half = 0; half < 2; half++) {
        size_t toff = (size_t)half * HALFTOK;
        gemm(xn2b + toff * 192, wfc1, fc1_b, h1, HALFTOK, 720, 192, 720, 1, 0, 1, 0, nullptr, nullptr);
        dwconv4_kernel<720, 768, 768, 1, 2, 1><<<dim3(HALFTOK / 4 * 192 / 256), dim3(256), 0, stream>>>(
            h1, dwt3, db3, h2);
        gemm(h2, wpw, pw_b, h3, HALFTOK, 720, 768, 768, 1, 1, 2, 0, nullptr, nullptr);
        mpap_kernel<<<dim3(HALFTOK / 4), dim3(256), 0, stream>>>(h3, mp, ap);
        saconv_kernel<<<dim3(128), dim3(256), 0, stream>>>(mp, ap, sa_w, sab);
        gemm(h3, wfc2, fc2_b, outp + toff * 180, HALFTOK, 180, 768, 180, 0, 0, 0, 1,
             sab, x1b + toff * 180);
    }
}